// Round 4
// baseline (765.140 us; speedup 1.0000x reference)
//
#include <hip/hip_runtime.h>

#define N_NODES 100000
#define N_EDGES 300000
#define M_PAD   100096   // 782*128
#define E_PAD   300032   // 2344*128

typedef unsigned short u16;
typedef short bf16x8 __attribute__((ext_vector_type(8)));
typedef float f32x4  __attribute__((ext_vector_type(4)));

__device__ __forceinline__ float bf2f(u16 u) {
    unsigned x = ((unsigned)u) << 16;
    return __builtin_bit_cast(float, x);
}
__device__ __forceinline__ u16 f2bf(float f) {
    unsigned u = __builtin_bit_cast(unsigned, f);
    unsigned r = (u + 0x7FFF + ((u >> 16) & 1)) >> 16;
    return (u16)r;
}

// ---------------- output layout (floats) ----------------
#define H_OFF   0
#define CP_OFF  25600000
#define VL_OFF  28800000
#define BL_OFF  29600000
#define VI_OFF  30800000

#define GLL(gp, lp) __builtin_amdgcn_global_load_lds( \
    (const __attribute__((address_space(1))) unsigned int*)(gp), \
    (__attribute__((address_space(3))) unsigned int*)(lp), 16, 0, 0)

// ============ per-atom-type valence MLP + h0 rows ============
__global__ void k_type_mlp(const float* __restrict__ atom_emb,
                           const float* __restrict__ vp_w1, const float* __restrict__ vp_b1,
                           const float* __restrict__ vp_w2, const float* __restrict__ vp_b2,
                           int* __restrict__ pv_tab, float* __restrict__ vl_tab,
                           float* __restrict__ h0_tab)
{
    int tid = threadIdx.x;
    for (int i = tid; i < 11 * 256; i += 256) h0_tab[i] = 0.f;
    __syncthreads();
    if (tid < 11) {
        int t = tid;
        const float* ae = atom_emb + t * 64;
        float lg[8];
        #pragma unroll
        for (int c = 0; c < 8; ++c) lg[c] = vp_b2[c];
        for (int j = 0; j < 32; ++j) {
            float z = vp_b1[j];
            for (int d = 0; d < 64; ++d) z += ae[d] * vp_w1[d * 32 + j];
            z = fmaxf(z, 0.f);
            #pragma unroll
            for (int c = 0; c < 8; ++c) lg[c] += z * vp_w2[j * 8 + c];
        }
        int best = 0;
        #pragma unroll
        for (int c = 1; c < 8; ++c) if (lg[c] > lg[best]) best = c;
        pv_tab[t] = best + 1;
        for (int c = 0; c < 8; ++c) vl_tab[t * 8 + c] = lg[c];
        float* h0 = h0_tab + t * 256;
        for (int d = 0; d < 64; ++d) h0[d] = ae[d];
        h0[64 + best] = 1.f;
    }
}

// ============ layer-0 tables + bond tables for layers 1,2 ============
__global__ void k_tables(const float* __restrict__ bond_emb,
                         const float* __restrict__ gnn_wself, const float* __restrict__ gnn_bself,
                         const float* __restrict__ gnn_wmsg, const float* __restrict__ gnn_bmsg,
                         const float* __restrict__ h0_tab,
                         float* __restrict__ self0_tab, float* __restrict__ msg0_tab,
                         float* __restrict__ bondtab)
{
    int b = blockIdx.x, c = threadIdx.x;
    if (b < 11) {
        int t = b;
        const float* h0 = h0_tab + t * 256;
        float acc = gnn_bself[c];
        for (int k = 0; k < 256; ++k) acc += h0[k] * gnn_wself[k * 256 + c];
        self0_tab[t * 256 + c] = acc;
    } else if (b < 66) {
        int idx = b - 11; int t = idx / 5, bb = idx % 5;
        const float* h0 = h0_tab + t * 256;
        float acc = gnn_bmsg[c];
        for (int k = 0; k < 256; ++k) acc += h0[k] * gnn_wmsg[k * 256 + c];
        const float* be = bond_emb + bb * 64;
        for (int k = 0; k < 64; ++k) acc += be[k] * gnn_wmsg[(256 + k) * 256 + c];
        msg0_tab[idx * 256 + c] = fmaxf(acc, 0.f);
    } else {
        int idx = b - 66; int l = idx / 5 + 1, bb = idx % 5;
        const float* w = gnn_wmsg + (size_t)l * 320 * 256;
        const float* be = bond_emb + bb * 64;
        float acc = gnn_bmsg[l * 256 + c];
        for (int k = 0; k < 64; ++k) acc += be[k] * w[(256 + k) * 256 + c];
        bondtab[(l - 1) * 5 * 256 + bb * 256 + c] = acc;
    }
}

// ============ bf16-transposed weight tables ============
__global__ void k_wtrans(const float* __restrict__ wmsg, const float* __restrict__ wself,
                         const float* __restrict__ bcw1, const float* __restrict__ cpw1,
                         const float* __restrict__ bcw2, const float* __restrict__ cpw2,
                         u16* __restrict__ BtL1, u16* __restrict__ BtL2, u16* __restrict__ Bt3,
                         u16* __restrict__ BtW2, u16* __restrict__ BtCP2)
{
    int b = blockIdx.x, k = threadIdx.x;
    if (b < 512) {
        int n = b;
        float v = (n < 256) ? wmsg[(size_t)1 * 320 * 256 + (size_t)k * 256 + n]
                            : wself[(size_t)1 * 256 * 256 + (size_t)k * 256 + (n - 256)];
        BtL1[n * 256 + k] = f2bf(v);
    } else if (b < 1024) {
        int n = b - 512;
        float v = (n < 256) ? wmsg[(size_t)2 * 320 * 256 + (size_t)k * 256 + n]
                            : wself[(size_t)2 * 256 * 256 + (size_t)k * 256 + (n - 256)];
        BtL2[n * 256 + k] = f2bf(v);
    } else if (b < 1408) {
        int n = b - 1024;
        float v;
        if (n < 128)      v = bcw1[k * 128 + n];
        else if (n < 256) v = bcw1[(256 + k) * 128 + (n - 128)];
        else              v = cpw1[k * 128 + (n - 256)];
        Bt3[n * 256 + k] = f2bf(v);
    } else if (b < 1536) {
        int n = b - 1408;
        if (k < 128) BtW2[n * 128 + k] = f2bf(n < 64 ? bcw2[k * 64 + n] : 0.f);
    } else {
        int n = b - 1536;
        if (k < 128) BtCP2[n * 128 + k] = f2bf(n < 32 ? cpw2[k * 32 + n] : 0.f);
    }
}

__global__ void k_setup_bias(const float* __restrict__ bself, const float* __restrict__ bcb1,
                             const float* __restrict__ cpb1,
                             float* __restrict__ bias512, float* __restrict__ biasPost)
{
    int i = blockIdx.x * 256 + threadIdx.x;
    if (i < 1024) {
        int l = i >> 9, c = i & 511;
        bias512[l * 512 + c] = (c < 256) ? 0.f : bself[(l + 1) * 256 + (c - 256)];
    } else if (i < 1408) {
        int c = i - 1024;
        biasPost[c] = (c < 128) ? bcb1[c] : ((c < 256) ? 0.f : cpb1[c - 256]);
    }
}

// ============ node init ============
__global__ void k_node_init(const float* __restrict__ x, const int* __restrict__ pv_tab,
                            const float* __restrict__ vl_tab,
                            int* __restrict__ types, int* __restrict__ pvarr,
                            int* __restrict__ degree, float* __restrict__ vl_out)
{
    int i = blockIdx.x * blockDim.x + threadIdx.x;
    if (i >= N_NODES) return;
    int t = (int)x[i * 16];
    t = min(max(t, 0), 10);
    types[i] = t;
    pvarr[i] = pv_tab[t];
    degree[i] = 0;
    float4 v0 = *(const float4*)&vl_tab[t * 8];
    float4 v1 = *(const float4*)&vl_tab[t * 8 + 4];
    *(float4*)&vl_out[i * 8]     = v0;
    *(float4*)&vl_out[i * 8 + 4] = v1;
}

__global__ void k_edge_deg(const int* __restrict__ ei, int* __restrict__ degree)
{
    int e = blockIdx.x * blockDim.x + threadIdx.x;
    if (e >= N_EDGES) return;
    atomicAdd(&degree[ei[e]], 1);
}

// ============ scan ============
#define SCAN_B 1024
__global__ void k_scan1(const int* __restrict__ degree, int* __restrict__ part, int* __restrict__ bsum)
{
    __shared__ int s[SCAN_B];
    int tid = threadIdx.x;
    int i = blockIdx.x * SCAN_B + tid;
    int v = (i < N_NODES) ? degree[i] : 0;
    s[tid] = v; __syncthreads();
    for (int off = 1; off < SCAN_B; off <<= 1) {
        int t = (tid >= off) ? s[tid - off] : 0;
        __syncthreads();
        s[tid] += t;
        __syncthreads();
    }
    if (i < N_NODES) part[i] = s[tid] - v;
    if (tid == SCAN_B - 1) bsum[blockIdx.x] = s[tid];
}

__global__ void k_scan2(const int* __restrict__ bsum, int* __restrict__ bbase, int nb)
{
    __shared__ int s[128];
    int tid = threadIdx.x;
    int v = (tid < nb) ? bsum[tid] : 0;
    s[tid] = v; __syncthreads();
    for (int off = 1; off < 128; off <<= 1) {
        int t = (tid >= off) ? s[tid - off] : 0;
        __syncthreads();
        s[tid] += t;
        __syncthreads();
    }
    bbase[tid] = s[tid] - v;
}

__global__ void k_scan3(int* __restrict__ part, const int* __restrict__ bbase, int* __restrict__ cursor)
{
    int i = blockIdx.x * SCAN_B + threadIdx.x;
    if (i >= N_NODES) return;
    int o = part[i] + bbase[blockIdx.x];
    part[i] = o;
    cursor[i] = o;
}

// ============ CSR fill (+ row/eid side arrays for the bond pass) ============
__global__ void k_csr_fill(const int* __restrict__ ei, const float* __restrict__ edge_attr,
                           const int* __restrict__ types, int* __restrict__ cursor,
                           int* __restrict__ csr, int* __restrict__ rowcsr, int* __restrict__ eidarr)
{
    int e = blockIdx.x * blockDim.x + threadIdx.x;
    if (e >= N_EDGES) return;
    int row = ei[e], col = ei[N_EDGES + e];
    int bt = (int)edge_attr[e * 4];
    bt = min(max(bt, 0), 4);
    int pos = atomicAdd(&cursor[row], 1);
    csr[pos] = col | (bt << 20) | (types[col] << 24);
    rowcsr[pos] = row;
    eidarr[pos] = e;
}

// ============ layer-0 aggregation (tables) -> h bf16 ============
__global__ __launch_bounds__(256) void k_agg0(const int* __restrict__ offsets, const int* __restrict__ degree,
                       const int* __restrict__ types,
                       const float* __restrict__ self0_tab, const float* __restrict__ msg0_tab,
                       const int* __restrict__ csr, u16* __restrict__ h)
{
    int wid = threadIdx.x >> 6, lane = threadIdx.x & 63;
    int node = blockIdx.x * 4 + wid;
    if (node >= N_NODES) return;
    int t = types[node];
    float4 acc = *(const float4*)&self0_tab[t * 256 + lane * 4];
    int start = offsets[node], deg = degree[node];
    for (int j = 0; j < deg; ++j) {
        int p = csr[start + j];
        int combo = ((p >> 24) & 0xF) * 5 + ((p >> 20) & 7);
        float4 m = *(const float4*)&msg0_tab[combo * 256 + lane * 4];
        acc.x += m.x; acc.y += m.y; acc.z += m.z; acc.w += m.w;
    }
    ushort4 r;
    r.x = f2bf(fmaxf(acc.x, 0.f)); r.y = f2bf(fmaxf(acc.y, 0.f));
    r.z = f2bf(fmaxf(acc.z, 0.f)); r.w = f2bf(fmaxf(acc.w, 0.f));
    *(ushort4*)&h[(size_t)node * 256 + lane * 4] = r;
}

// ============ layers 1,2 aggregation; final layer fuses damp/viol/h_out ============
__global__ __launch_bounds__(256) void k_agg12(const int* __restrict__ offsets, const int* __restrict__ degree,
                        const u16* __restrict__ hs, const u16* __restrict__ hm,
                        const float* __restrict__ bondtab, const int* __restrict__ csr,
                        u16* __restrict__ h, int final_layer, const int* __restrict__ pvarr,
                        float* __restrict__ h_out, u16* __restrict__ hd_bf, float* __restrict__ viol_out)
{
    int wid = threadIdx.x >> 6, lane = threadIdx.x & 63;
    int node = blockIdx.x * 4 + wid;
    if (node >= N_NODES) return;
    ushort4 s4 = *(const ushort4*)&hs[(size_t)node * 256 + lane * 4];
    float ax = bf2f(s4.x), ay = bf2f(s4.y), az = bf2f(s4.z), aw = bf2f(s4.w);
    int start = offsets[node], deg = degree[node];
    for (int j = 0; j < deg; ++j) {
        int p = csr[start + j];
        int c = p & 0xFFFFF;
        int bt = (p >> 20) & 7;
        ushort4 m4 = *(const ushort4*)&hm[(size_t)c * 256 + lane * 4];
        float4 bb = *(const float4*)&bondtab[bt * 256 + lane * 4];
        ax += fmaxf(bf2f(m4.x) + bb.x, 0.f);
        ay += fmaxf(bf2f(m4.y) + bb.y, 0.f);
        az += fmaxf(bf2f(m4.z) + bb.z, 0.f);
        aw += fmaxf(bf2f(m4.w) + bb.w, 0.f);
    }
    ax = fmaxf(ax, 0.f); ay = fmaxf(ay, 0.f); az = fmaxf(az, 0.f); aw = fmaxf(aw, 0.f);
    if (!final_layer) {
        ushort4 r;
        r.x = f2bf(ax); r.y = f2bf(ay); r.z = f2bf(az); r.w = f2bf(aw);
        *(ushort4*)&h[(size_t)node * 256 + lane * 4] = r;
    } else {
        float viol = fmaxf((float)deg - (float)pvarr[node], 0.f);
        float s = 1.f / (1.f + viol);
        ax *= s; ay *= s; az *= s; aw *= s;
        float4 v = make_float4(ax, ay, az, aw);
        *(float4*)&h_out[(size_t)node * 256 + lane * 4] = v;
        ushort4 r;
        r.x = f2bf(ax); r.y = f2bf(ay); r.z = f2bf(az); r.w = f2bf(aw);
        *(ushort4*)&hd_bf[(size_t)node * 256 + lane * 4] = r;
        if (lane == 0) viol_out[node] = viol;
    }
}

// ================== layer GEMM: B-in-LDS-once + A-direct-to-regs, barrier-free K-loop ==================
// B tile [128 n][256 k] staged ONCE into 64 KB LDS (XOR-swizzled 16-B chunks), one barrier.
// A fragments stream straight from global (L2-resident; wave reads 16 rows x 64 B per frag).
// K-loop: 8 slices x (4 global loads + 4 ds_reads + 16 MFMA), no barriers, no vmcnt(0) drains.
__global__ __launch_bounds__(256) void k_gemm_dual(
    const u16* __restrict__ A, const u16* __restrict__ Bt,
    const float* __restrict__ bias512,
    u16* __restrict__ Dm, u16* __restrict__ Ds, int M, int MT)
{
    __shared__ u16 Bs[128 * 256];   // 64 KB
    int b = blockIdx.x;
    int rsub = b & 31;
    int nt = rsub >> 3, m8 = rsub & 7;
    int mt = (b >> 5) * 8 + m8;
    if (mt >= MT) return;
    int bm = mt * 128, bn = nt * 128;

    int t = threadIdx.x;
    int lane = t & 63, w = t >> 6;
    int wm = w & 1, wn = w >> 1;
    int q = lane >> 4, r = lane & 15;

    // ---- stage B once: physical chunk t&31, row g*8+(t>>5); source chunk = phys ^ (row&15) ----
    #pragma unroll
    for (int g = 0; g < 16; ++g) {
        int row = g * 8 + (t >> 5);
        int lchunk = (t & 31) ^ (row & 15);
        GLL(Bt + (size_t)(bn + row) * 256 + lchunk * 8, Bs + g * 2048 + t * 8);
    }

    f32x4 zero = {0.f, 0.f, 0.f, 0.f};
    f32x4 acc[4][4];
    #pragma unroll
    for (int i = 0; i < 4; ++i)
        #pragma unroll
        for (int j = 0; j < 4; ++j) acc[i][j] = zero;

    const u16* Ap0 = A + (size_t)(bm + wm * 64 + r) * 256 + q * 8;

    __syncthreads();   // Bs ready (GLL drained by barrier's vmcnt(0))

    #pragma unroll
    for (int kk = 0; kk < 8; ++kk) {
        bf16x8 af[4], bfr[4];
        #pragma unroll
        for (int i = 0; i < 4; ++i)
            af[i] = *(const bf16x8*)(Ap0 + (size_t)i * 16 * 256 + kk * 32);
        #pragma unroll
        for (int j = 0; j < 4; ++j)
            bfr[j] = *(const bf16x8*)&Bs[(wn * 64 + j * 16 + r) * 256 + (((kk * 4 + q) ^ r)) * 8];
        #pragma unroll
        for (int i = 0; i < 4; ++i)
            #pragma unroll
            for (int j = 0; j < 4; ++j)
                acc[i][j] = __builtin_amdgcn_mfma_f32_16x16x32_bf16(af[i], bfr[j], acc[i][j], 0, 0, 0);
    }
    #pragma unroll
    for (int i = 0; i < 4; ++i) {
        int rowb = bm + wm * 64 + i * 16 + q * 4;
        #pragma unroll
        for (int j = 0; j < 4; ++j) {
            int colg = bn + wn * 64 + j * 16 + r;
            float bv = bias512[colg];
            u16* D = (colg < 256) ? Dm : Ds;
            int col = colg & 255;
            #pragma unroll
            for (int rr = 0; rr < 4; ++rr) {
                int rowg = rowb + rr;
                if (rowg < M) D[(size_t)rowg * 256 + col] = f2bf(acc[i][j][rr] + bv);
            }
        }
    }
}

// ================== post GEMM (N=384), same barrier-free structure ==================
__global__ __launch_bounds__(256) void k_gemm_post(
    const u16* __restrict__ A, const u16* __restrict__ Bt3,
    const float* __restrict__ biasPost,
    u16* __restrict__ UV, u16* __restrict__ CP1, int M, int MT)
{
    __shared__ u16 Bs[128 * 256];
    int b = blockIdx.x;
    int rsub = b % 24;
    int nt = rsub >> 3, m8 = rsub & 7;
    int mt = (b / 24) * 8 + m8;
    if (mt >= MT) return;
    int bm = mt * 128, bn = nt * 128;

    int t = threadIdx.x;
    int lane = t & 63, w = t >> 6;
    int wm = w & 1, wn = w >> 1;
    int q = lane >> 4, r = lane & 15;

    #pragma unroll
    for (int g = 0; g < 16; ++g) {
        int row = g * 8 + (t >> 5);
        int lchunk = (t & 31) ^ (row & 15);
        GLL(Bt3 + (size_t)(bn + row) * 256 + lchunk * 8, Bs + g * 2048 + t * 8);
    }

    f32x4 zero = {0.f, 0.f, 0.f, 0.f};
    f32x4 acc[4][4];
    #pragma unroll
    for (int i = 0; i < 4; ++i)
        #pragma unroll
        for (int j = 0; j < 4; ++j) acc[i][j] = zero;

    const u16* Ap0 = A + (size_t)(bm + wm * 64 + r) * 256 + q * 8;

    __syncthreads();

    #pragma unroll
    for (int kk = 0; kk < 8; ++kk) {
        bf16x8 af[4], bfr[4];
        #pragma unroll
        for (int i = 0; i < 4; ++i)
            af[i] = *(const bf16x8*)(Ap0 + (size_t)i * 16 * 256 + kk * 32);
        #pragma unroll
        for (int j = 0; j < 4; ++j)
            bfr[j] = *(const bf16x8*)&Bs[(wn * 64 + j * 16 + r) * 256 + (((kk * 4 + q) ^ r)) * 8];
        #pragma unroll
        for (int i = 0; i < 4; ++i)
            #pragma unroll
            for (int j = 0; j < 4; ++j)
                acc[i][j] = __builtin_amdgcn_mfma_f32_16x16x32_bf16(af[i], bfr[j], acc[i][j], 0, 0, 0);
    }
    #pragma unroll
    for (int i = 0; i < 4; ++i) {
        int rowb = bm + wm * 64 + i * 16 + q * 4;
        #pragma unroll
        for (int j = 0; j < 4; ++j) {
            int coll = wn * 64 + j * 16 + r;
            float bv = biasPost[bn + coll];
            #pragma unroll
            for (int rr = 0; rr < 4; ++rr) {
                int rowg = rowb + rr;
                if (rowg < M) {
                    float val = acc[i][j][rr] + bv;
                    if (nt < 2) UV[(size_t)rowg * 256 + bn + coll] = f2bf(val);
                    else        CP1[(size_t)rowg * 128 + coll] = f2bf(fmaxf(val, 0.f));
                }
            }
        }
    }
}

// ================== small K=128 MFMA GEMM (cp2 only) ==================
__global__ __launch_bounds__(256) void k_gemm_k128(
    const u16* __restrict__ A, const u16* __restrict__ Bt,
    const float* __restrict__ bias, float* __restrict__ C,
    int ldc, int M, int N)
{
    __shared__ u16 As[4096];
    __shared__ u16 Bs[4096];
    int t = threadIdx.x;
    int lane = t & 63, w = t >> 6;
    int wm = w & 1, wn = w >> 1;
    int bm = blockIdx.x * 128;
    int arow = t >> 2, acol = (t & 3) * 8;
    int q = lane >> 4, r = lane & 15;
    const u16* Ag = A + (size_t)(bm + arow) * 128 + acol;
    const u16* Bg = Bt + (size_t)arow * 128 + acol;
    f32x4 zero = {0.f, 0.f, 0.f, 0.f};
    f32x4 acc[4][4];
    #pragma unroll
    for (int i = 0; i < 4; ++i)
        #pragma unroll
        for (int j = 0; j < 4; ++j) acc[i][j] = zero;

    for (int kc = 0; kc < 4; ++kc) {
        __syncthreads();
        GLL(Ag + kc * 32,            As + t * 8);
        GLL(Ag + 64 * 128 + kc * 32, As + 2048 + t * 8);
        GLL(Bg + kc * 32,            Bs + t * 8);
        GLL(Bg + 64 * 128 + kc * 32, Bs + 2048 + t * 8);
        __syncthreads();
        bf16x8 af[4], bfr[4];
        #pragma unroll
        for (int i = 0; i < 4; ++i)
            af[i] = *(const bf16x8*)&As[(wm * 64 + i * 16 + r) * 32 + q * 8];
        #pragma unroll
        for (int j = 0; j < 4; ++j)
            bfr[j] = *(const bf16x8*)&Bs[(wn * 64 + j * 16 + r) * 32 + q * 8];
        #pragma unroll
        for (int i = 0; i < 4; ++i)
            #pragma unroll
            for (int j = 0; j < 4; ++j)
                acc[i][j] = __builtin_amdgcn_mfma_f32_16x16x32_bf16(af[i], bfr[j], acc[i][j], 0, 0, 0);
    }
    #pragma unroll
    for (int i = 0; i < 4; ++i) {
        int rowb = bm + wm * 64 + i * 16 + q * 4;
        #pragma unroll
        for (int j = 0; j < 4; ++j) {
            int colg = wn * 64 + j * 16 + r;
            if (colg >= N) continue;
            float bv = bias[colg];
            #pragma unroll
            for (int rr = 0; rr < 4; ++rr) {
                int rowg = rowb + rr;
                if (rowg < M) C[(size_t)rowg * ldc + colg] = acc[i][j][rr] + bv;
            }
        }
    }
}

// ================== fused bond kernel ==================
__global__ __launch_bounds__(256) void k_bond_fused(
    const int* __restrict__ csr, const int* __restrict__ rowcsr, const int* __restrict__ eidarr,
    const int* __restrict__ types, const int* __restrict__ pvarr, const int* __restrict__ pv_tab,
    const u16* __restrict__ uv, const float* __restrict__ bc_w1,
    const u16* __restrict__ BtW2, const float* __restrict__ bc_b2,
    const float* __restrict__ bc_w3, const float* __restrict__ bc_b3,
    float* __restrict__ bl_out)
{
    __shared__ u16 T1s[16384];     // 32 KB: 4 chunks x [128 rows][32 k]; reused as f32 T2 [128][64]
    __shared__ u16 Bs[16384];      // 32 KB: 4 chunks x [128 cols][32 k]
    __shared__ float w5s[128], w6s[128], W3s[256], b2s[64], b3s[4];
    __shared__ int pvts[16];

    int t = threadIdx.x;
    int p0 = blockIdx.x * 128;

    if (t < 128) { w5s[t] = bc_w1[512 * 128 + t]; w6s[t] = bc_w1[513 * 128 + t]; }
    if (t < 256) W3s[t] = bc_w3[t];
    if (t < 64) b2s[t] = bc_b2[t];
    if (t < 4)  b3s[t] = bc_b3[t];
    if (t < 11) pvts[t] = pv_tab[t];
    #pragma unroll
    for (int c = 0; c < 4; ++c) {
        GLL(BtW2 + (size_t)(t >> 2) * 128 + c * 32 + (t & 3) * 8,        Bs + c * 4096 + t * 8);
        GLL(BtW2 + (size_t)(64 + (t >> 2)) * 128 + c * 32 + (t & 3) * 8, Bs + c * 4096 + 2048 + t * 8);
    }

    int l = t >> 1;            // local row 0..127
    int half = t & 1;          // which 64-col half
    int pos = p0 + l;
    int prow = 0, pk = 0;
    if (pos < N_EDGES) { prow = rowcsr[pos]; pk = csr[pos]; }
    int pcol = pk & 0xFFFFF;
    float pvr = (float)pvarr[prow];
    __syncthreads();   // w5s/w6s/pvts ready (pvts must not be read before this barrier)
    float pvc = (float)pvts[(pk >> 24) & 0xF];

    const u16* up = uv + (size_t)prow * 256 + half * 64;
    const u16* vp = uv + (size_t)pcol * 256 + 128 + half * 64;
    #pragma unroll
    for (int j = 0; j < 8; ++j) {
        int c = half * 64 + j * 8;
        ushort4 ua = *(const ushort4*)(up + j * 8);
        ushort4 ub = *(const ushort4*)(up + j * 8 + 4);
        ushort4 va = *(const ushort4*)(vp + j * 8);
        ushort4 vb = *(const ushort4*)(vp + j * 8 + 4);
        int chunk = c >> 5, kk = c & 31;
        u16* dst = T1s + chunk * 4096 + l * 32 + kk;
        dst[0] = f2bf(fmaxf(bf2f(ua.x) + bf2f(va.x) + pvr * w5s[c+0] + pvc * w6s[c+0], 0.f));
        dst[1] = f2bf(fmaxf(bf2f(ua.y) + bf2f(va.y) + pvr * w5s[c+1] + pvc * w6s[c+1], 0.f));
        dst[2] = f2bf(fmaxf(bf2f(ua.z) + bf2f(va.z) + pvr * w5s[c+2] + pvc * w6s[c+2], 0.f));
        dst[3] = f2bf(fmaxf(bf2f(ua.w) + bf2f(va.w) + pvr * w5s[c+3] + pvc * w6s[c+3], 0.f));
        dst[4] = f2bf(fmaxf(bf2f(ub.x) + bf2f(vb.x) + pvr * w5s[c+4] + pvc * w6s[c+4], 0.f));
        dst[5] = f2bf(fmaxf(bf2f(ub.y) + bf2f(vb.y) + pvr * w5s[c+5] + pvc * w6s[c+5], 0.f));
        dst[6] = f2bf(fmaxf(bf2f(ub.z) + bf2f(vb.z) + pvr * w5s[c+6] + pvc * w6s[c+6], 0.f));
        dst[7] = f2bf(fmaxf(bf2f(ub.w) + bf2f(vb.w) + pvr * w5s[c+7] + pvc * w6s[c+7], 0.f));
    }
    __syncthreads();   // T1s + Bs (GLL drained by barrier) ready

    int lane = t & 63, w = t >> 6;
    int wm = w & 1, wn = w >> 1;
    int q = lane >> 4, r = lane & 15;
    f32x4 zero = {0.f, 0.f, 0.f, 0.f};
    f32x4 acc[4][4];
    #pragma unroll
    for (int i = 0; i < 4; ++i)
        #pragma unroll
        for (int j = 0; j < 4; ++j) acc[i][j] = zero;
    #pragma unroll
    for (int c = 0; c < 4; ++c) {
        bf16x8 af[4], bfr[4];
        #pragma unroll
        for (int i = 0; i < 4; ++i)
            af[i] = *(const bf16x8*)&T1s[c * 4096 + (wm * 64 + i * 16 + r) * 32 + q * 8];
        #pragma unroll
        for (int j = 0; j < 4; ++j)
            bfr[j] = *(const bf16x8*)&Bs[c * 4096 + (wn * 64 + j * 16 + r) * 32 + q * 8];
        #pragma unroll
        for (int i = 0; i < 4; ++i)
            #pragma unroll
            for (int j = 0; j < 4; ++j)
                acc[i][j] = __builtin_amdgcn_mfma_f32_16x16x32_bf16(af[i], bfr[j], acc[i][j], 0, 0, 0);
    }
    __syncthreads();   // all T1s reads done; reuse as f32 T2

    float* T2f = (float*)T1s;   // [128][64]
    if (wn == 0) {
        #pragma unroll
        for (int i = 0; i < 4; ++i) {
            int row = wm * 64 + i * 16 + q * 4;
            #pragma unroll
            for (int j = 0; j < 4; ++j) {
                int col = j * 16 + r;
                float bv = b2s[col];
                #pragma unroll
                for (int rr = 0; rr < 4; ++rr)
                    T2f[(row + rr) * 64 + col] = fmaxf(acc[i][j][rr] + bv, 0.f);
            }
        }
    }
    __syncthreads();

    if (t < 128) {
        int pos3 = p0 + t;
        if (pos3 < N_EDGES) {
            float a0 = b3s[0], a1 = b3s[1], a2 = b3s[2], a3 = b3s[3];
            const float* trow = &T2f[t * 64];
            #pragma unroll 8
            for (int kk = 0; kk < 64; ++kk) {
                int k = (kk + t) & 63;           // rotate start: spread banks across lanes
                float tv = trow[k];
                a0 += tv * W3s[k * 4 + 0];
                a1 += tv * W3s[k * 4 + 1];
                a2 += tv * W3s[k * 4 + 2];
                a3 += tv * W3s[k * 4 + 3];
            }
            int prow3 = rowcsr[pos3];
            int pk3 = csr[pos3];
            int tc = (pk3 >> 24) & 0xF;
            int tr = types[prow3];
            int pr = pvarr[prow3];
            int pc = pvts[tc];
            float halogen = (tr == 4 || tr == 5 || tc == 4 || tc == 5) ? 1.f : 0.f;
            float l1 = (pr <= 1 || pc <= 1) ? 1.f : 0.f;
            float l2 = (pr <= 2 || pc <= 2) ? 1.f : 0.f;
            float pen13 = -100.f * halogen - 50.f * l1;
            a1 += pen13;
            a3 += pen13;
            a2 += pen13 - 50.f * l2;
            int eid = eidarr[pos3];
            *(float4*)&bl_out[(size_t)eid * 4] = make_float4(a0, a1, a2, a3);
        }
    }
}

// ================================================================
extern "C" void kernel_launch(void* const* d_in, const int* in_sizes, int n_in,
                              void* d_out, int out_size, void* d_ws, size_t ws_size,
                              hipStream_t stream)
{
    const float* x          = (const float*)d_in[0];
    const float* edge_attr  = (const float*)d_in[1];
    const float* atom_emb   = (const float*)d_in[2];
    const float* bond_emb   = (const float*)d_in[3];
    const float* vp_w1      = (const float*)d_in[4];
    const float* vp_b1      = (const float*)d_in[5];
    const float* vp_w2      = (const float*)d_in[6];
    const float* vp_b2      = (const float*)d_in[7];
    const float* gnn_wself  = (const float*)d_in[8];
    const float* gnn_bself  = (const float*)d_in[9];
    const float* gnn_wmsg   = (const float*)d_in[10];
    const float* gnn_bmsg   = (const float*)d_in[11];
    const float* bc_w1      = (const float*)d_in[12];
    const float* bc_b1      = (const float*)d_in[13];
    const float* bc_w2      = (const float*)d_in[14];
    const float* bc_b2      = (const float*)d_in[15];
    const float* bc_w3      = (const float*)d_in[16];
    const float* bc_b3      = (const float*)d_in[17];
    const float* cp_w1      = (const float*)d_in[18];
    const float* cp_b1      = (const float*)d_in[19];
    const float* cp_w2      = (const float*)d_in[20];
    const float* cp_b2      = (const float*)d_in[21];
    const int*   ei         = (const int*)d_in[22];

    float* out    = (float*)d_out;
    float* h_out  = out + H_OFF;
    float* cp_out = out + CP_OFF;
    float* vl_out = out + VL_OFF;
    float* bl_out = out + BL_OFF;
    float* vi_out = out + VI_OFF;

    // ---- workspace layout ----
    char* base = (char*)d_ws;
    const size_t S = (size_t)M_PAD * 256 * 2;   // 51,249,152 B
    u16* h_bf  = (u16*)(base + 0 * S);           // R0: h ; later uv
    u16* uv_bf = (u16*)(base + 0 * S);
    u16* hm_bf = (u16*)(base + 1 * S);           // R1: hm
    u16* hs_bf = (u16*)(base + 2 * S);           // R2: hs
    u16* hd_bf = (u16*)(base + 3 * S);           // R3: damped h bf16
    u16* cp1_bf= (u16*)(base + 4 * S);           // R4: [M_PAD][128] bf16
    char* w    = base + 4 * S + (size_t)M_PAD * 128 * 2;
    int* degree  = (int*)w; w += (size_t)N_NODES * 4;
    int* offsets = (int*)w; w += (size_t)N_NODES * 4;
    int* cursor  = (int*)w; w += (size_t)N_NODES * 4;
    int* types   = (int*)w; w += (size_t)N_NODES * 4;
    int* pvarr   = (int*)w; w += (size_t)N_NODES * 4;
    int* csr     = (int*)w; w += (size_t)E_PAD * 4;
    int* rowcsr  = (int*)w; w += (size_t)E_PAD * 4;
    int* eidarr  = (int*)w; w += (size_t)E_PAD * 4;
    int* bsum    = (int*)w; w += 4096;
    int* bbase   = (int*)w; w += 4096;
    int* pv_tab  = (int*)w; w += 1024;
    float* vl_tab    = (float*)w; w += 2048;
    float* h0_tab    = (float*)w; w += 11 * 256 * 4;
    float* self0_tab = (float*)w; w += 11 * 256 * 4;
    float* msg0_tab  = (float*)w; w += 55 * 256 * 4;
    float* bondtab   = (float*)w; w += 2 * 5 * 256 * 4;
    u16* BtL1  = (u16*)w; w += 512 * 256 * 2;
    u16* BtL2  = (u16*)w; w += 512 * 256 * 2;
    u16* Bt3   = (u16*)w; w += 384 * 256 * 2;
    u16* BtW2  = (u16*)w; w += 128 * 128 * 2;
    u16* BtCP2 = (u16*)w; w += 128 * 128 * 2;
    float* bias512  = (float*)w; w += 2 * 512 * 4;
    float* biasPost = (float*)w; w += 384 * 4;

    // ---- setup ----
    k_type_mlp<<<1, 256, 0, stream>>>(atom_emb, vp_w1, vp_b1, vp_w2, vp_b2, pv_tab, vl_tab, h0_tab);
    k_tables<<<76, 256, 0, stream>>>(bond_emb, gnn_wself, gnn_bself, gnn_wmsg, gnn_bmsg,
                                     h0_tab, self0_tab, msg0_tab, bondtab);
    k_wtrans<<<1664, 256, 0, stream>>>(gnn_wmsg, gnn_wself, bc_w1, cp_w1, bc_w2, cp_w2,
                                       BtL1, BtL2, Bt3, BtW2, BtCP2);
    k_setup_bias<<<6, 256, 0, stream>>>(gnn_bself, bc_b1, cp_b1, bias512, biasPost);
    k_node_init<<<(N_NODES + 255) / 256, 256, 0, stream>>>(x, pv_tab, vl_tab, types, pvarr, degree, vl_out);
    k_edge_deg<<<(N_EDGES + 255) / 256, 256, 0, stream>>>(ei, degree);
    int nb = (N_NODES + SCAN_B - 1) / SCAN_B;
    k_scan1<<<nb, SCAN_B, 0, stream>>>(degree, offsets, bsum);
    k_scan2<<<1, 128, 0, stream>>>(bsum, bbase, nb);
    k_scan3<<<nb, SCAN_B, 0, stream>>>(offsets, bbase, cursor);
    k_csr_fill<<<(N_EDGES + 255) / 256, 256, 0, stream>>>(ei, edge_attr, types, cursor, csr, rowcsr, eidarr);
    k_agg0<<<N_NODES / 4, 256, 0, stream>>>(offsets, degree, types, self0_tab, msg0_tab, csr, h_bf);

    // ---- GNN layers 1,2 (l=2 fuses damp/viol/h_out) ----
    const int MT = M_PAD / 128;           // 782
    const int QB = (MT + 7) / 8;          // 98
    for (int l = 1; l <= 2; ++l) {
        const u16* BtL = (l == 1) ? BtL1 : BtL2;
        k_gemm_dual<<<QB * 32, 256, 0, stream>>>(h_bf, BtL, bias512 + (size_t)(l - 1) * 512,
                                                 hm_bf, hs_bf, N_NODES, MT);
        k_agg12<<<N_NODES / 4, 256, 0, stream>>>(offsets, degree, hs_bf, hm_bf,
                                                 bondtab + (size_t)(l - 1) * 5 * 256, csr, h_bf,
                                                 (l == 2) ? 1 : 0, pvarr, h_out, hd_bf, vi_out);
    }

    // ---- uv + cp1 fused; then cp2 ----
    k_gemm_post<<<QB * 24, 256, 0, stream>>>(hd_bf, Bt3, biasPost, uv_bf, cp1_bf, N_NODES, MT);
    k_gemm_k128<<<MT, 256, 0, stream>>>(cp1_bf, BtCP2, cp_b2, cp_out, 32, N_NODES, 32);

    // ---- fused bond chain ----
    k_bond_fused<<<E_PAD / 128, 256, 0, stream>>>(csr, rowcsr, eidarr, types, pvarr, pv_tab,
                                                  uv_bf, bc_w1, BtW2, bc_b2, bc_w3, bc_b3, bl_out);
}

// Round 5
// 641.324 us; speedup vs baseline: 1.1931x; 1.1931x over previous
//
#include <hip/hip_runtime.h>

#define N_NODES 100000
#define N_EDGES 300000
#define M_PAD   100096   // 782*128
#define E_PAD   300032   // 2344*128

typedef unsigned short u16;
typedef short bf16x8 __attribute__((ext_vector_type(8)));
typedef float f32x4  __attribute__((ext_vector_type(4)));
typedef unsigned short u16x8 __attribute__((ext_vector_type(8)));

__device__ __forceinline__ float bf2f(u16 u) {
    unsigned x = ((unsigned)u) << 16;
    return __builtin_bit_cast(float, x);
}
__device__ __forceinline__ u16 f2bf(float f) {
    unsigned u = __builtin_bit_cast(unsigned, f);
    unsigned r = (u + 0x7FFF + ((u >> 16) & 1)) >> 16;
    return (u16)r;
}

// ---------------- output layout (floats) ----------------
#define H_OFF   0
#define CP_OFF  25600000
#define VL_OFF  28800000
#define BL_OFF  29600000
#define VI_OFF  30800000

#define GLL(gp, lp) __builtin_amdgcn_global_load_lds( \
    (const __attribute__((address_space(1))) unsigned int*)(gp), \
    (__attribute__((address_space(3))) unsigned int*)(lp), 16, 0, 0)

// ============ per-atom-type valence MLP + h0 rows ============
__global__ void k_type_mlp(const float* __restrict__ atom_emb,
                           const float* __restrict__ vp_w1, const float* __restrict__ vp_b1,
                           const float* __restrict__ vp_w2, const float* __restrict__ vp_b2,
                           int* __restrict__ pv_tab, float* __restrict__ vl_tab,
                           float* __restrict__ h0_tab)
{
    int tid = threadIdx.x;
    for (int i = tid; i < 11 * 256; i += 256) h0_tab[i] = 0.f;
    __syncthreads();
    if (tid < 11) {
        int t = tid;
        const float* ae = atom_emb + t * 64;
        float lg[8];
        #pragma unroll
        for (int c = 0; c < 8; ++c) lg[c] = vp_b2[c];
        for (int j = 0; j < 32; ++j) {
            float z = vp_b1[j];
            for (int d = 0; d < 64; ++d) z += ae[d] * vp_w1[d * 32 + j];
            z = fmaxf(z, 0.f);
            #pragma unroll
            for (int c = 0; c < 8; ++c) lg[c] += z * vp_w2[j * 8 + c];
        }
        int best = 0;
        #pragma unroll
        for (int c = 1; c < 8; ++c) if (lg[c] > lg[best]) best = c;
        pv_tab[t] = best + 1;
        for (int c = 0; c < 8; ++c) vl_tab[t * 8 + c] = lg[c];
        float* h0 = h0_tab + t * 256;
        for (int d = 0; d < 64; ++d) h0[d] = ae[d];
        h0[64 + best] = 1.f;
    }
}

// ============ layer-0 tables + bond tables for layers 1,2 ============
__global__ void k_tables(const float* __restrict__ bond_emb,
                         const float* __restrict__ gnn_wself, const float* __restrict__ gnn_bself,
                         const float* __restrict__ gnn_wmsg, const float* __restrict__ gnn_bmsg,
                         const float* __restrict__ h0_tab,
                         float* __restrict__ self0_tab, float* __restrict__ msg0_tab,
                         float* __restrict__ bondtab)
{
    int b = blockIdx.x, c = threadIdx.x;
    if (b < 11) {
        int t = b;
        const float* h0 = h0_tab + t * 256;
        float acc = gnn_bself[c];
        for (int k = 0; k < 256; ++k) acc += h0[k] * gnn_wself[k * 256 + c];
        self0_tab[t * 256 + c] = acc;
    } else if (b < 66) {
        int idx = b - 11; int t = idx / 5, bb = idx % 5;
        const float* h0 = h0_tab + t * 256;
        float acc = gnn_bmsg[c];
        for (int k = 0; k < 256; ++k) acc += h0[k] * gnn_wmsg[k * 256 + c];
        const float* be = bond_emb + bb * 64;
        for (int k = 0; k < 64; ++k) acc += be[k] * gnn_wmsg[(256 + k) * 256 + c];
        msg0_tab[idx * 256 + c] = fmaxf(acc, 0.f);
    } else {
        int idx = b - 66; int l = idx / 5 + 1, bb = idx % 5;
        const float* w = gnn_wmsg + (size_t)l * 320 * 256;
        const float* be = bond_emb + bb * 64;
        float acc = gnn_bmsg[l * 256 + c];
        for (int k = 0; k < 64; ++k) acc += be[k] * w[(256 + k) * 256 + c];
        bondtab[(l - 1) * 5 * 256 + bb * 256 + c] = acc;
    }
}

// ============ bf16-transposed weight tables ============
__global__ void k_wtrans(const float* __restrict__ wmsg, const float* __restrict__ wself,
                         const float* __restrict__ bcw1, const float* __restrict__ cpw1,
                         const float* __restrict__ bcw2, const float* __restrict__ cpw2,
                         u16* __restrict__ BtL1, u16* __restrict__ BtL2, u16* __restrict__ Bt3,
                         u16* __restrict__ BtW2, u16* __restrict__ BtCP2)
{
    int b = blockIdx.x, k = threadIdx.x;
    if (b < 512) {
        int n = b;
        float v = (n < 256) ? wmsg[(size_t)1 * 320 * 256 + (size_t)k * 256 + n]
                            : wself[(size_t)1 * 256 * 256 + (size_t)k * 256 + (n - 256)];
        BtL1[n * 256 + k] = f2bf(v);
    } else if (b < 1024) {
        int n = b - 512;
        float v = (n < 256) ? wmsg[(size_t)2 * 320 * 256 + (size_t)k * 256 + n]
                            : wself[(size_t)2 * 256 * 256 + (size_t)k * 256 + (n - 256)];
        BtL2[n * 256 + k] = f2bf(v);
    } else if (b < 1408) {
        int n = b - 1024;
        float v;
        if (n < 128)      v = bcw1[k * 128 + n];
        else if (n < 256) v = bcw1[(256 + k) * 128 + (n - 128)];
        else              v = cpw1[k * 128 + (n - 256)];
        Bt3[n * 256 + k] = f2bf(v);
    } else if (b < 1536) {
        int n = b - 1408;
        if (k < 128) BtW2[n * 128 + k] = f2bf(n < 64 ? bcw2[k * 64 + n] : 0.f);
    } else {
        int n = b - 1536;
        if (k < 128) BtCP2[n * 128 + k] = f2bf(n < 32 ? cpw2[k * 32 + n] : 0.f);
    }
}

__global__ void k_setup_bias(const float* __restrict__ bself, const float* __restrict__ bcb1,
                             const float* __restrict__ cpb1,
                             float* __restrict__ bias512, float* __restrict__ biasPost)
{
    int i = blockIdx.x * 256 + threadIdx.x;
    if (i < 1024) {
        int l = i >> 9, c = i & 511;
        bias512[l * 512 + c] = (c < 256) ? 0.f : bself[(l + 1) * 256 + (c - 256)];
    } else if (i < 1408) {
        int c = i - 1024;
        biasPost[c] = (c < 128) ? bcb1[c] : ((c < 256) ? 0.f : cpb1[c - 256]);
    }
}

// ============ node init ============
__global__ void k_node_init(const float* __restrict__ x, const int* __restrict__ pv_tab,
                            const float* __restrict__ vl_tab,
                            int* __restrict__ types, int* __restrict__ pvarr,
                            int* __restrict__ degree, float* __restrict__ vl_out)
{
    int i = blockIdx.x * blockDim.x + threadIdx.x;
    if (i >= N_NODES) return;
    int t = (int)x[i * 16];
    t = min(max(t, 0), 10);
    types[i] = t;
    pvarr[i] = pv_tab[t];
    degree[i] = 0;
    float4 v0 = *(const float4*)&vl_tab[t * 8];
    float4 v1 = *(const float4*)&vl_tab[t * 8 + 4];
    *(float4*)&vl_out[i * 8]     = v0;
    *(float4*)&vl_out[i * 8 + 4] = v1;
}

__global__ void k_edge_deg(const int* __restrict__ ei, int* __restrict__ degree)
{
    int e = blockIdx.x * blockDim.x + threadIdx.x;
    if (e >= N_EDGES) return;
    atomicAdd(&degree[ei[e]], 1);
}

// ============ scan ============
#define SCAN_B 1024
__global__ void k_scan1(const int* __restrict__ degree, int* __restrict__ part, int* __restrict__ bsum)
{
    __shared__ int s[SCAN_B];
    int tid = threadIdx.x;
    int i = blockIdx.x * SCAN_B + tid;
    int v = (i < N_NODES) ? degree[i] : 0;
    s[tid] = v; __syncthreads();
    for (int off = 1; off < SCAN_B; off <<= 1) {
        int t = (tid >= off) ? s[tid - off] : 0;
        __syncthreads();
        s[tid] += t;
        __syncthreads();
    }
    if (i < N_NODES) part[i] = s[tid] - v;
    if (tid == SCAN_B - 1) bsum[blockIdx.x] = s[tid];
}

__global__ void k_scan2(const int* __restrict__ bsum, int* __restrict__ bbase, int nb)
{
    __shared__ int s[128];
    int tid = threadIdx.x;
    int v = (tid < nb) ? bsum[tid] : 0;
    s[tid] = v; __syncthreads();
    for (int off = 1; off < 128; off <<= 1) {
        int t = (tid >= off) ? s[tid - off] : 0;
        __syncthreads();
        s[tid] += t;
        __syncthreads();
    }
    bbase[tid] = s[tid] - v;
}

__global__ void k_scan3(int* __restrict__ part, const int* __restrict__ bbase, int* __restrict__ cursor)
{
    int i = blockIdx.x * SCAN_B + threadIdx.x;
    if (i >= N_NODES) return;
    int o = part[i] + bbase[blockIdx.x];
    part[i] = o;
    cursor[i] = o;
}

// ============ CSR fill (+ row/eid side arrays for the bond pass) ============
__global__ void k_csr_fill(const int* __restrict__ ei, const float* __restrict__ edge_attr,
                           const int* __restrict__ types, int* __restrict__ cursor,
                           int* __restrict__ csr, int* __restrict__ rowcsr, int* __restrict__ eidarr)
{
    int e = blockIdx.x * blockDim.x + threadIdx.x;
    if (e >= N_EDGES) return;
    int row = ei[e], col = ei[N_EDGES + e];
    int bt = (int)edge_attr[e * 4];
    bt = min(max(bt, 0), 4);
    int pos = atomicAdd(&cursor[row], 1);
    csr[pos] = col | (bt << 20) | (types[col] << 24);
    rowcsr[pos] = row;
    eidarr[pos] = e;
}

// ============ layer-0 aggregation (tables) -> h bf16 ============
__global__ __launch_bounds__(256) void k_agg0(const int* __restrict__ offsets, const int* __restrict__ degree,
                       const int* __restrict__ types,
                       const float* __restrict__ self0_tab, const float* __restrict__ msg0_tab,
                       const int* __restrict__ csr, u16* __restrict__ h)
{
    int wid = threadIdx.x >> 6, lane = threadIdx.x & 63;
    int node = blockIdx.x * 4 + wid;
    if (node >= N_NODES) return;
    int t = types[node];
    float4 acc = *(const float4*)&self0_tab[t * 256 + lane * 4];
    int start = offsets[node], deg = degree[node];
    for (int j = 0; j < deg; ++j) {
        int p = csr[start + j];
        int combo = ((p >> 24) & 0xF) * 5 + ((p >> 20) & 7);
        float4 m = *(const float4*)&msg0_tab[combo * 256 + lane * 4];
        acc.x += m.x; acc.y += m.y; acc.z += m.z; acc.w += m.w;
    }
    ushort4 r;
    r.x = f2bf(fmaxf(acc.x, 0.f)); r.y = f2bf(fmaxf(acc.y, 0.f));
    r.z = f2bf(fmaxf(acc.z, 0.f)); r.w = f2bf(fmaxf(acc.w, 0.f));
    *(ushort4*)&h[(size_t)node * 256 + lane * 4] = r;
}

// ============ layers 1,2 aggregation; final layer fuses damp/viol/h_out ============
__global__ __launch_bounds__(256) void k_agg12(const int* __restrict__ offsets, const int* __restrict__ degree,
                        const u16* __restrict__ hs, const u16* __restrict__ hm,
                        const float* __restrict__ bondtab, const int* __restrict__ csr,
                        u16* __restrict__ h, int final_layer, const int* __restrict__ pvarr,
                        float* __restrict__ h_out, u16* __restrict__ hd_bf, float* __restrict__ viol_out)
{
    int wid = threadIdx.x >> 6, lane = threadIdx.x & 63;
    int node = blockIdx.x * 4 + wid;
    if (node >= N_NODES) return;
    ushort4 s4 = *(const ushort4*)&hs[(size_t)node * 256 + lane * 4];
    float ax = bf2f(s4.x), ay = bf2f(s4.y), az = bf2f(s4.z), aw = bf2f(s4.w);
    int start = offsets[node], deg = degree[node];
    for (int j = 0; j < deg; ++j) {
        int p = csr[start + j];
        int c = p & 0xFFFFF;
        int bt = (p >> 20) & 7;
        ushort4 m4 = *(const ushort4*)&hm[(size_t)c * 256 + lane * 4];
        float4 bb = *(const float4*)&bondtab[bt * 256 + lane * 4];
        ax += fmaxf(bf2f(m4.x) + bb.x, 0.f);
        ay += fmaxf(bf2f(m4.y) + bb.y, 0.f);
        az += fmaxf(bf2f(m4.z) + bb.z, 0.f);
        aw += fmaxf(bf2f(m4.w) + bb.w, 0.f);
    }
    ax = fmaxf(ax, 0.f); ay = fmaxf(ay, 0.f); az = fmaxf(az, 0.f); aw = fmaxf(aw, 0.f);
    if (!final_layer) {
        ushort4 r;
        r.x = f2bf(ax); r.y = f2bf(ay); r.z = f2bf(az); r.w = f2bf(aw);
        *(ushort4*)&h[(size_t)node * 256 + lane * 4] = r;
    } else {
        float viol = fmaxf((float)deg - (float)pvarr[node], 0.f);
        float s = 1.f / (1.f + viol);
        ax *= s; ay *= s; az *= s; aw *= s;
        float4 v = make_float4(ax, ay, az, aw);
        *(float4*)&h_out[(size_t)node * 256 + lane * 4] = v;
        ushort4 r;
        r.x = f2bf(ax); r.y = f2bf(ay); r.z = f2bf(az); r.w = f2bf(aw);
        *(ushort4*)&hd_bf[(size_t)node * 256 + lane * 4] = r;
        if (lane == 0) viol_out[node] = viol;
    }
}

// ================== layer GEMM: round-1 structure + LDS-staged coalesced C-write ==================
// K-loop identical to the measured-best 664µs version (BK=32, 2 barriers/step, GLL staging).
// NEW: epilogue stages C through a 32KB LDS tile so global stores are 16B/lane full-line
// (was 64x 2-byte scattered stores -> 32B segments, the suspected write-BW ceiling).
__global__ __launch_bounds__(256) void k_gemm_dual(
    const u16* __restrict__ A, const u16* __restrict__ Bt,
    const float* __restrict__ bias512,
    u16* __restrict__ Dm, u16* __restrict__ Ds, int M, int MT)
{
    __shared__ u16 S[24576];          // As 8KB | Bs 8KB | Cs 32KB = 48KB
    u16* As = S;
    u16* Bs = S + 4096;
    u16* Cs = S + 8192;
    int b = blockIdx.x;
    int rsub = b & 31;
    int nt = rsub >> 3, m8 = rsub & 7;
    int mt = (b >> 5) * 8 + m8;
    if (mt >= MT) return;
    int bm = mt * 128, bn = nt * 128;

    int t = threadIdx.x;
    int lane = t & 63, w = t >> 6;
    int wm = w & 1, wn = w >> 1;
    f32x4 zero = {0.f, 0.f, 0.f, 0.f};
    f32x4 acc[4][4];
    #pragma unroll
    for (int i = 0; i < 4; ++i)
        #pragma unroll
        for (int j = 0; j < 4; ++j) acc[i][j] = zero;

    int arow = t >> 2, acol = (t & 3) * 8;
    const u16* Ag = A + (size_t)(bm + arow) * 256 + acol;
    const u16* Bg = Bt + (size_t)(bn + arow) * 256 + acol;
    u16* Asp = As + t * 8;
    u16* Bsp = Bs + t * 8;
    int q = lane >> 4, r = lane & 15;

    for (int k0 = 0; k0 < 256; k0 += 32) {
        __syncthreads();
        GLL(Ag + k0,            Asp);
        GLL(Ag + 64 * 256 + k0, Asp + 2048);
        GLL(Bg + k0,            Bsp);
        GLL(Bg + 64 * 256 + k0, Bsp + 2048);
        __syncthreads();
        bf16x8 af[4], bfr[4];
        #pragma unroll
        for (int i = 0; i < 4; ++i)
            af[i] = *(const bf16x8*)&As[(wm * 64 + i * 16 + r) * 32 + q * 8];
        #pragma unroll
        for (int j = 0; j < 4; ++j)
            bfr[j] = *(const bf16x8*)&Bs[(wn * 64 + j * 16 + r) * 32 + q * 8];
        #pragma unroll
        for (int i = 0; i < 4; ++i)
            #pragma unroll
            for (int j = 0; j < 4; ++j)
                acc[i][j] = __builtin_amdgcn_mfma_f32_16x16x32_bf16(af[i], bfr[j], acc[i][j], 0, 0, 0);
    }
    // ---- epilogue: acc -> LDS C-tile (bias fused), then full-line stores ----
    #pragma unroll
    for (int i = 0; i < 4; ++i) {
        int rowl = wm * 64 + i * 16 + q * 4;
        #pragma unroll
        for (int j = 0; j < 4; ++j) {
            int coll = wn * 64 + j * 16 + r;
            float bv = bias512[bn + coll];
            #pragma unroll
            for (int rr = 0; rr < 4; ++rr)
                Cs[(rowl + rr) * 128 + coll] = f2bf(acc[i][j][rr] + bv);
        }
    }
    __syncthreads();
    u16* Dbase = (nt < 2) ? (Dm + bn) : (Ds + (bn - 256));
    int c16 = (t & 15) * 8, rbase = t >> 4;
    #pragma unroll
    for (int g = 0; g < 8; ++g) {
        int rowl = rbase + g * 16;
        int rowg = bm + rowl;
        if (rowg < M) {
            u16x8 v = *(const u16x8*)&Cs[rowl * 128 + c16];
            *(u16x8*)&Dbase[(size_t)rowg * 256 + c16] = v;
        }
    }
}

// ================== post GEMM (N=384): same structure + coalesced epilogue ==================
__global__ __launch_bounds__(256) void k_gemm_post(
    const u16* __restrict__ A, const u16* __restrict__ Bt3,
    const float* __restrict__ biasPost,
    u16* __restrict__ UV, u16* __restrict__ CP1, int M, int MT)
{
    __shared__ u16 S[24576];
    u16* As = S;
    u16* Bs = S + 4096;
    u16* Cs = S + 8192;
    int b = blockIdx.x;
    int rsub = b % 24;
    int nt = rsub >> 3, m8 = rsub & 7;
    int mt = (b / 24) * 8 + m8;
    if (mt >= MT) return;
    int bm = mt * 128, bn = nt * 128;

    int t = threadIdx.x;
    int lane = t & 63, w = t >> 6;
    int wm = w & 1, wn = w >> 1;
    f32x4 zero = {0.f, 0.f, 0.f, 0.f};
    f32x4 acc[4][4];
    #pragma unroll
    for (int i = 0; i < 4; ++i)
        #pragma unroll
        for (int j = 0; j < 4; ++j) acc[i][j] = zero;

    int arow = t >> 2, acol = (t & 3) * 8;
    const u16* Ag = A + (size_t)(bm + arow) * 256 + acol;
    const u16* Bg = Bt3 + (size_t)(bn + arow) * 256 + acol;
    u16* Asp = As + t * 8;
    u16* Bsp = Bs + t * 8;
    int q = lane >> 4, r = lane & 15;

    for (int k0 = 0; k0 < 256; k0 += 32) {
        __syncthreads();
        GLL(Ag + k0,            Asp);
        GLL(Ag + 64 * 256 + k0, Asp + 2048);
        GLL(Bg + k0,            Bsp);
        GLL(Bg + 64 * 256 + k0, Bsp + 2048);
        __syncthreads();
        bf16x8 af[4], bfr[4];
        #pragma unroll
        for (int i = 0; i < 4; ++i)
            af[i] = *(const bf16x8*)&As[(wm * 64 + i * 16 + r) * 32 + q * 8];
        #pragma unroll
        for (int j = 0; j < 4; ++j)
            bfr[j] = *(const bf16x8*)&Bs[(wn * 64 + j * 16 + r) * 32 + q * 8];
        #pragma unroll
        for (int i = 0; i < 4; ++i)
            #pragma unroll
            for (int j = 0; j < 4; ++j)
                acc[i][j] = __builtin_amdgcn_mfma_f32_16x16x32_bf16(af[i], bfr[j], acc[i][j], 0, 0, 0);
    }
    // ---- epilogue: acc -> LDS (bias + relu for cp1 block), full-line stores ----
    #pragma unroll
    for (int i = 0; i < 4; ++i) {
        int rowl = wm * 64 + i * 16 + q * 4;
        #pragma unroll
        for (int j = 0; j < 4; ++j) {
            int coll = wn * 64 + j * 16 + r;
            float bv = biasPost[bn + coll];
            #pragma unroll
            for (int rr = 0; rr < 4; ++rr) {
                float val = acc[i][j][rr] + bv;
                if (nt == 2) val = fmaxf(val, 0.f);
                Cs[(rowl + rr) * 128 + coll] = f2bf(val);
            }
        }
    }
    __syncthreads();
    int c16 = (t & 15) * 8, rbase = t >> 4;
    #pragma unroll
    for (int g = 0; g < 8; ++g) {
        int rowl = rbase + g * 16;
        int rowg = bm + rowl;
        if (rowg < M) {
            u16x8 v = *(const u16x8*)&Cs[rowl * 128 + c16];
            if (nt < 2) *(u16x8*)&UV[(size_t)rowg * 256 + bn + c16] = v;
            else        *(u16x8*)&CP1[(size_t)rowg * 128 + c16] = v;
        }
    }
}

// ================== small K=128 MFMA GEMM (cp2 only) ==================
__global__ __launch_bounds__(256) void k_gemm_k128(
    const u16* __restrict__ A, const u16* __restrict__ Bt,
    const float* __restrict__ bias, float* __restrict__ C,
    int ldc, int M, int N)
{
    __shared__ u16 As[4096];
    __shared__ u16 Bs[4096];
    int t = threadIdx.x;
    int lane = t & 63, w = t >> 6;
    int wm = w & 1, wn = w >> 1;
    int bm = blockIdx.x * 128;
    int arow = t >> 2, acol = (t & 3) * 8;
    int q = lane >> 4, r = lane & 15;
    const u16* Ag = A + (size_t)(bm + arow) * 128 + acol;
    const u16* Bg = Bt + (size_t)arow * 128 + acol;
    f32x4 zero = {0.f, 0.f, 0.f, 0.f};
    f32x4 acc[4][4];
    #pragma unroll
    for (int i = 0; i < 4; ++i)
        #pragma unroll
        for (int j = 0; j < 4; ++j) acc[i][j] = zero;

    for (int kc = 0; kc < 4; ++kc) {
        __syncthreads();
        GLL(Ag + kc * 32,            As + t * 8);
        GLL(Ag + 64 * 128 + kc * 32, As + 2048 + t * 8);
        GLL(Bg + kc * 32,            Bs + t * 8);
        GLL(Bg + 64 * 128 + kc * 32, Bs + 2048 + t * 8);
        __syncthreads();
        bf16x8 af[4], bfr[4];
        #pragma unroll
        for (int i = 0; i < 4; ++i)
            af[i] = *(const bf16x8*)&As[(wm * 64 + i * 16 + r) * 32 + q * 8];
        #pragma unroll
        for (int j = 0; j < 4; ++j)
            bfr[j] = *(const bf16x8*)&Bs[(wn * 64 + j * 16 + r) * 32 + q * 8];
        #pragma unroll
        for (int i = 0; i < 4; ++i)
            #pragma unroll
            for (int j = 0; j < 4; ++j)
                acc[i][j] = __builtin_amdgcn_mfma_f32_16x16x32_bf16(af[i], bfr[j], acc[i][j], 0, 0, 0);
    }
    #pragma unroll
    for (int i = 0; i < 4; ++i) {
        int rowb = bm + wm * 64 + i * 16 + q * 4;
        #pragma unroll
        for (int j = 0; j < 4; ++j) {
            int colg = wn * 64 + j * 16 + r;
            if (colg >= N) continue;
            float bv = bias[colg];
            #pragma unroll
            for (int rr = 0; rr < 4; ++rr) {
                int rowg = rowb + rr;
                if (rowg < M) C[(size_t)rowg * ldc + colg] = acc[i][j][rr] + bv;
            }
        }
    }
}

// ================== fused bond kernel ==================
__global__ __launch_bounds__(256) void k_bond_fused(
    const int* __restrict__ csr, const int* __restrict__ rowcsr, const int* __restrict__ eidarr,
    const int* __restrict__ types, const int* __restrict__ pvarr, const int* __restrict__ pv_tab,
    const u16* __restrict__ uv, const float* __restrict__ bc_w1,
    const u16* __restrict__ BtW2, const float* __restrict__ bc_b2,
    const float* __restrict__ bc_w3, const float* __restrict__ bc_b3,
    float* __restrict__ bl_out)
{
    __shared__ u16 T1s[16384];     // 32 KB: 4 chunks x [128 rows][32 k]; reused as f32 T2 [128][64]
    __shared__ u16 Bs[16384];      // 32 KB: 4 chunks x [128 cols][32 k]
    __shared__ float w5s[128], w6s[128], W3s[256], b2s[64], b3s[4];
    __shared__ int pvts[16];

    int t = threadIdx.x;
    int p0 = blockIdx.x * 128;

    if (t < 128) { w5s[t] = bc_w1[512 * 128 + t]; w6s[t] = bc_w1[513 * 128 + t]; }
    if (t < 256) W3s[t] = bc_w3[t];
    if (t < 64) b2s[t] = bc_b2[t];
    if (t < 4)  b3s[t] = bc_b3[t];
    if (t < 11) pvts[t] = pv_tab[t];
    #pragma unroll
    for (int c = 0; c < 4; ++c) {
        GLL(BtW2 + (size_t)(t >> 2) * 128 + c * 32 + (t & 3) * 8,        Bs + c * 4096 + t * 8);
        GLL(BtW2 + (size_t)(64 + (t >> 2)) * 128 + c * 32 + (t & 3) * 8, Bs + c * 4096 + 2048 + t * 8);
    }

    int l = t >> 1;            // local row 0..127
    int half = t & 1;          // which 64-col half
    int pos = p0 + l;
    int prow = 0, pk = 0;
    if (pos < N_EDGES) { prow = rowcsr[pos]; pk = csr[pos]; }
    int pcol = pk & 0xFFFFF;
    float pvr = (float)pvarr[prow];
    __syncthreads();   // w5s/w6s/pvts ready (pvts must not be read before this barrier)
    float pvc = (float)pvts[(pk >> 24) & 0xF];

    const u16* up = uv + (size_t)prow * 256 + half * 64;
    const u16* vp = uv + (size_t)pcol * 256 + 128 + half * 64;
    #pragma unroll
    for (int j = 0; j < 8; ++j) {
        int c = half * 64 + j * 8;
        ushort4 ua = *(const ushort4*)(up + j * 8);
        ushort4 ub = *(const ushort4*)(up + j * 8 + 4);
        ushort4 va = *(const ushort4*)(vp + j * 8);
        ushort4 vb = *(const ushort4*)(vp + j * 8 + 4);
        int chunk = c >> 5, kk = c & 31;
        u16* dst = T1s + chunk * 4096 + l * 32 + kk;
        dst[0] = f2bf(fmaxf(bf2f(ua.x) + bf2f(va.x) + pvr * w5s[c+0] + pvc * w6s[c+0], 0.f));
        dst[1] = f2bf(fmaxf(bf2f(ua.y) + bf2f(va.y) + pvr * w5s[c+1] + pvc * w6s[c+1], 0.f));
        dst[2] = f2bf(fmaxf(bf2f(ua.z) + bf2f(va.z) + pvr * w5s[c+2] + pvc * w6s[c+2], 0.f));
        dst[3] = f2bf(fmaxf(bf2f(ua.w) + bf2f(va.w) + pvr * w5s[c+3] + pvc * w6s[c+3], 0.f));
        dst[4] = f2bf(fmaxf(bf2f(ub.x) + bf2f(vb.x) + pvr * w5s[c+4] + pvc * w6s[c+4], 0.f));
        dst[5] = f2bf(fmaxf(bf2f(ub.y) + bf2f(vb.y) + pvr * w5s[c+5] + pvc * w6s[c+5], 0.f));
        dst[6] = f2bf(fmaxf(bf2f(ub.z) + bf2f(vb.z) + pvr * w5s[c+6] + pvc * w6s[c+6], 0.f));
        dst[7] = f2bf(fmaxf(bf2f(ub.w) + bf2f(vb.w) + pvr * w5s[c+7] + pvc * w6s[c+7], 0.f));
    }
    __syncthreads();   // T1s + Bs (GLL drained by barrier) ready

    int lane = t & 63, w = t >> 6;
    int wm = w & 1, wn = w >> 1;
    int q = lane >> 4, r = lane & 15;
    f32x4 zero = {0.f, 0.f, 0.f, 0.f};
    f32x4 acc[4][4];
    #pragma unroll
    for (int i = 0; i < 4; ++i)
        #pragma unroll
        for (int j = 0; j < 4; ++j) acc[i][j] = zero;
    #pragma unroll
    for (int c = 0; c < 4; ++c) {
        bf16x8 af[4], bfr[4];
        #pragma unroll
        for (int i = 0; i < 4; ++i)
            af[i] = *(const bf16x8*)&T1s[c * 4096 + (wm * 64 + i * 16 + r) * 32 + q * 8];
        #pragma unroll
        for (int j = 0; j < 4; ++j)
            bfr[j] = *(const bf16x8*)&Bs[c * 4096 + (wn * 64 + j * 16 + r) * 32 + q * 8];
        #pragma unroll
        for (int i = 0; i < 4; ++i)
            #pragma unroll
            for (int j = 0; j < 4; ++j)
                acc[i][j] = __builtin_amdgcn_mfma_f32_16x16x32_bf16(af[i], bfr[j], acc[i][j], 0, 0, 0);
    }
    __syncthreads();   // all T1s reads done; reuse as f32 T2

    float* T2f = (float*)T1s;   // [128][64]
    if (wn == 0) {
        #pragma unroll
        for (int i = 0; i < 4; ++i) {
            int row = wm * 64 + i * 16 + q * 4;
            #pragma unroll
            for (int j = 0; j < 4; ++j) {
                int col = j * 16 + r;
                float bv = b2s[col];
                #pragma unroll
                for (int rr = 0; rr < 4; ++rr)
                    T2f[(row + rr) * 64 + col] = fmaxf(acc[i][j][rr] + bv, 0.f);
            }
        }
    }
    __syncthreads();

    if (t < 128) {
        int pos3 = p0 + t;
        if (pos3 < N_EDGES) {
            float a0 = b3s[0], a1 = b3s[1], a2 = b3s[2], a3 = b3s[3];
            const float* trow = &T2f[t * 64];
            #pragma unroll 8
            for (int kk = 0; kk < 64; ++kk) {
                int k = (kk + t) & 63;           // rotate start: spread banks across lanes
                float tv = trow[k];
                a0 += tv * W3s[k * 4 + 0];
                a1 += tv * W3s[k * 4 + 1];
                a2 += tv * W3s[k * 4 + 2];
                a3 += tv * W3s[k * 4 + 3];
            }
            int prow3 = rowcsr[pos3];
            int pk3 = csr[pos3];
            int tc = (pk3 >> 24) & 0xF;
            int tr = types[prow3];
            int pr = pvarr[prow3];
            int pc = pvts[tc];
            float halogen = (tr == 4 || tr == 5 || tc == 4 || tc == 5) ? 1.f : 0.f;
            float l1 = (pr <= 1 || pc <= 1) ? 1.f : 0.f;
            float l2 = (pr <= 2 || pc <= 2) ? 1.f : 0.f;
            float pen13 = -100.f * halogen - 50.f * l1;
            a1 += pen13;
            a3 += pen13;
            a2 += pen13 - 50.f * l2;
            int eid = eidarr[pos3];
            *(float4*)&bl_out[(size_t)eid * 4] = make_float4(a0, a1, a2, a3);
        }
    }
}

// ================================================================
extern "C" void kernel_launch(void* const* d_in, const int* in_sizes, int n_in,
                              void* d_out, int out_size, void* d_ws, size_t ws_size,
                              hipStream_t stream)
{
    const float* x          = (const float*)d_in[0];
    const float* edge_attr  = (const float*)d_in[1];
    const float* atom_emb   = (const float*)d_in[2];
    const float* bond_emb   = (const float*)d_in[3];
    const float* vp_w1      = (const float*)d_in[4];
    const float* vp_b1      = (const float*)d_in[5];
    const float* vp_w2      = (const float*)d_in[6];
    const float* vp_b2      = (const float*)d_in[7];
    const float* gnn_wself  = (const float*)d_in[8];
    const float* gnn_bself  = (const float*)d_in[9];
    const float* gnn_wmsg   = (const float*)d_in[10];
    const float* gnn_bmsg   = (const float*)d_in[11];
    const float* bc_w1      = (const float*)d_in[12];
    const float* bc_b1      = (const float*)d_in[13];
    const float* bc_w2      = (const float*)d_in[14];
    const float* bc_b2      = (const float*)d_in[15];
    const float* bc_w3      = (const float*)d_in[16];
    const float* bc_b3      = (const float*)d_in[17];
    const float* cp_w1      = (const float*)d_in[18];
    const float* cp_b1      = (const float*)d_in[19];
    const float* cp_w2      = (const float*)d_in[20];
    const float* cp_b2      = (const float*)d_in[21];
    const int*   ei         = (const int*)d_in[22];

    float* out    = (float*)d_out;
    float* h_out  = out + H_OFF;
    float* cp_out = out + CP_OFF;
    float* vl_out = out + VL_OFF;
    float* bl_out = out + BL_OFF;
    float* vi_out = out + VI_OFF;

    // ---- workspace layout ----
    char* base = (char*)d_ws;
    const size_t S = (size_t)M_PAD * 256 * 2;   // 51,249,152 B
    u16* h_bf  = (u16*)(base + 0 * S);           // R0: h ; later uv
    u16* uv_bf = (u16*)(base + 0 * S);
    u16* hm_bf = (u16*)(base + 1 * S);           // R1: hm
    u16* hs_bf = (u16*)(base + 2 * S);           // R2: hs
    u16* hd_bf = (u16*)(base + 3 * S);           // R3: damped h bf16
    u16* cp1_bf= (u16*)(base + 4 * S);           // R4: [M_PAD][128] bf16
    char* w    = base + 4 * S + (size_t)M_PAD * 128 * 2;
    int* degree  = (int*)w; w += (size_t)N_NODES * 4;
    int* offsets = (int*)w; w += (size_t)N_NODES * 4;
    int* cursor  = (int*)w; w += (size_t)N_NODES * 4;
    int* types   = (int*)w; w += (size_t)N_NODES * 4;
    int* pvarr   = (int*)w; w += (size_t)N_NODES * 4;
    int* csr     = (int*)w; w += (size_t)E_PAD * 4;
    int* rowcsr  = (int*)w; w += (size_t)E_PAD * 4;
    int* eidarr  = (int*)w; w += (size_t)E_PAD * 4;
    int* bsum    = (int*)w; w += 4096;
    int* bbase   = (int*)w; w += 4096;
    int* pv_tab  = (int*)w; w += 1024;
    float* vl_tab    = (float*)w; w += 2048;
    float* h0_tab    = (float*)w; w += 11 * 256 * 4;
    float* self0_tab = (float*)w; w += 11 * 256 * 4;
    float* msg0_tab  = (float*)w; w += 55 * 256 * 4;
    float* bondtab   = (float*)w; w += 2 * 5 * 256 * 4;
    u16* BtL1  = (u16*)w; w += 512 * 256 * 2;
    u16* BtL2  = (u16*)w; w += 512 * 256 * 2;
    u16* Bt3   = (u16*)w; w += 384 * 256 * 2;
    u16* BtW2  = (u16*)w; w += 128 * 128 * 2;
    u16* BtCP2 = (u16*)w; w += 128 * 128 * 2;
    float* bias512  = (float*)w; w += 2 * 512 * 4;
    float* biasPost = (float*)w; w += 384 * 4;

    // ---- setup ----
    k_type_mlp<<<1, 256, 0, stream>>>(atom_emb, vp_w1, vp_b1, vp_w2, vp_b2, pv_tab, vl_tab, h0_tab);
    k_tables<<<76, 256, 0, stream>>>(bond_emb, gnn_wself, gnn_bself, gnn_wmsg, gnn_bmsg,
                                     h0_tab, self0_tab, msg0_tab, bondtab);
    k_wtrans<<<1664, 256, 0, stream>>>(gnn_wmsg, gnn_wself, bc_w1, cp_w1, bc_w2, cp_w2,
                                       BtL1, BtL2, Bt3, BtW2, BtCP2);
    k_setup_bias<<<6, 256, 0, stream>>>(gnn_bself, bc_b1, cp_b1, bias512, biasPost);
    k_node_init<<<(N_NODES + 255) / 256, 256, 0, stream>>>(x, pv_tab, vl_tab, types, pvarr, degree, vl_out);
    k_edge_deg<<<(N_EDGES + 255) / 256, 256, 0, stream>>>(ei, degree);
    int nb = (N_NODES + SCAN_B - 1) / SCAN_B;
    k_scan1<<<nb, SCAN_B, 0, stream>>>(degree, offsets, bsum);
    k_scan2<<<1, 128, 0, stream>>>(bsum, bbase, nb);
    k_scan3<<<nb, SCAN_B, 0, stream>>>(offsets, bbase, cursor);
    k_csr_fill<<<(N_EDGES + 255) / 256, 256, 0, stream>>>(ei, edge_attr, types, cursor, csr, rowcsr, eidarr);
    k_agg0<<<N_NODES / 4, 256, 0, stream>>>(offsets, degree, types, self0_tab, msg0_tab, csr, h_bf);

    // ---- GNN layers 1,2 (l=2 fuses damp/viol/h_out) ----
    const int MT = M_PAD / 128;           // 782
    const int QB = (MT + 7) / 8;          // 98
    for (int l = 1; l <= 2; ++l) {
        const u16* BtL = (l == 1) ? BtL1 : BtL2;
        k_gemm_dual<<<QB * 32, 256, 0, stream>>>(h_bf, BtL, bias512 + (size_t)(l - 1) * 512,
                                                 hm_bf, hs_bf, N_NODES, MT);
        k_agg12<<<N_NODES / 4, 256, 0, stream>>>(offsets, degree, hs_bf, hm_bf,
                                                 bondtab + (size_t)(l - 1) * 5 * 256, csr, h_bf,
                                                 (l == 2) ? 1 : 0, pvarr, h_out, hd_bf, vi_out);
    }

    // ---- uv + cp1 fused; then cp2 ----
    k_gemm_post<<<QB * 24, 256, 0, stream>>>(hd_bf, Bt3, biasPost, uv_bf, cp1_bf, N_NODES, MT);
    k_gemm_k128<<<MT, 256, 0, stream>>>(cp1_bf, BtCP2, cp_b2, cp_out, 32, N_NODES, 32);

    // ---- fused bond chain ----
    k_bond_fused<<<E_PAD / 128, 256, 0, stream>>>(csr, rowcsr, eidarr, types, pvarr, pv_tab,
                                                  uv_bf, bc_w1, BtW2, bc_b2, bc_w3, bc_b3, bl_out);
}

// Round 6
// 631.365 us; speedup vs baseline: 1.2119x; 1.0158x over previous
//
#include <hip/hip_runtime.h>

#define N_NODES 100000
#define N_EDGES 300000
#define M_PAD   100096   // 782*128
#define E_PAD   300032   // 2344*128

typedef unsigned short u16;
typedef short bf16x8 __attribute__((ext_vector_type(8)));
typedef float f32x4  __attribute__((ext_vector_type(4)));
typedef unsigned short u16x8 __attribute__((ext_vector_type(8)));

__device__ __forceinline__ float bf2f(u16 u) {
    unsigned x = ((unsigned)u) << 16;
    return __builtin_bit_cast(float, x);
}
__device__ __forceinline__ u16 f2bf(float f) {
    unsigned u = __builtin_bit_cast(unsigned, f);
    unsigned r = (u + 0x7FFF + ((u >> 16) & 1)) >> 16;
    return (u16)r;
}

// ---------------- output layout (floats) ----------------
#define H_OFF   0
#define CP_OFF  25600000
#define VL_OFF  28800000
#define BL_OFF  29600000
#define VI_OFF  30800000

#define GLL(gp, lp) __builtin_amdgcn_global_load_lds( \
    (const __attribute__((address_space(1))) unsigned int*)(gp), \
    (__attribute__((address_space(3))) unsigned int*)(lp), 16, 0, 0)

// ============ per-atom-type valence MLP + h0 rows ============
__global__ void k_type_mlp(const float* __restrict__ atom_emb,
                           const float* __restrict__ vp_w1, const float* __restrict__ vp_b1,
                           const float* __restrict__ vp_w2, const float* __restrict__ vp_b2,
                           int* __restrict__ pv_tab, float* __restrict__ vl_tab,
                           float* __restrict__ h0_tab)
{
    int tid = threadIdx.x;
    for (int i = tid; i < 11 * 256; i += 256) h0_tab[i] = 0.f;
    __syncthreads();
    if (tid < 11) {
        int t = tid;
        const float* ae = atom_emb + t * 64;
        float lg[8];
        #pragma unroll
        for (int c = 0; c < 8; ++c) lg[c] = vp_b2[c];
        for (int j = 0; j < 32; ++j) {
            float z = vp_b1[j];
            for (int d = 0; d < 64; ++d) z += ae[d] * vp_w1[d * 32 + j];
            z = fmaxf(z, 0.f);
            #pragma unroll
            for (int c = 0; c < 8; ++c) lg[c] += z * vp_w2[j * 8 + c];
        }
        int best = 0;
        #pragma unroll
        for (int c = 1; c < 8; ++c) if (lg[c] > lg[best]) best = c;
        pv_tab[t] = best + 1;
        for (int c = 0; c < 8; ++c) vl_tab[t * 8 + c] = lg[c];
        float* h0 = h0_tab + t * 256;
        for (int d = 0; d < 64; ++d) h0[d] = ae[d];
        h0[64 + best] = 1.f;
    }
}

// ============ layer-0 tables + bond tables for layers 1,2 ============
__global__ void k_tables(const float* __restrict__ bond_emb,
                         const float* __restrict__ gnn_wself, const float* __restrict__ gnn_bself,
                         const float* __restrict__ gnn_wmsg, const float* __restrict__ gnn_bmsg,
                         const float* __restrict__ h0_tab,
                         float* __restrict__ self0_tab, float* __restrict__ msg0_tab,
                         float* __restrict__ bondtab)
{
    int b = blockIdx.x, c = threadIdx.x;
    if (b < 11) {
        int t = b;
        const float* h0 = h0_tab + t * 256;
        float acc = gnn_bself[c];
        for (int k = 0; k < 256; ++k) acc += h0[k] * gnn_wself[k * 256 + c];
        self0_tab[t * 256 + c] = acc;
    } else if (b < 66) {
        int idx = b - 11; int t = idx / 5, bb = idx % 5;
        const float* h0 = h0_tab + t * 256;
        float acc = gnn_bmsg[c];
        for (int k = 0; k < 256; ++k) acc += h0[k] * gnn_wmsg[k * 256 + c];
        const float* be = bond_emb + bb * 64;
        for (int k = 0; k < 64; ++k) acc += be[k] * gnn_wmsg[(256 + k) * 256 + c];
        msg0_tab[idx * 256 + c] = fmaxf(acc, 0.f);
    } else {
        int idx = b - 66; int l = idx / 5 + 1, bb = idx % 5;
        const float* w = gnn_wmsg + (size_t)l * 320 * 256;
        const float* be = bond_emb + bb * 64;
        float acc = gnn_bmsg[l * 256 + c];
        for (int k = 0; k < 64; ++k) acc += be[k] * w[(256 + k) * 256 + c];
        bondtab[(l - 1) * 5 * 256 + bb * 256 + c] = acc;
    }
}

// ============ bf16-transposed weight tables ============
__global__ void k_wtrans(const float* __restrict__ wmsg, const float* __restrict__ wself,
                         const float* __restrict__ bcw1, const float* __restrict__ cpw1,
                         const float* __restrict__ bcw2, const float* __restrict__ cpw2,
                         u16* __restrict__ BtL1, u16* __restrict__ BtL2, u16* __restrict__ Bt3,
                         u16* __restrict__ BtW2, u16* __restrict__ BtCP2)
{
    int b = blockIdx.x, k = threadIdx.x;
    if (b < 512) {
        int n = b;
        float v = (n < 256) ? wmsg[(size_t)1 * 320 * 256 + (size_t)k * 256 + n]
                            : wself[(size_t)1 * 256 * 256 + (size_t)k * 256 + (n - 256)];
        BtL1[n * 256 + k] = f2bf(v);
    } else if (b < 1024) {
        int n = b - 512;
        float v = (n < 256) ? wmsg[(size_t)2 * 320 * 256 + (size_t)k * 256 + n]
                            : wself[(size_t)2 * 256 * 256 + (size_t)k * 256 + (n - 256)];
        BtL2[n * 256 + k] = f2bf(v);
    } else if (b < 1408) {
        int n = b - 1024;
        float v;
        if (n < 128)      v = bcw1[k * 128 + n];
        else if (n < 256) v = bcw1[(256 + k) * 128 + (n - 128)];
        else              v = cpw1[k * 128 + (n - 256)];
        Bt3[n * 256 + k] = f2bf(v);
    } else if (b < 1536) {
        int n = b - 1408;
        if (k < 128) BtW2[n * 128 + k] = f2bf(n < 64 ? bcw2[k * 64 + n] : 0.f);
    } else {
        int n = b - 1536;
        if (k < 128) BtCP2[n * 128 + k] = f2bf(n < 32 ? cpw2[k * 32 + n] : 0.f);
    }
}

__global__ void k_setup_bias(const float* __restrict__ bself, const float* __restrict__ bcb1,
                             const float* __restrict__ cpb1,
                             float* __restrict__ bias512, float* __restrict__ biasPost)
{
    int i = blockIdx.x * 256 + threadIdx.x;
    if (i < 1024) {
        int l = i >> 9, c = i & 511;
        bias512[l * 512 + c] = (c < 256) ? 0.f : bself[(l + 1) * 256 + (c - 256)];
    } else if (i < 1408) {
        int c = i - 1024;
        biasPost[c] = (c < 128) ? bcb1[c] : ((c < 256) ? 0.f : cpb1[c - 256]);
    }
}

// ============ node init ============
__global__ void k_node_init(const float* __restrict__ x, const int* __restrict__ pv_tab,
                            const float* __restrict__ vl_tab,
                            int* __restrict__ types, int* __restrict__ pvarr,
                            int* __restrict__ degree, float* __restrict__ vl_out)
{
    int i = blockIdx.x * blockDim.x + threadIdx.x;
    if (i >= N_NODES) return;
    int t = (int)x[i * 16];
    t = min(max(t, 0), 10);
    types[i] = t;
    pvarr[i] = pv_tab[t];
    degree[i] = 0;
    float4 v0 = *(const float4*)&vl_tab[t * 8];
    float4 v1 = *(const float4*)&vl_tab[t * 8 + 4];
    *(float4*)&vl_out[i * 8]     = v0;
    *(float4*)&vl_out[i * 8 + 4] = v1;
}

__global__ void k_edge_deg(const int* __restrict__ ei, int* __restrict__ degree)
{
    int e = blockIdx.x * blockDim.x + threadIdx.x;
    if (e >= N_EDGES) return;
    atomicAdd(&degree[ei[e]], 1);
}

// ============ scan ============
#define SCAN_B 1024
__global__ void k_scan1(const int* __restrict__ degree, int* __restrict__ part, int* __restrict__ bsum)
{
    __shared__ int s[SCAN_B];
    int tid = threadIdx.x;
    int i = blockIdx.x * SCAN_B + tid;
    int v = (i < N_NODES) ? degree[i] : 0;
    s[tid] = v; __syncthreads();
    for (int off = 1; off < SCAN_B; off <<= 1) {
        int t = (tid >= off) ? s[tid - off] : 0;
        __syncthreads();
        s[tid] += t;
        __syncthreads();
    }
    if (i < N_NODES) part[i] = s[tid] - v;
    if (tid == SCAN_B - 1) bsum[blockIdx.x] = s[tid];
}

__global__ void k_scan2(const int* __restrict__ bsum, int* __restrict__ bbase, int nb)
{
    __shared__ int s[128];
    int tid = threadIdx.x;
    int v = (tid < nb) ? bsum[tid] : 0;
    s[tid] = v; __syncthreads();
    for (int off = 1; off < 128; off <<= 1) {
        int t = (tid >= off) ? s[tid - off] : 0;
        __syncthreads();
        s[tid] += t;
        __syncthreads();
    }
    bbase[tid] = s[tid] - v;
}

__global__ void k_scan3(int* __restrict__ part, const int* __restrict__ bbase, int* __restrict__ cursor)
{
    int i = blockIdx.x * SCAN_B + threadIdx.x;
    if (i >= N_NODES) return;
    int o = part[i] + bbase[blockIdx.x];
    part[i] = o;
    cursor[i] = o;
}

// ============ CSR fill (+ row/eid side arrays for the bond pass) ============
__global__ void k_csr_fill(const int* __restrict__ ei, const float* __restrict__ edge_attr,
                           const int* __restrict__ types, int* __restrict__ cursor,
                           int* __restrict__ csr, int* __restrict__ rowcsr, int* __restrict__ eidarr)
{
    int e = blockIdx.x * blockDim.x + threadIdx.x;
    if (e >= N_EDGES) return;
    int row = ei[e], col = ei[N_EDGES + e];
    int bt = (int)edge_attr[e * 4];
    bt = min(max(bt, 0), 4);
    int pos = atomicAdd(&cursor[row], 1);
    csr[pos] = col | (bt << 20) | (types[col] << 24);
    rowcsr[pos] = row;
    eidarr[pos] = e;
}

// ============ layer-0 aggregation (tables) -> h bf16 ============
__global__ __launch_bounds__(256) void k_agg0(const int* __restrict__ offsets, const int* __restrict__ degree,
                       const int* __restrict__ types,
                       const float* __restrict__ self0_tab, const float* __restrict__ msg0_tab,
                       const int* __restrict__ csr, u16* __restrict__ h)
{
    int wid = threadIdx.x >> 6, lane = threadIdx.x & 63;
    int node = blockIdx.x * 4 + wid;
    if (node >= N_NODES) return;
    int t = types[node];
    float4 acc = *(const float4*)&self0_tab[t * 256 + lane * 4];
    int start = offsets[node], deg = degree[node];
    for (int j = 0; j < deg; ++j) {
        int p = csr[start + j];
        int combo = ((p >> 24) & 0xF) * 5 + ((p >> 20) & 7);
        float4 m = *(const float4*)&msg0_tab[combo * 256 + lane * 4];
        acc.x += m.x; acc.y += m.y; acc.z += m.z; acc.w += m.w;
    }
    ushort4 r;
    r.x = f2bf(fmaxf(acc.x, 0.f)); r.y = f2bf(fmaxf(acc.y, 0.f));
    r.z = f2bf(fmaxf(acc.z, 0.f)); r.w = f2bf(fmaxf(acc.w, 0.f));
    *(ushort4*)&h[(size_t)node * 256 + lane * 4] = r;
}

// ============ layers 1,2 aggregation; final layer fuses damp/viol/h_out ============
__global__ __launch_bounds__(256) void k_agg12(const int* __restrict__ offsets, const int* __restrict__ degree,
                        const u16* __restrict__ hs, const u16* __restrict__ hm,
                        const float* __restrict__ bondtab, const int* __restrict__ csr,
                        u16* __restrict__ h, int final_layer, const int* __restrict__ pvarr,
                        float* __restrict__ h_out, u16* __restrict__ hd_bf, float* __restrict__ viol_out)
{
    int wid = threadIdx.x >> 6, lane = threadIdx.x & 63;
    int node = blockIdx.x * 4 + wid;
    if (node >= N_NODES) return;
    ushort4 s4 = *(const ushort4*)&hs[(size_t)node * 256 + lane * 4];
    float ax = bf2f(s4.x), ay = bf2f(s4.y), az = bf2f(s4.z), aw = bf2f(s4.w);
    int start = offsets[node], deg = degree[node];
    for (int j = 0; j < deg; ++j) {
        int p = csr[start + j];
        int c = p & 0xFFFFF;
        int bt = (p >> 20) & 7;
        ushort4 m4 = *(const ushort4*)&hm[(size_t)c * 256 + lane * 4];
        float4 bb = *(const float4*)&bondtab[bt * 256 + lane * 4];
        ax += fmaxf(bf2f(m4.x) + bb.x, 0.f);
        ay += fmaxf(bf2f(m4.y) + bb.y, 0.f);
        az += fmaxf(bf2f(m4.z) + bb.z, 0.f);
        aw += fmaxf(bf2f(m4.w) + bb.w, 0.f);
    }
    ax = fmaxf(ax, 0.f); ay = fmaxf(ay, 0.f); az = fmaxf(az, 0.f); aw = fmaxf(aw, 0.f);
    if (!final_layer) {
        ushort4 r;
        r.x = f2bf(ax); r.y = f2bf(ay); r.z = f2bf(az); r.w = f2bf(aw);
        *(ushort4*)&h[(size_t)node * 256 + lane * 4] = r;
    } else {
        float viol = fmaxf((float)deg - (float)pvarr[node], 0.f);
        float s = 1.f / (1.f + viol);
        ax *= s; ay *= s; az *= s; aw *= s;
        float4 v = make_float4(ax, ay, az, aw);
        *(float4*)&h_out[(size_t)node * 256 + lane * 4] = v;
        ushort4 r;
        r.x = f2bf(ax); r.y = f2bf(ay); r.z = f2bf(az); r.w = f2bf(aw);
        *(ushort4*)&hd_bf[(size_t)node * 256 + lane * 4] = r;
        if (lane == 0) viol_out[node] = viol;
    }
}

// ================== layer GEMM: double-buffered GLL (T3-min) + coalesced C epilogue ==================
// Per k-step: ds_read(cur buf) -> issue GLL(next buf) -> 16 MFMA -> ONE barrier.
// Next-tile loads fly during MFMA; barrier drain only waits the残り latency.
// LDS 32KB total: {As0,Bs0,As1,Bs1} during K-loop, reused as Cs[128][128] in epilogue.
__global__ __launch_bounds__(256) void k_gemm_dual(
    const u16* __restrict__ A, const u16* __restrict__ Bt,
    const float* __restrict__ bias512,
    u16* __restrict__ Dm, u16* __restrict__ Ds, int M, int MT)
{
    __shared__ u16 S[16384];          // 32 KB
    u16* As0 = S;
    u16* Bs0 = S + 4096;
    u16* As1 = S + 8192;
    u16* Bs1 = S + 12288;
    u16* Cs  = S;                     // epilogue reuse [128][128]
    int b = blockIdx.x;
    int rsub = b & 31;
    int nt = rsub >> 3, m8 = rsub & 7;
    int mt = (b >> 5) * 8 + m8;
    if (mt >= MT) return;
    int bm = mt * 128, bn = nt * 128;

    int t = threadIdx.x;
    int lane = t & 63, w = t >> 6;
    int wm = w & 1, wn = w >> 1;
    f32x4 zero = {0.f, 0.f, 0.f, 0.f};
    f32x4 acc[4][4];
    #pragma unroll
    for (int i = 0; i < 4; ++i)
        #pragma unroll
        for (int j = 0; j < 4; ++j) acc[i][j] = zero;

    int arow = t >> 2, acol = (t & 3) * 8;
    const u16* Ag = A + (size_t)(bm + arow) * 256 + acol;
    const u16* Bg = Bt + (size_t)(bn + arow) * 256 + acol;
    int q = lane >> 4, r = lane & 15;

    // prologue: stage k-step 0 into buf0
    GLL(Ag,            As0 + t * 8);
    GLL(Ag + 64 * 256, As0 + 2048 + t * 8);
    GLL(Bg,            Bs0 + t * 8);
    GLL(Bg + 64 * 256, Bs0 + 2048 + t * 8);
    __syncthreads();

    #pragma unroll
    for (int ks = 0; ks < 8; ++ks) {
        u16* cA = (ks & 1) ? As1 : As0;
        u16* cB = (ks & 1) ? Bs1 : Bs0;
        // ds_read current fragments FIRST (no outstanding vmcnt dependence)
        bf16x8 af[4], bfr[4];
        #pragma unroll
        for (int i = 0; i < 4; ++i)
            af[i] = *(const bf16x8*)&cA[(wm * 64 + i * 16 + r) * 32 + q * 8];
        #pragma unroll
        for (int j = 0; j < 4; ++j)
            bfr[j] = *(const bf16x8*)&cB[(wn * 64 + j * 16 + r) * 32 + q * 8];
        // issue next-tile loads (overlap with MFMA below; drained by the barrier)
        if (ks < 7) {
            u16* nA = (ks & 1) ? As0 : As1;
            u16* nB = (ks & 1) ? Bs0 : Bs1;
            int k0 = (ks + 1) * 32;
            GLL(Ag + k0,            nA + t * 8);
            GLL(Ag + 64 * 256 + k0, nA + 2048 + t * 8);
            GLL(Bg + k0,            nB + t * 8);
            GLL(Bg + 64 * 256 + k0, nB + 2048 + t * 8);
        }
        #pragma unroll
        for (int i = 0; i < 4; ++i)
            #pragma unroll
            for (int j = 0; j < 4; ++j)
                acc[i][j] = __builtin_amdgcn_mfma_f32_16x16x32_bf16(af[i], bfr[j], acc[i][j], 0, 0, 0);
        __syncthreads();
    }

    // ---- epilogue: acc -> LDS C-tile (bias fused), then full-line stores ----
    #pragma unroll
    for (int i = 0; i < 4; ++i) {
        int rowl = wm * 64 + i * 16 + q * 4;
        #pragma unroll
        for (int j = 0; j < 4; ++j) {
            int coll = wn * 64 + j * 16 + r;
            float bv = bias512[bn + coll];
            #pragma unroll
            for (int rr = 0; rr < 4; ++rr)
                Cs[(rowl + rr) * 128 + coll] = f2bf(acc[i][j][rr] + bv);
        }
    }
    __syncthreads();
    u16* Dbase = (nt < 2) ? (Dm + bn) : (Ds + (bn - 256));
    int c16 = (t & 15) * 8, rbase = t >> 4;
    #pragma unroll
    for (int g = 0; g < 8; ++g) {
        int rowl = rbase + g * 16;
        int rowg = bm + rowl;
        if (rowg < M) {
            u16x8 v = *(const u16x8*)&Cs[rowl * 128 + c16];
            *(u16x8*)&Dbase[(size_t)rowg * 256 + c16] = v;
        }
    }
}

// ================== post GEMM (N=384): same dbuf structure ==================
__global__ __launch_bounds__(256) void k_gemm_post(
    const u16* __restrict__ A, const u16* __restrict__ Bt3,
    const float* __restrict__ biasPost,
    u16* __restrict__ UV, u16* __restrict__ CP1, int M, int MT)
{
    __shared__ u16 S[16384];
    u16* As0 = S;
    u16* Bs0 = S + 4096;
    u16* As1 = S + 8192;
    u16* Bs1 = S + 12288;
    u16* Cs  = S;
    int b = blockIdx.x;
    int rsub = b % 24;
    int nt = rsub >> 3, m8 = rsub & 7;
    int mt = (b / 24) * 8 + m8;
    if (mt >= MT) return;
    int bm = mt * 128, bn = nt * 128;

    int t = threadIdx.x;
    int lane = t & 63, w = t >> 6;
    int wm = w & 1, wn = w >> 1;
    f32x4 zero = {0.f, 0.f, 0.f, 0.f};
    f32x4 acc[4][4];
    #pragma unroll
    for (int i = 0; i < 4; ++i)
        #pragma unroll
        for (int j = 0; j < 4; ++j) acc[i][j] = zero;

    int arow = t >> 2, acol = (t & 3) * 8;
    const u16* Ag = A + (size_t)(bm + arow) * 256 + acol;
    const u16* Bg = Bt3 + (size_t)(bn + arow) * 256 + acol;
    int q = lane >> 4, r = lane & 15;

    GLL(Ag,            As0 + t * 8);
    GLL(Ag + 64 * 256, As0 + 2048 + t * 8);
    GLL(Bg,            Bs0 + t * 8);
    GLL(Bg + 64 * 256, Bs0 + 2048 + t * 8);
    __syncthreads();

    #pragma unroll
    for (int ks = 0; ks < 8; ++ks) {
        u16* cA = (ks & 1) ? As1 : As0;
        u16* cB = (ks & 1) ? Bs1 : Bs0;
        bf16x8 af[4], bfr[4];
        #pragma unroll
        for (int i = 0; i < 4; ++i)
            af[i] = *(const bf16x8*)&cA[(wm * 64 + i * 16 + r) * 32 + q * 8];
        #pragma unroll
        for (int j = 0; j < 4; ++j)
            bfr[j] = *(const bf16x8*)&cB[(wn * 64 + j * 16 + r) * 32 + q * 8];
        if (ks < 7) {
            u16* nA = (ks & 1) ? As0 : As1;
            u16* nB = (ks & 1) ? Bs0 : Bs1;
            int k0 = (ks + 1) * 32;
            GLL(Ag + k0,            nA + t * 8);
            GLL(Ag + 64 * 256 + k0, nA + 2048 + t * 8);
            GLL(Bg + k0,            nB + t * 8);
            GLL(Bg + 64 * 256 + k0, nB + 2048 + t * 8);
        }
        #pragma unroll
        for (int i = 0; i < 4; ++i)
            #pragma unroll
            for (int j = 0; j < 4; ++j)
                acc[i][j] = __builtin_amdgcn_mfma_f32_16x16x32_bf16(af[i], bfr[j], acc[i][j], 0, 0, 0);
        __syncthreads();
    }

    // ---- epilogue: acc -> LDS (bias + relu for cp1 block), full-line stores ----
    #pragma unroll
    for (int i = 0; i < 4; ++i) {
        int rowl = wm * 64 + i * 16 + q * 4;
        #pragma unroll
        for (int j = 0; j < 4; ++j) {
            int coll = wn * 64 + j * 16 + r;
            float bv = biasPost[bn + coll];
            #pragma unroll
            for (int rr = 0; rr < 4; ++rr) {
                float val = acc[i][j][rr] + bv;
                if (nt == 2) val = fmaxf(val, 0.f);
                Cs[(rowl + rr) * 128 + coll] = f2bf(val);
            }
        }
    }
    __syncthreads();
    int c16 = (t & 15) * 8, rbase = t >> 4;
    #pragma unroll
    for (int g = 0; g < 8; ++g) {
        int rowl = rbase + g * 16;
        int rowg = bm + rowl;
        if (rowg < M) {
            u16x8 v = *(const u16x8*)&Cs[rowl * 128 + c16];
            if (nt < 2) *(u16x8*)&UV[(size_t)rowg * 256 + bn + c16] = v;
            else        *(u16x8*)&CP1[(size_t)rowg * 128 + c16] = v;
        }
    }
}

// ================== small K=128 MFMA GEMM (cp2 only) ==================
__global__ __launch_bounds__(256) void k_gemm_k128(
    const u16* __restrict__ A, const u16* __restrict__ Bt,
    const float* __restrict__ bias, float* __restrict__ C,
    int ldc, int M, int N)
{
    __shared__ u16 As[4096];
    __shared__ u16 Bs[4096];
    int t = threadIdx.x;
    int lane = t & 63, w = t >> 6;
    int wm = w & 1, wn = w >> 1;
    int bm = blockIdx.x * 128;
    int arow = t >> 2, acol = (t & 3) * 8;
    int q = lane >> 4, r = lane & 15;
    const u16* Ag = A + (size_t)(bm + arow) * 128 + acol;
    const u16* Bg = Bt + (size_t)arow * 128 + acol;
    f32x4 zero = {0.f, 0.f, 0.f, 0.f};
    f32x4 acc[4][4];
    #pragma unroll
    for (int i = 0; i < 4; ++i)
        #pragma unroll
        for (int j = 0; j < 4; ++j) acc[i][j] = zero;

    for (int kc = 0; kc < 4; ++kc) {
        __syncthreads();
        GLL(Ag + kc * 32,            As + t * 8);
        GLL(Ag + 64 * 128 + kc * 32, As + 2048 + t * 8);
        GLL(Bg + kc * 32,            Bs + t * 8);
        GLL(Bg + 64 * 128 + kc * 32, Bs + 2048 + t * 8);
        __syncthreads();
        bf16x8 af[4], bfr[4];
        #pragma unroll
        for (int i = 0; i < 4; ++i)
            af[i] = *(const bf16x8*)&As[(wm * 64 + i * 16 + r) * 32 + q * 8];
        #pragma unroll
        for (int j = 0; j < 4; ++j)
            bfr[j] = *(const bf16x8*)&Bs[(wn * 64 + j * 16 + r) * 32 + q * 8];
        #pragma unroll
        for (int i = 0; i < 4; ++i)
            #pragma unroll
            for (int j = 0; j < 4; ++j)
                acc[i][j] = __builtin_amdgcn_mfma_f32_16x16x32_bf16(af[i], bfr[j], acc[i][j], 0, 0, 0);
    }
    #pragma unroll
    for (int i = 0; i < 4; ++i) {
        int rowb = bm + wm * 64 + i * 16 + q * 4;
        #pragma unroll
        for (int j = 0; j < 4; ++j) {
            int colg = wn * 64 + j * 16 + r;
            if (colg >= N) continue;
            float bv = bias[colg];
            #pragma unroll
            for (int rr = 0; rr < 4; ++rr) {
                int rowg = rowb + rr;
                if (rowg < M) C[(size_t)rowg * ldc + colg] = acc[i][j][rr] + bv;
            }
        }
    }
}

// ================== fused bond kernel ==================
__global__ __launch_bounds__(256) void k_bond_fused(
    const int* __restrict__ csr, const int* __restrict__ rowcsr, const int* __restrict__ eidarr,
    const int* __restrict__ types, const int* __restrict__ pvarr, const int* __restrict__ pv_tab,
    const u16* __restrict__ uv, const float* __restrict__ bc_w1,
    const u16* __restrict__ BtW2, const float* __restrict__ bc_b2,
    const float* __restrict__ bc_w3, const float* __restrict__ bc_b3,
    float* __restrict__ bl_out)
{
    __shared__ u16 T1s[16384];     // 32 KB: 4 chunks x [128 rows][32 k]; reused as f32 T2 [128][64]
    __shared__ u16 Bs[16384];      // 32 KB: 4 chunks x [128 cols][32 k]
    __shared__ float w5s[128], w6s[128], W3s[256], b2s[64], b3s[4];
    __shared__ int pvts[16];

    int t = threadIdx.x;
    int p0 = blockIdx.x * 128;

    if (t < 128) { w5s[t] = bc_w1[512 * 128 + t]; w6s[t] = bc_w1[513 * 128 + t]; }
    if (t < 256) W3s[t] = bc_w3[t];
    if (t < 64) b2s[t] = bc_b2[t];
    if (t < 4)  b3s[t] = bc_b3[t];
    if (t < 11) pvts[t] = pv_tab[t];
    #pragma unroll
    for (int c = 0; c < 4; ++c) {
        GLL(BtW2 + (size_t)(t >> 2) * 128 + c * 32 + (t & 3) * 8,        Bs + c * 4096 + t * 8);
        GLL(BtW2 + (size_t)(64 + (t >> 2)) * 128 + c * 32 + (t & 3) * 8, Bs + c * 4096 + 2048 + t * 8);
    }

    int l = t >> 1;            // local row 0..127
    int half = t & 1;          // which 64-col half
    int pos = p0 + l;
    int prow = 0, pk = 0;
    if (pos < N_EDGES) { prow = rowcsr[pos]; pk = csr[pos]; }
    int pcol = pk & 0xFFFFF;
    float pvr = (float)pvarr[prow];
    __syncthreads();   // w5s/w6s/pvts ready (pvts must not be read before this barrier)
    float pvc = (float)pvts[(pk >> 24) & 0xF];

    const u16* up = uv + (size_t)prow * 256 + half * 64;
    const u16* vp = uv + (size_t)pcol * 256 + 128 + half * 64;
    #pragma unroll
    for (int j = 0; j < 8; ++j) {
        int c = half * 64 + j * 8;
        ushort4 ua = *(const ushort4*)(up + j * 8);
        ushort4 ub = *(const ushort4*)(up + j * 8 + 4);
        ushort4 va = *(const ushort4*)(vp + j * 8);
        ushort4 vb = *(const ushort4*)(vp + j * 8 + 4);
        int chunk = c >> 5, kk = c & 31;
        u16* dst = T1s + chunk * 4096 + l * 32 + kk;
        dst[0] = f2bf(fmaxf(bf2f(ua.x) + bf2f(va.x) + pvr * w5s[c+0] + pvc * w6s[c+0], 0.f));
        dst[1] = f2bf(fmaxf(bf2f(ua.y) + bf2f(va.y) + pvr * w5s[c+1] + pvc * w6s[c+1], 0.f));
        dst[2] = f2bf(fmaxf(bf2f(ua.z) + bf2f(va.z) + pvr * w5s[c+2] + pvc * w6s[c+2], 0.f));
        dst[3] = f2bf(fmaxf(bf2f(ua.w) + bf2f(va.w) + pvr * w5s[c+3] + pvc * w6s[c+3], 0.f));
        dst[4] = f2bf(fmaxf(bf2f(ub.x) + bf2f(vb.x) + pvr * w5s[c+4] + pvc * w6s[c+4], 0.f));
        dst[5] = f2bf(fmaxf(bf2f(ub.y) + bf2f(vb.y) + pvr * w5s[c+5] + pvc * w6s[c+5], 0.f));
        dst[6] = f2bf(fmaxf(bf2f(ub.z) + bf2f(vb.z) + pvr * w5s[c+6] + pvc * w6s[c+6], 0.f));
        dst[7] = f2bf(fmaxf(bf2f(ub.w) + bf2f(vb.w) + pvr * w5s[c+7] + pvc * w6s[c+7], 0.f));
    }
    __syncthreads();   // T1s + Bs (GLL drained by barrier) ready

    int lane = t & 63, w = t >> 6;
    int wm = w & 1, wn = w >> 1;
    int q = lane >> 4, r = lane & 15;
    f32x4 zero = {0.f, 0.f, 0.f, 0.f};
    f32x4 acc[4][4];
    #pragma unroll
    for (int i = 0; i < 4; ++i)
        #pragma unroll
        for (int j = 0; j < 4; ++j) acc[i][j] = zero;
    #pragma unroll
    for (int c = 0; c < 4; ++c) {
        bf16x8 af[4], bfr[4];
        #pragma unroll
        for (int i = 0; i < 4; ++i)
            af[i] = *(const bf16x8*)&T1s[c * 4096 + (wm * 64 + i * 16 + r) * 32 + q * 8];
        #pragma unroll
        for (int j = 0; j < 4; ++j)
            bfr[j] = *(const bf16x8*)&Bs[c * 4096 + (wn * 64 + j * 16 + r) * 32 + q * 8];
        #pragma unroll
        for (int i = 0; i < 4; ++i)
            #pragma unroll
            for (int j = 0; j < 4; ++j)
                acc[i][j] = __builtin_amdgcn_mfma_f32_16x16x32_bf16(af[i], bfr[j], acc[i][j], 0, 0, 0);
    }
    __syncthreads();   // all T1s reads done; reuse as f32 T2

    float* T2f = (float*)T1s;   // [128][64]
    if (wn == 0) {
        #pragma unroll
        for (int i = 0; i < 4; ++i) {
            int row = wm * 64 + i * 16 + q * 4;
            #pragma unroll
            for (int j = 0; j < 4; ++j) {
                int col = j * 16 + r;
                float bv = b2s[col];
                #pragma unroll
                for (int rr = 0; rr < 4; ++rr)
                    T2f[(row + rr) * 64 + col] = fmaxf(acc[i][j][rr] + bv, 0.f);
            }
        }
    }
    __syncthreads();

    if (t < 128) {
        int pos3 = p0 + t;
        if (pos3 < N_EDGES) {
            float a0 = b3s[0], a1 = b3s[1], a2 = b3s[2], a3 = b3s[3];
            const float* trow = &T2f[t * 64];
            #pragma unroll 8
            for (int kk = 0; kk < 64; ++kk) {
                int k = (kk + t) & 63;           // rotate start: spread banks across lanes
                float tv = trow[k];
                a0 += tv * W3s[k * 4 + 0];
                a1 += tv * W3s[k * 4 + 1];
                a2 += tv * W3s[k * 4 + 2];
                a3 += tv * W3s[k * 4 + 3];
            }
            int prow3 = rowcsr[pos3];
            int pk3 = csr[pos3];
            int tc = (pk3 >> 24) & 0xF;
            int tr = types[prow3];
            int pr = pvarr[prow3];
            int pc = pvts[tc];
            float halogen = (tr == 4 || tr == 5 || tc == 4 || tc == 5) ? 1.f : 0.f;
            float l1 = (pr <= 1 || pc <= 1) ? 1.f : 0.f;
            float l2 = (pr <= 2 || pc <= 2) ? 1.f : 0.f;
            float pen13 = -100.f * halogen - 50.f * l1;
            a1 += pen13;
            a3 += pen13;
            a2 += pen13 - 50.f * l2;
            int eid = eidarr[pos3];
            *(float4*)&bl_out[(size_t)eid * 4] = make_float4(a0, a1, a2, a3);
        }
    }
}

// ================================================================
extern "C" void kernel_launch(void* const* d_in, const int* in_sizes, int n_in,
                              void* d_out, int out_size, void* d_ws, size_t ws_size,
                              hipStream_t stream)
{
    const float* x          = (const float*)d_in[0];
    const float* edge_attr  = (const float*)d_in[1];
    const float* atom_emb   = (const float*)d_in[2];
    const float* bond_emb   = (const float*)d_in[3];
    const float* vp_w1      = (const float*)d_in[4];
    const float* vp_b1      = (const float*)d_in[5];
    const float* vp_w2      = (const float*)d_in[6];
    const float* vp_b2      = (const float*)d_in[7];
    const float* gnn_wself  = (const float*)d_in[8];
    const float* gnn_bself  = (const float*)d_in[9];
    const float* gnn_wmsg   = (const float*)d_in[10];
    const float* gnn_bmsg   = (const float*)d_in[11];
    const float* bc_w1      = (const float*)d_in[12];
    const float* bc_b1      = (const float*)d_in[13];
    const float* bc_w2      = (const float*)d_in[14];
    const float* bc_b2      = (const float*)d_in[15];
    const float* bc_w3      = (const float*)d_in[16];
    const float* bc_b3      = (const float*)d_in[17];
    const float* cp_w1      = (const float*)d_in[18];
    const float* cp_b1      = (const float*)d_in[19];
    const float* cp_w2      = (const float*)d_in[20];
    const float* cp_b2      = (const float*)d_in[21];
    const int*   ei         = (const int*)d_in[22];

    float* out    = (float*)d_out;
    float* h_out  = out + H_OFF;
    float* cp_out = out + CP_OFF;
    float* vl_out = out + VL_OFF;
    float* bl_out = out + BL_OFF;
    float* vi_out = out + VI_OFF;

    // ---- workspace layout ----
    char* base = (char*)d_ws;
    const size_t S = (size_t)M_PAD * 256 * 2;   // 51,249,152 B
    u16* h_bf  = (u16*)(base + 0 * S);           // R0: h ; later uv
    u16* uv_bf = (u16*)(base + 0 * S);
    u16* hm_bf = (u16*)(base + 1 * S);           // R1: hm
    u16* hs_bf = (u16*)(base + 2 * S);           // R2: hs
    u16* hd_bf = (u16*)(base + 3 * S);           // R3: damped h bf16
    u16* cp1_bf= (u16*)(base + 4 * S);           // R4: [M_PAD][128] bf16
    char* w    = base + 4 * S + (size_t)M_PAD * 128 * 2;
    int* degree  = (int*)w; w += (size_t)N_NODES * 4;
    int* offsets = (int*)w; w += (size_t)N_NODES * 4;
    int* cursor  = (int*)w; w += (size_t)N_NODES * 4;
    int* types   = (int*)w; w += (size_t)N_NODES * 4;
    int* pvarr   = (int*)w; w += (size_t)N_NODES * 4;
    int* csr     = (int*)w; w += (size_t)E_PAD * 4;
    int* rowcsr  = (int*)w; w += (size_t)E_PAD * 4;
    int* eidarr  = (int*)w; w += (size_t)E_PAD * 4;
    int* bsum    = (int*)w; w += 4096;
    int* bbase   = (int*)w; w += 4096;
    int* pv_tab  = (int*)w; w += 1024;
    float* vl_tab    = (float*)w; w += 2048;
    float* h0_tab    = (float*)w; w += 11 * 256 * 4;
    float* self0_tab = (float*)w; w += 11 * 256 * 4;
    float* msg0_tab  = (float*)w; w += 55 * 256 * 4;
    float* bondtab   = (float*)w; w += 2 * 5 * 256 * 4;
    u16* BtL1  = (u16*)w; w += 512 * 256 * 2;
    u16* BtL2  = (u16*)w; w += 512 * 256 * 2;
    u16* Bt3   = (u16*)w; w += 384 * 256 * 2;
    u16* BtW2  = (u16*)w; w += 128 * 128 * 2;
    u16* BtCP2 = (u16*)w; w += 128 * 128 * 2;
    float* bias512  = (float*)w; w += 2 * 512 * 4;
    float* biasPost = (float*)w; w += 384 * 4;

    // ---- setup ----
    k_type_mlp<<<1, 256, 0, stream>>>(atom_emb, vp_w1, vp_b1, vp_w2, vp_b2, pv_tab, vl_tab, h0_tab);
    k_tables<<<76, 256, 0, stream>>>(bond_emb, gnn_wself, gnn_bself, gnn_wmsg, gnn_bmsg,
                                     h0_tab, self0_tab, msg0_tab, bondtab);
    k_wtrans<<<1664, 256, 0, stream>>>(gnn_wmsg, gnn_wself, bc_w1, cp_w1, bc_w2, cp_w2,
                                       BtL1, BtL2, Bt3, BtW2, BtCP2);
    k_setup_bias<<<6, 256, 0, stream>>>(gnn_bself, bc_b1, cp_b1, bias512, biasPost);
    k_node_init<<<(N_NODES + 255) / 256, 256, 0, stream>>>(x, pv_tab, vl_tab, types, pvarr, degree, vl_out);
    k_edge_deg<<<(N_EDGES + 255) / 256, 256, 0, stream>>>(ei, degree);
    int nb = (N_NODES + SCAN_B - 1) / SCAN_B;
    k_scan1<<<nb, SCAN_B, 0, stream>>>(degree, offsets, bsum);
    k_scan2<<<1, 128, 0, stream>>>(bsum, bbase, nb);
    k_scan3<<<nb, SCAN_B, 0, stream>>>(offsets, bbase, cursor);
    k_csr_fill<<<(N_EDGES + 255) / 256, 256, 0, stream>>>(ei, edge_attr, types, cursor, csr, rowcsr, eidarr);
    k_agg0<<<N_NODES / 4, 256, 0, stream>>>(offsets, degree, types, self0_tab, msg0_tab, csr, h_bf);

    // ---- GNN layers 1,2 (l=2 fuses damp/viol/h_out) ----
    const int MT = M_PAD / 128;           // 782
    const int QB = (MT + 7) / 8;          // 98
    for (int l = 1; l <= 2; ++l) {
        const u16* BtL = (l == 1) ? BtL1 : BtL2;
        k_gemm_dual<<<QB * 32, 256, 0, stream>>>(h_bf, BtL, bias512 + (size_t)(l - 1) * 512,
                                                 hm_bf, hs_bf, N_NODES, MT);
        k_agg12<<<N_NODES / 4, 256, 0, stream>>>(offsets, degree, hs_bf, hm_bf,
                                                 bondtab + (size_t)(l - 1) * 5 * 256, csr, h_bf,
                                                 (l == 2) ? 1 : 0, pvarr, h_out, hd_bf, vi_out);
    }

    // ---- uv + cp1 fused; then cp2 ----
    k_gemm_post<<<QB * 24, 256, 0, stream>>>(hd_bf, Bt3, biasPost, uv_bf, cp1_bf, N_NODES, MT);
    k_gemm_k128<<<MT, 256, 0, stream>>>(cp1_bf, BtCP2, cp_b2, cp_out, 32, N_NODES, 32);

    // ---- fused bond chain ----
    k_bond_fused<<<E_PAD / 128, 256, 0, stream>>>(csr, rowcsr, eidarr, types, pvarr, pv_tab,
                                                  uv_bf, bc_w1, BtW2, bc_b2, bc_w3, bc_b3, bl_out);
}

// Round 7
// 610.878 us; speedup vs baseline: 1.2525x; 1.0335x over previous
//
#include <hip/hip_runtime.h>

#define N_NODES 100000
#define N_EDGES 300000
#define M_PAD   100096   // 782*128
#define E_PAD   300032   // 2344*128

typedef unsigned short u16;
typedef short bf16x8 __attribute__((ext_vector_type(8)));
typedef float f32x4  __attribute__((ext_vector_type(4)));
typedef unsigned short u16x8 __attribute__((ext_vector_type(8)));

__device__ __forceinline__ float bf2f(u16 u) {
    unsigned x = ((unsigned)u) << 16;
    return __builtin_bit_cast(float, x);
}
__device__ __forceinline__ u16 f2bf(float f) {
    unsigned u = __builtin_bit_cast(unsigned, f);
    unsigned r = (u + 0x7FFF + ((u >> 16) & 1)) >> 16;
    return (u16)r;
}

// ---------------- output layout (floats) ----------------
#define H_OFF   0
#define CP_OFF  25600000
#define VL_OFF  28800000
#define BL_OFF  29600000
#define VI_OFF  30800000

#define GLL(gp, lp) __builtin_amdgcn_global_load_lds( \
    (const __attribute__((address_space(1))) unsigned int*)(gp), \
    (__attribute__((address_space(3))) unsigned int*)(lp), 16, 0, 0)

// ============ per-atom-type valence MLP + h0 rows ============
__global__ void k_type_mlp(const float* __restrict__ atom_emb,
                           const float* __restrict__ vp_w1, const float* __restrict__ vp_b1,
                           const float* __restrict__ vp_w2, const float* __restrict__ vp_b2,
                           int* __restrict__ pv_tab, float* __restrict__ vl_tab,
                           float* __restrict__ h0_tab)
{
    int tid = threadIdx.x;
    for (int i = tid; i < 11 * 256; i += 256) h0_tab[i] = 0.f;
    __syncthreads();
    if (tid < 11) {
        int t = tid;
        const float* ae = atom_emb + t * 64;
        float lg[8];
        #pragma unroll
        for (int c = 0; c < 8; ++c) lg[c] = vp_b2[c];
        for (int j = 0; j < 32; ++j) {
            float z = vp_b1[j];
            for (int d = 0; d < 64; ++d) z += ae[d] * vp_w1[d * 32 + j];
            z = fmaxf(z, 0.f);
            #pragma unroll
            for (int c = 0; c < 8; ++c) lg[c] += z * vp_w2[j * 8 + c];
        }
        int best = 0;
        #pragma unroll
        for (int c = 1; c < 8; ++c) if (lg[c] > lg[best]) best = c;
        pv_tab[t] = best + 1;
        for (int c = 0; c < 8; ++c) vl_tab[t * 8 + c] = lg[c];
        float* h0 = h0_tab + t * 256;
        for (int d = 0; d < 64; ++d) h0[d] = ae[d];
        h0[64 + best] = 1.f;
    }
}

// ============ layer-0 tables + bond tables for layers 1,2 ============
__global__ void k_tables(const float* __restrict__ bond_emb,
                         const float* __restrict__ gnn_wself, const float* __restrict__ gnn_bself,
                         const float* __restrict__ gnn_wmsg, const float* __restrict__ gnn_bmsg,
                         const float* __restrict__ h0_tab,
                         float* __restrict__ self0_tab, float* __restrict__ msg0_tab,
                         float* __restrict__ bondtab)
{
    int b = blockIdx.x, c = threadIdx.x;
    if (b < 11) {
        int t = b;
        const float* h0 = h0_tab + t * 256;
        float acc = gnn_bself[c];
        for (int k = 0; k < 256; ++k) acc += h0[k] * gnn_wself[k * 256 + c];
        self0_tab[t * 256 + c] = acc;
    } else if (b < 66) {
        int idx = b - 11; int t = idx / 5, bb = idx % 5;
        const float* h0 = h0_tab + t * 256;
        float acc = gnn_bmsg[c];
        for (int k = 0; k < 256; ++k) acc += h0[k] * gnn_wmsg[k * 256 + c];
        const float* be = bond_emb + bb * 64;
        for (int k = 0; k < 64; ++k) acc += be[k] * gnn_wmsg[(256 + k) * 256 + c];
        msg0_tab[idx * 256 + c] = fmaxf(acc, 0.f);
    } else {
        int idx = b - 66; int l = idx / 5 + 1, bb = idx % 5;
        const float* w = gnn_wmsg + (size_t)l * 320 * 256;
        const float* be = bond_emb + bb * 64;
        float acc = gnn_bmsg[l * 256 + c];
        for (int k = 0; k < 64; ++k) acc += be[k] * w[(256 + k) * 256 + c];
        bondtab[(l - 1) * 5 * 256 + bb * 256 + c] = acc;
    }
}

// ============ bf16-transposed weight tables ============
__global__ void k_wtrans(const float* __restrict__ wmsg, const float* __restrict__ wself,
                         const float* __restrict__ bcw1, const float* __restrict__ cpw1,
                         const float* __restrict__ bcw2, const float* __restrict__ cpw2,
                         u16* __restrict__ BtL1, u16* __restrict__ BtL2, u16* __restrict__ Bt3,
                         u16* __restrict__ BtW2, u16* __restrict__ BtCP2)
{
    int b = blockIdx.x, k = threadIdx.x;
    if (b < 512) {
        int n = b;
        float v = (n < 256) ? wmsg[(size_t)1 * 320 * 256 + (size_t)k * 256 + n]
                            : wself[(size_t)1 * 256 * 256 + (size_t)k * 256 + (n - 256)];
        BtL1[n * 256 + k] = f2bf(v);
    } else if (b < 1024) {
        int n = b - 512;
        float v = (n < 256) ? wmsg[(size_t)2 * 320 * 256 + (size_t)k * 256 + n]
                            : wself[(size_t)2 * 256 * 256 + (size_t)k * 256 + (n - 256)];
        BtL2[n * 256 + k] = f2bf(v);
    } else if (b < 1408) {
        int n = b - 1024;
        float v;
        if (n < 128)      v = bcw1[k * 128 + n];
        else if (n < 256) v = bcw1[(256 + k) * 128 + (n - 128)];
        else              v = cpw1[k * 128 + (n - 256)];
        Bt3[n * 256 + k] = f2bf(v);
    } else if (b < 1536) {
        int n = b - 1408;
        if (k < 128) BtW2[n * 128 + k] = f2bf(n < 64 ? bcw2[k * 64 + n] : 0.f);
    } else {
        int n = b - 1536;
        if (k < 128) BtCP2[n * 128 + k] = f2bf(n < 32 ? cpw2[k * 32 + n] : 0.f);
    }
}

__global__ void k_setup_bias(const float* __restrict__ bself, const float* __restrict__ bcb1,
                             const float* __restrict__ cpb1,
                             float* __restrict__ bias512, float* __restrict__ biasPost)
{
    int i = blockIdx.x * 256 + threadIdx.x;
    if (i < 1024) {
        int l = i >> 9, c = i & 511;
        bias512[l * 512 + c] = (c < 256) ? 0.f : bself[(l + 1) * 256 + (c - 256)];
    } else if (i < 1408) {
        int c = i - 1024;
        biasPost[c] = (c < 128) ? bcb1[c] : ((c < 256) ? 0.f : cpb1[c - 256]);
    }
}

// ============ node init ============
__global__ void k_node_init(const float* __restrict__ x, const int* __restrict__ pv_tab,
                            const float* __restrict__ vl_tab,
                            int* __restrict__ types, int* __restrict__ pvarr,
                            int* __restrict__ degree, float* __restrict__ vl_out)
{
    int i = blockIdx.x * blockDim.x + threadIdx.x;
    if (i >= N_NODES) return;
    int t = (int)x[i * 16];
    t = min(max(t, 0), 10);
    types[i] = t;
    pvarr[i] = pv_tab[t];
    degree[i] = 0;
    float4 v0 = *(const float4*)&vl_tab[t * 8];
    float4 v1 = *(const float4*)&vl_tab[t * 8 + 4];
    *(float4*)&vl_out[i * 8]     = v0;
    *(float4*)&vl_out[i * 8 + 4] = v1;
}

__global__ void k_edge_deg(const int* __restrict__ ei, int* __restrict__ degree)
{
    int e = blockIdx.x * blockDim.x + threadIdx.x;
    if (e >= N_EDGES) return;
    atomicAdd(&degree[ei[e]], 1);
}

// ============ scan ============
#define SCAN_B 1024
__global__ void k_scan1(const int* __restrict__ degree, int* __restrict__ part, int* __restrict__ bsum)
{
    __shared__ int s[SCAN_B];
    int tid = threadIdx.x;
    int i = blockIdx.x * SCAN_B + tid;
    int v = (i < N_NODES) ? degree[i] : 0;
    s[tid] = v; __syncthreads();
    for (int off = 1; off < SCAN_B; off <<= 1) {
        int t = (tid >= off) ? s[tid - off] : 0;
        __syncthreads();
        s[tid] += t;
        __syncthreads();
    }
    if (i < N_NODES) part[i] = s[tid] - v;
    if (tid == SCAN_B - 1) bsum[blockIdx.x] = s[tid];
}

__global__ void k_scan2(const int* __restrict__ bsum, int* __restrict__ bbase, int nb)
{
    __shared__ int s[128];
    int tid = threadIdx.x;
    int v = (tid < nb) ? bsum[tid] : 0;
    s[tid] = v; __syncthreads();
    for (int off = 1; off < 128; off <<= 1) {
        int t = (tid >= off) ? s[tid - off] : 0;
        __syncthreads();
        s[tid] += t;
        __syncthreads();
    }
    bbase[tid] = s[tid] - v;
}

__global__ void k_scan3(int* __restrict__ part, const int* __restrict__ bbase, int* __restrict__ cursor)
{
    int i = blockIdx.x * SCAN_B + threadIdx.x;
    if (i >= N_NODES) return;
    int o = part[i] + bbase[blockIdx.x];
    part[i] = o;
    cursor[i] = o;
}

// ============ CSR fill (+ row/eid side arrays for the bond pass) ============
__global__ void k_csr_fill(const int* __restrict__ ei, const float* __restrict__ edge_attr,
                           const int* __restrict__ types, int* __restrict__ cursor,
                           int* __restrict__ csr, int* __restrict__ rowcsr, int* __restrict__ eidarr)
{
    int e = blockIdx.x * blockDim.x + threadIdx.x;
    if (e >= N_EDGES) return;
    int row = ei[e], col = ei[N_EDGES + e];
    int bt = (int)edge_attr[e * 4];
    bt = min(max(bt, 0), 4);
    int pos = atomicAdd(&cursor[row], 1);
    csr[pos] = col | (bt << 20) | (types[col] << 24);
    rowcsr[pos] = row;
    eidarr[pos] = e;
}

// ============ layer-0 aggregation (tables) -> h bf16 ============
__global__ __launch_bounds__(256) void k_agg0(const int* __restrict__ offsets, const int* __restrict__ degree,
                       const int* __restrict__ types,
                       const float* __restrict__ self0_tab, const float* __restrict__ msg0_tab,
                       const int* __restrict__ csr, u16* __restrict__ h)
{
    int wid = threadIdx.x >> 6, lane = threadIdx.x & 63;
    int node = blockIdx.x * 4 + wid;
    if (node >= N_NODES) return;
    int t = types[node];
    float4 acc = *(const float4*)&self0_tab[t * 256 + lane * 4];
    int start = offsets[node], deg = degree[node];
    for (int j = 0; j < deg; ++j) {
        int p = csr[start + j];
        int combo = ((p >> 24) & 0xF) * 5 + ((p >> 20) & 7);
        float4 m = *(const float4*)&msg0_tab[combo * 256 + lane * 4];
        acc.x += m.x; acc.y += m.y; acc.z += m.z; acc.w += m.w;
    }
    ushort4 r;
    r.x = f2bf(fmaxf(acc.x, 0.f)); r.y = f2bf(fmaxf(acc.y, 0.f));
    r.z = f2bf(fmaxf(acc.z, 0.f)); r.w = f2bf(fmaxf(acc.w, 0.f));
    *(ushort4*)&h[(size_t)node * 256 + lane * 4] = r;
}

// ============ layers 1,2 aggregation; final layer fuses damp/viol/h_out ============
__global__ __launch_bounds__(256) void k_agg12(const int* __restrict__ offsets, const int* __restrict__ degree,
                        const u16* __restrict__ hs, const u16* __restrict__ hm,
                        const float* __restrict__ bondtab, const int* __restrict__ csr,
                        u16* __restrict__ h, int final_layer, const int* __restrict__ pvarr,
                        float* __restrict__ h_out, u16* __restrict__ hd_bf, float* __restrict__ viol_out)
{
    int wid = threadIdx.x >> 6, lane = threadIdx.x & 63;
    int node = blockIdx.x * 4 + wid;
    if (node >= N_NODES) return;
    ushort4 s4 = *(const ushort4*)&hs[(size_t)node * 256 + lane * 4];
    float ax = bf2f(s4.x), ay = bf2f(s4.y), az = bf2f(s4.z), aw = bf2f(s4.w);
    int start = offsets[node], deg = degree[node];
    for (int j = 0; j < deg; ++j) {
        int p = csr[start + j];
        int c = p & 0xFFFFF;
        int bt = (p >> 20) & 7;
        ushort4 m4 = *(const ushort4*)&hm[(size_t)c * 256 + lane * 4];
        float4 bb = *(const float4*)&bondtab[bt * 256 + lane * 4];
        ax += fmaxf(bf2f(m4.x) + bb.x, 0.f);
        ay += fmaxf(bf2f(m4.y) + bb.y, 0.f);
        az += fmaxf(bf2f(m4.z) + bb.z, 0.f);
        aw += fmaxf(bf2f(m4.w) + bb.w, 0.f);
    }
    ax = fmaxf(ax, 0.f); ay = fmaxf(ay, 0.f); az = fmaxf(az, 0.f); aw = fmaxf(aw, 0.f);
    if (!final_layer) {
        ushort4 r;
        r.x = f2bf(ax); r.y = f2bf(ay); r.z = f2bf(az); r.w = f2bf(aw);
        *(ushort4*)&h[(size_t)node * 256 + lane * 4] = r;
    } else {
        float viol = fmaxf((float)deg - (float)pvarr[node], 0.f);
        float s = 1.f / (1.f + viol);
        ax *= s; ay *= s; az *= s; aw *= s;
        float4 v = make_float4(ax, ay, az, aw);
        *(float4*)&h_out[(size_t)node * 256 + lane * 4] = v;
        ushort4 r;
        r.x = f2bf(ax); r.y = f2bf(ay); r.z = f2bf(az); r.w = f2bf(aw);
        *(ushort4*)&hd_bf[(size_t)node * 256 + lane * 4] = r;
        if (lane == 0) viol_out[node] = viol;
    }
}

// ================== layer GEMM: 3-buffer pipeline, counted vmcnt (T4), raw barriers ==================
// Per k-step: issue 4 GLL(next buf) -> s_waitcnt vmcnt(4) [current buf landed; in-order retire]
// -> raw s_barrier (NO vmcnt(0) drain) -> ds_read(cur) -> 16 MFMA. Next-tile loads stay in
// flight across the barrier and MFMA phase. 3-buffer rotation makes one barrier/step safe:
// GLL at step j overwrites the buffer last read at j-2, and the per-step rendezvous guarantees
// those reads retired (each wave's MFMA forced lgkmcnt before it reached the barrier).
// LDS 48KB = 3 x {A 8KB | B 8KB}; epilogue reuses first 32KB as Cs after a full __syncthreads.
__global__ __launch_bounds__(256) void k_gemm_dual(
    const u16* __restrict__ A, const u16* __restrict__ Bt,
    const float* __restrict__ bias512,
    u16* __restrict__ Dm, u16* __restrict__ Ds, int M, int MT)
{
    __shared__ u16 S[24576];          // 48 KB: buf i at S + i*8192 (A) / +4096 (B), i=0..2
    u16* Cs = S;                      // epilogue reuse [128][128]
    int b = blockIdx.x;
    int rsub = b & 31;
    int nt = rsub >> 3, m8 = rsub & 7;
    int mt = (b >> 5) * 8 + m8;
    if (mt >= MT) return;
    int bm = mt * 128, bn = nt * 128;

    int t = threadIdx.x;
    int lane = t & 63, w = t >> 6;
    int wm = w & 1, wn = w >> 1;
    f32x4 zero = {0.f, 0.f, 0.f, 0.f};
    f32x4 acc[4][4];
    #pragma unroll
    for (int i = 0; i < 4; ++i)
        #pragma unroll
        for (int j = 0; j < 4; ++j) acc[i][j] = zero;

    int arow = t >> 2, acol = (t & 3) * 8;
    const u16* Ag = A + (size_t)(bm + arow) * 256 + acol;
    const u16* Bg = Bt + (size_t)(bn + arow) * 256 + acol;
    int q = lane >> 4, r = lane & 15;

    // prologue: stage k-step 0 into buf0 (stays outstanding until first vmcnt)
    GLL(Ag,            S + t * 8);
    GLL(Ag + 64 * 256, S + 2048 + t * 8);
    GLL(Bg,            S + 4096 + t * 8);
    GLL(Bg + 64 * 256, S + 4096 + 2048 + t * 8);

    #pragma unroll
    for (int ks = 0; ks < 8; ++ks) {
        int cb = (ks % 3) * 8192;
        if (ks < 7) {
            int nb = ((ks + 1) % 3) * 8192;
            int k0 = (ks + 1) * 32;
            GLL(Ag + k0,            S + nb + t * 8);
            GLL(Ag + 64 * 256 + k0, S + nb + 2048 + t * 8);
            GLL(Bg + k0,            S + nb + 4096 + t * 8);
            GLL(Bg + 64 * 256 + k0, S + nb + 4096 + 2048 + t * 8);
            asm volatile("s_waitcnt vmcnt(4)" ::: "memory");
        } else {
            asm volatile("s_waitcnt vmcnt(0)" ::: "memory");
        }
        __builtin_amdgcn_s_barrier();
        __builtin_amdgcn_sched_barrier(0);
        bf16x8 af[4], bfr[4];
        #pragma unroll
        for (int i = 0; i < 4; ++i)
            af[i] = *(const bf16x8*)&S[cb + (wm * 64 + i * 16 + r) * 32 + q * 8];
        #pragma unroll
        for (int j = 0; j < 4; ++j)
            bfr[j] = *(const bf16x8*)&S[cb + 4096 + (wn * 64 + j * 16 + r) * 32 + q * 8];
        #pragma unroll
        for (int i = 0; i < 4; ++i)
            #pragma unroll
            for (int j = 0; j < 4; ++j)
                acc[i][j] = __builtin_amdgcn_mfma_f32_16x16x32_bf16(af[i], bfr[j], acc[i][j], 0, 0, 0);
    }
    __syncthreads();   // all last-buffer reads done before Cs overwrite (vmcnt already 0)

    // ---- epilogue: acc -> LDS C-tile (bias fused), then full-line stores ----
    #pragma unroll
    for (int i = 0; i < 4; ++i) {
        int rowl = wm * 64 + i * 16 + q * 4;
        #pragma unroll
        for (int j = 0; j < 4; ++j) {
            int coll = wn * 64 + j * 16 + r;
            float bv = bias512[bn + coll];
            #pragma unroll
            for (int rr = 0; rr < 4; ++rr)
                Cs[(rowl + rr) * 128 + coll] = f2bf(acc[i][j][rr] + bv);
        }
    }
    __syncthreads();
    u16* Dbase = (nt < 2) ? (Dm + bn) : (Ds + (bn - 256));
    int c16 = (t & 15) * 8, rbase = t >> 4;
    #pragma unroll
    for (int g = 0; g < 8; ++g) {
        int rowl = rbase + g * 16;
        int rowg = bm + rowl;
        if (rowg < M) {
            u16x8 v = *(const u16x8*)&Cs[rowl * 128 + c16];
            *(u16x8*)&Dbase[(size_t)rowg * 256 + c16] = v;
        }
    }
}

// ================== post GEMM (N=384): same counted-vmcnt pipeline ==================
__global__ __launch_bounds__(256) void k_gemm_post(
    const u16* __restrict__ A, const u16* __restrict__ Bt3,
    const float* __restrict__ biasPost,
    u16* __restrict__ UV, u16* __restrict__ CP1, int M, int MT)
{
    __shared__ u16 S[24576];
    u16* Cs = S;
    int b = blockIdx.x;
    int rsub = b % 24;
    int nt = rsub >> 3, m8 = rsub & 7;
    int mt = (b / 24) * 8 + m8;
    if (mt >= MT) return;
    int bm = mt * 128, bn = nt * 128;

    int t = threadIdx.x;
    int lane = t & 63, w = t >> 6;
    int wm = w & 1, wn = w >> 1;
    f32x4 zero = {0.f, 0.f, 0.f, 0.f};
    f32x4 acc[4][4];
    #pragma unroll
    for (int i = 0; i < 4; ++i)
        #pragma unroll
        for (int j = 0; j < 4; ++j) acc[i][j] = zero;

    int arow = t >> 2, acol = (t & 3) * 8;
    const u16* Ag = A + (size_t)(bm + arow) * 256 + acol;
    const u16* Bg = Bt3 + (size_t)(bn + arow) * 256 + acol;
    int q = lane >> 4, r = lane & 15;

    GLL(Ag,            S + t * 8);
    GLL(Ag + 64 * 256, S + 2048 + t * 8);
    GLL(Bg,            S + 4096 + t * 8);
    GLL(Bg + 64 * 256, S + 4096 + 2048 + t * 8);

    #pragma unroll
    for (int ks = 0; ks < 8; ++ks) {
        int cb = (ks % 3) * 8192;
        if (ks < 7) {
            int nb = ((ks + 1) % 3) * 8192;
            int k0 = (ks + 1) * 32;
            GLL(Ag + k0,            S + nb + t * 8);
            GLL(Ag + 64 * 256 + k0, S + nb + 2048 + t * 8);
            GLL(Bg + k0,            S + nb + 4096 + t * 8);
            GLL(Bg + 64 * 256 + k0, S + nb + 4096 + 2048 + t * 8);
            asm volatile("s_waitcnt vmcnt(4)" ::: "memory");
        } else {
            asm volatile("s_waitcnt vmcnt(0)" ::: "memory");
        }
        __builtin_amdgcn_s_barrier();
        __builtin_amdgcn_sched_barrier(0);
        bf16x8 af[4], bfr[4];
        #pragma unroll
        for (int i = 0; i < 4; ++i)
            af[i] = *(const bf16x8*)&S[cb + (wm * 64 + i * 16 + r) * 32 + q * 8];
        #pragma unroll
        for (int j = 0; j < 4; ++j)
            bfr[j] = *(const bf16x8*)&S[cb + 4096 + (wn * 64 + j * 16 + r) * 32 + q * 8];
        #pragma unroll
        for (int i = 0; i < 4; ++i)
            #pragma unroll
            for (int j = 0; j < 4; ++j)
                acc[i][j] = __builtin_amdgcn_mfma_f32_16x16x32_bf16(af[i], bfr[j], acc[i][j], 0, 0, 0);
    }
    __syncthreads();

    // ---- epilogue: acc -> LDS (bias + relu for cp1 block), full-line stores ----
    #pragma unroll
    for (int i = 0; i < 4; ++i) {
        int rowl = wm * 64 + i * 16 + q * 4;
        #pragma unroll
        for (int j = 0; j < 4; ++j) {
            int coll = wn * 64 + j * 16 + r;
            float bv = biasPost[bn + coll];
            #pragma unroll
            for (int rr = 0; rr < 4; ++rr) {
                float val = acc[i][j][rr] + bv;
                if (nt == 2) val = fmaxf(val, 0.f);
                Cs[(rowl + rr) * 128 + coll] = f2bf(val);
            }
        }
    }
    __syncthreads();
    int c16 = (t & 15) * 8, rbase = t >> 4;
    #pragma unroll
    for (int g = 0; g < 8; ++g) {
        int rowl = rbase + g * 16;
        int rowg = bm + rowl;
        if (rowg < M) {
            u16x8 v = *(const u16x8*)&Cs[rowl * 128 + c16];
            if (nt < 2) *(u16x8*)&UV[(size_t)rowg * 256 + bn + c16] = v;
            else        *(u16x8*)&CP1[(size_t)rowg * 128 + c16] = v;
        }
    }
}

// ================== small K=128 MFMA GEMM (cp2 only) ==================
__global__ __launch_bounds__(256) void k_gemm_k128(
    const u16* __restrict__ A, const u16* __restrict__ Bt,
    const float* __restrict__ bias, float* __restrict__ C,
    int ldc, int M, int N)
{
    __shared__ u16 As[4096];
    __shared__ u16 Bs[4096];
    int t = threadIdx.x;
    int lane = t & 63, w = t >> 6;
    int wm = w & 1, wn = w >> 1;
    int bm = blockIdx.x * 128;
    int arow = t >> 2, acol = (t & 3) * 8;
    int q = lane >> 4, r = lane & 15;
    const u16* Ag = A + (size_t)(bm + arow) * 128 + acol;
    const u16* Bg = Bt + (size_t)arow * 128 + acol;
    f32x4 zero = {0.f, 0.f, 0.f, 0.f};
    f32x4 acc[4][4];
    #pragma unroll
    for (int i = 0; i < 4; ++i)
        #pragma unroll
        for (int j = 0; j < 4; ++j) acc[i][j] = zero;

    for (int kc = 0; kc < 4; ++kc) {
        __syncthreads();
        GLL(Ag + kc * 32,            As + t * 8);
        GLL(Ag + 64 * 128 + kc * 32, As + 2048 + t * 8);
        GLL(Bg + kc * 32,            Bs + t * 8);
        GLL(Bg + 64 * 128 + kc * 32, Bs + 2048 + t * 8);
        __syncthreads();
        bf16x8 af[4], bfr[4];
        #pragma unroll
        for (int i = 0; i < 4; ++i)
            af[i] = *(const bf16x8*)&As[(wm * 64 + i * 16 + r) * 32 + q * 8];
        #pragma unroll
        for (int j = 0; j < 4; ++j)
            bfr[j] = *(const bf16x8*)&Bs[(wn * 64 + j * 16 + r) * 32 + q * 8];
        #pragma unroll
        for (int i = 0; i < 4; ++i)
            #pragma unroll
            for (int j = 0; j < 4; ++j)
                acc[i][j] = __builtin_amdgcn_mfma_f32_16x16x32_bf16(af[i], bfr[j], acc[i][j], 0, 0, 0);
    }
    #pragma unroll
    for (int i = 0; i < 4; ++i) {
        int rowb = bm + wm * 64 + i * 16 + q * 4;
        #pragma unroll
        for (int j = 0; j < 4; ++j) {
            int colg = wn * 64 + j * 16 + r;
            if (colg >= N) continue;
            float bv = bias[colg];
            #pragma unroll
            for (int rr = 0; rr < 4; ++rr) {
                int rowg = rowb + rr;
                if (rowg < M) C[(size_t)rowg * ldc + colg] = acc[i][j][rr] + bv;
            }
        }
    }
}

// ================== fused bond kernel ==================
__global__ __launch_bounds__(256) void k_bond_fused(
    const int* __restrict__ csr, const int* __restrict__ rowcsr, const int* __restrict__ eidarr,
    const int* __restrict__ types, const int* __restrict__ pvarr, const int* __restrict__ pv_tab,
    const u16* __restrict__ uv, const float* __restrict__ bc_w1,
    const u16* __restrict__ BtW2, const float* __restrict__ bc_b2,
    const float* __restrict__ bc_w3, const float* __restrict__ bc_b3,
    float* __restrict__ bl_out)
{
    __shared__ u16 T1s[16384];     // 32 KB: 4 chunks x [128 rows][32 k]; reused as f32 T2 [128][64]
    __shared__ u16 Bs[16384];      // 32 KB: 4 chunks x [128 cols][32 k]
    __shared__ float w5s[128], w6s[128], W3s[256], b2s[64], b3s[4];
    __shared__ int pvts[16];

    int t = threadIdx.x;
    int p0 = blockIdx.x * 128;

    if (t < 128) { w5s[t] = bc_w1[512 * 128 + t]; w6s[t] = bc_w1[513 * 128 + t]; }
    if (t < 256) W3s[t] = bc_w3[t];
    if (t < 64) b2s[t] = bc_b2[t];
    if (t < 4)  b3s[t] = bc_b3[t];
    if (t < 11) pvts[t] = pv_tab[t];
    #pragma unroll
    for (int c = 0; c < 4; ++c) {
        GLL(BtW2 + (size_t)(t >> 2) * 128 + c * 32 + (t & 3) * 8,        Bs + c * 4096 + t * 8);
        GLL(BtW2 + (size_t)(64 + (t >> 2)) * 128 + c * 32 + (t & 3) * 8, Bs + c * 4096 + 2048 + t * 8);
    }

    int l = t >> 1;            // local row 0..127
    int half = t & 1;          // which 64-col half
    int pos = p0 + l;
    int prow = 0, pk = 0;
    if (pos < N_EDGES) { prow = rowcsr[pos]; pk = csr[pos]; }
    int pcol = pk & 0xFFFFF;
    float pvr = (float)pvarr[prow];
    __syncthreads();   // w5s/w6s/pvts ready (pvts must not be read before this barrier)
    float pvc = (float)pvts[(pk >> 24) & 0xF];

    const u16* up = uv + (size_t)prow * 256 + half * 64;
    const u16* vp = uv + (size_t)pcol * 256 + 128 + half * 64;
    #pragma unroll
    for (int j = 0; j < 8; ++j) {
        int c = half * 64 + j * 8;
        ushort4 ua = *(const ushort4*)(up + j * 8);
        ushort4 ub = *(const ushort4*)(up + j * 8 + 4);
        ushort4 va = *(const ushort4*)(vp + j * 8);
        ushort4 vb = *(const ushort4*)(vp + j * 8 + 4);
        int chunk = c >> 5, kk = c & 31;
        u16* dst = T1s + chunk * 4096 + l * 32 + kk;
        dst[0] = f2bf(fmaxf(bf2f(ua.x) + bf2f(va.x) + pvr * w5s[c+0] + pvc * w6s[c+0], 0.f));
        dst[1] = f2bf(fmaxf(bf2f(ua.y) + bf2f(va.y) + pvr * w5s[c+1] + pvc * w6s[c+1], 0.f));
        dst[2] = f2bf(fmaxf(bf2f(ua.z) + bf2f(va.z) + pvr * w5s[c+2] + pvc * w6s[c+2], 0.f));
        dst[3] = f2bf(fmaxf(bf2f(ua.w) + bf2f(va.w) + pvr * w5s[c+3] + pvc * w6s[c+3], 0.f));
        dst[4] = f2bf(fmaxf(bf2f(ub.x) + bf2f(vb.x) + pvr * w5s[c+4] + pvc * w6s[c+4], 0.f));
        dst[5] = f2bf(fmaxf(bf2f(ub.y) + bf2f(vb.y) + pvr * w5s[c+5] + pvc * w6s[c+5], 0.f));
        dst[6] = f2bf(fmaxf(bf2f(ub.z) + bf2f(vb.z) + pvr * w5s[c+6] + pvc * w6s[c+6], 0.f));
        dst[7] = f2bf(fmaxf(bf2f(ub.w) + bf2f(vb.w) + pvr * w5s[c+7] + pvc * w6s[c+7], 0.f));
    }
    __syncthreads();   // T1s + Bs (GLL drained by barrier) ready

    int lane = t & 63, w = t >> 6;
    int wm = w & 1, wn = w >> 1;
    int q = lane >> 4, r = lane & 15;
    f32x4 zero = {0.f, 0.f, 0.f, 0.f};
    f32x4 acc[4][4];
    #pragma unroll
    for (int i = 0; i < 4; ++i)
        #pragma unroll
        for (int j = 0; j < 4; ++j) acc[i][j] = zero;
    #pragma unroll
    for (int c = 0; c < 4; ++c) {
        bf16x8 af[4], bfr[4];
        #pragma unroll
        for (int i = 0; i < 4; ++i)
            af[i] = *(const bf16x8*)&T1s[c * 4096 + (wm * 64 + i * 16 + r) * 32 + q * 8];
        #pragma unroll
        for (int j = 0; j < 4; ++j)
            bfr[j] = *(const bf16x8*)&Bs[c * 4096 + (wn * 64 + j * 16 + r) * 32 + q * 8];
        #pragma unroll
        for (int i = 0; i < 4; ++i)
            #pragma unroll
            for (int j = 0; j < 4; ++j)
                acc[i][j] = __builtin_amdgcn_mfma_f32_16x16x32_bf16(af[i], bfr[j], acc[i][j], 0, 0, 0);
    }
    __syncthreads();   // all T1s reads done; reuse as f32 T2

    float* T2f = (float*)T1s;   // [128][64]
    if (wn == 0) {
        #pragma unroll
        for (int i = 0; i < 4; ++i) {
            int row = wm * 64 + i * 16 + q * 4;
            #pragma unroll
            for (int j = 0; j < 4; ++j) {
                int col = j * 16 + r;
                float bv = b2s[col];
                #pragma unroll
                for (int rr = 0; rr < 4; ++rr)
                    T2f[(row + rr) * 64 + col] = fmaxf(acc[i][j][rr] + bv, 0.f);
            }
        }
    }
    __syncthreads();

    if (t < 128) {
        int pos3 = p0 + t;
        if (pos3 < N_EDGES) {
            float a0 = b3s[0], a1 = b3s[1], a2 = b3s[2], a3 = b3s[3];
            const float* trow = &T2f[t * 64];
            #pragma unroll 8
            for (int kk = 0; kk < 64; ++kk) {
                int k = (kk + t) & 63;           // rotate start: spread banks across lanes
                float tv = trow[k];
                a0 += tv * W3s[k * 4 + 0];
                a1 += tv * W3s[k * 4 + 1];
                a2 += tv * W3s[k * 4 + 2];
                a3 += tv * W3s[k * 4 + 3];
            }
            int prow3 = rowcsr[pos3];
            int pk3 = csr[pos3];
            int tc = (pk3 >> 24) & 0xF;
            int tr = types[prow3];
            int pr = pvarr[prow3];
            int pc = pvts[tc];
            float halogen = (tr == 4 || tr == 5 || tc == 4 || tc == 5) ? 1.f : 0.f;
            float l1 = (pr <= 1 || pc <= 1) ? 1.f : 0.f;
            float l2 = (pr <= 2 || pc <= 2) ? 1.f : 0.f;
            float pen13 = -100.f * halogen - 50.f * l1;
            a1 += pen13;
            a3 += pen13;
            a2 += pen13 - 50.f * l2;
            int eid = eidarr[pos3];
            *(float4*)&bl_out[(size_t)eid * 4] = make_float4(a0, a1, a2, a3);
        }
    }
}

// ================================================================
extern "C" void kernel_launch(void* const* d_in, const int* in_sizes, int n_in,
                              void* d_out, int out_size, void* d_ws, size_t ws_size,
                              hipStream_t stream)
{
    const float* x          = (const float*)d_in[0];
    const float* edge_attr  = (const float*)d_in[1];
    const float* atom_emb   = (const float*)d_in[2];
    const float* bond_emb   = (const float*)d_in[3];
    const float* vp_w1      = (const float*)d_in[4];
    const float* vp_b1      = (const float*)d_in[5];
    const float* vp_w2      = (const float*)d_in[6];
    const float* vp_b2      = (const float*)d_in[7];
    const float* gnn_wself  = (const float*)d_in[8];
    const float* gnn_bself  = (const float*)d_in[9];
    const float* gnn_wmsg   = (const float*)d_in[10];
    const float* gnn_bmsg   = (const float*)d_in[11];
    const float* bc_w1      = (const float*)d_in[12];
    const float* bc_b1      = (const float*)d_in[13];
    const float* bc_w2      = (const float*)d_in[14];
    const float* bc_b2      = (const float*)d_in[15];
    const float* bc_w3      = (const float*)d_in[16];
    const float* bc_b3      = (const float*)d_in[17];
    const float* cp_w1      = (const float*)d_in[18];
    const float* cp_b1      = (const float*)d_in[19];
    const float* cp_w2      = (const float*)d_in[20];
    const float* cp_b2      = (const float*)d_in[21];
    const int*   ei         = (const int*)d_in[22];

    float* out    = (float*)d_out;
    float* h_out  = out + H_OFF;
    float* cp_out = out + CP_OFF;
    float* vl_out = out + VL_OFF;
    float* bl_out = out + BL_OFF;
    float* vi_out = out + VI_OFF;

    // ---- workspace layout ----
    char* base = (char*)d_ws;
    const size_t S = (size_t)M_PAD * 256 * 2;   // 51,249,152 B
    u16* h_bf  = (u16*)(base + 0 * S);           // R0: h ; later uv
    u16* uv_bf = (u16*)(base + 0 * S);
    u16* hm_bf = (u16*)(base + 1 * S);           // R1: hm
    u16* hs_bf = (u16*)(base + 2 * S);           // R2: hs
    u16* hd_bf = (u16*)(base + 3 * S);           // R3: damped h bf16
    u16* cp1_bf= (u16*)(base + 4 * S);           // R4: [M_PAD][128] bf16
    char* w    = base + 4 * S + (size_t)M_PAD * 128 * 2;
    int* degree  = (int*)w; w += (size_t)N_NODES * 4;
    int* offsets = (int*)w; w += (size_t)N_NODES * 4;
    int* cursor  = (int*)w; w += (size_t)N_NODES * 4;
    int* types   = (int*)w; w += (size_t)N_NODES * 4;
    int* pvarr   = (int*)w; w += (size_t)N_NODES * 4;
    int* csr     = (int*)w; w += (size_t)E_PAD * 4;
    int* rowcsr  = (int*)w; w += (size_t)E_PAD * 4;
    int* eidarr  = (int*)w; w += (size_t)E_PAD * 4;
    int* bsum    = (int*)w; w += 4096;
    int* bbase   = (int*)w; w += 4096;
    int* pv_tab  = (int*)w; w += 1024;
    float* vl_tab    = (float*)w; w += 2048;
    float* h0_tab    = (float*)w; w += 11 * 256 * 4;
    float* self0_tab = (float*)w; w += 11 * 256 * 4;
    float* msg0_tab  = (float*)w; w += 55 * 256 * 4;
    float* bondtab   = (float*)w; w += 2 * 5 * 256 * 4;
    u16* BtL1  = (u16*)w; w += 512 * 256 * 2;
    u16* BtL2  = (u16*)w; w += 512 * 256 * 2;
    u16* Bt3   = (u16*)w; w += 384 * 256 * 2;
    u16* BtW2  = (u16*)w; w += 128 * 128 * 2;
    u16* BtCP2 = (u16*)w; w += 128 * 128 * 2;
    float* bias512  = (float*)w; w += 2 * 512 * 4;
    float* biasPost = (float*)w; w += 384 * 4;

    // ---- setup ----
    k_type_mlp<<<1, 256, 0, stream>>>(atom_emb, vp_w1, vp_b1, vp_w2, vp_b2, pv_tab, vl_tab, h0_tab);
    k_tables<<<76, 256, 0, stream>>>(bond_emb, gnn_wself, gnn_bself, gnn_wmsg, gnn_bmsg,
                                     h0_tab, self0_tab, msg0_tab, bondtab);
    k_wtrans<<<1664, 256, 0, stream>>>(gnn_wmsg, gnn_wself, bc_w1, cp_w1, bc_w2, cp_w2,
                                       BtL1, BtL2, Bt3, BtW2, BtCP2);
    k_setup_bias<<<6, 256, 0, stream>>>(gnn_bself, bc_b1, cp_b1, bias512, biasPost);
    k_node_init<<<(N_NODES + 255) / 256, 256, 0, stream>>>(x, pv_tab, vl_tab, types, pvarr, degree, vl_out);
    k_edge_deg<<<(N_EDGES + 255) / 256, 256, 0, stream>>>(ei, degree);
    int nb = (N_NODES + SCAN_B - 1) / SCAN_B;
    k_scan1<<<nb, SCAN_B, 0, stream>>>(degree, offsets, bsum);
    k_scan2<<<1, 128, 0, stream>>>(bsum, bbase, nb);
    k_scan3<<<nb, SCAN_B, 0, stream>>>(offsets, bbase, cursor);
    k_csr_fill<<<(N_EDGES + 255) / 256, 256, 0, stream>>>(ei, edge_attr, types, cursor, csr, rowcsr, eidarr);
    k_agg0<<<N_NODES / 4, 256, 0, stream>>>(offsets, degree, types, self0_tab, msg0_tab, csr, h_bf);

    // ---- GNN layers 1,2 (l=2 fuses damp/viol/h_out) ----
    const int MT = M_PAD / 128;           // 782
    const int QB = (MT + 7) / 8;          // 98
    for (int l = 1; l <= 2; ++l) {
        const u16* BtL = (l == 1) ? BtL1 : BtL2;
        k_gemm_dual<<<QB * 32, 256, 0, stream>>>(h_bf, BtL, bias512 + (size_t)(l - 1) * 512,
                                                 hm_bf, hs_bf, N_NODES, MT);
        k_agg12<<<N_NODES / 4, 256, 0, stream>>>(offsets, degree, hs_bf, hm_bf,
                                                 bondtab + (size_t)(l - 1) * 5 * 256, csr, h_bf,
                                                 (l == 2) ? 1 : 0, pvarr, h_out, hd_bf, vi_out);
    }

    // ---- uv + cp1 fused; then cp2 ----
    k_gemm_post<<<QB * 24, 256, 0, stream>>>(hd_bf, Bt3, biasPost, uv_bf, cp1_bf, N_NODES, MT);
    k_gemm_k128<<<MT, 256, 0, stream>>>(cp1_bf, BtCP2, cp_b2, cp_out, 32, N_NODES, 32);

    // ---- fused bond chain ----
    k_bond_fused<<<E_PAD / 128, 256, 0, stream>>>(csr, rowcsr, eidarr, types, pvarr, pv_tab,
                                                  uv_bf, bc_w1, BtW2, bc_b2, bc_w3, bc_b3, bl_out);
}

// Round 8
// 607.227 us; speedup vs baseline: 1.2601x; 1.0060x over previous
//
#include <hip/hip_runtime.h>

#define N_NODES 100000
#define N_EDGES 300000
#define M_PAD   100096   // 782*128
#define E_PAD   300032   // 2344*128

typedef unsigned short u16;
typedef short bf16x8 __attribute__((ext_vector_type(8)));
typedef float f32x4  __attribute__((ext_vector_type(4)));
typedef unsigned short u16x8 __attribute__((ext_vector_type(8)));

__device__ __forceinline__ float bf2f(u16 u) {
    unsigned x = ((unsigned)u) << 16;
    return __builtin_bit_cast(float, x);
}
__device__ __forceinline__ u16 f2bf(float f) {
    unsigned u = __builtin_bit_cast(unsigned, f);
    unsigned r = (u + 0x7FFF + ((u >> 16) & 1)) >> 16;
    return (u16)r;
}

// ---------------- output layout (floats) ----------------
#define H_OFF   0
#define CP_OFF  25600000
#define VL_OFF  28800000
#define BL_OFF  29600000
#define VI_OFF  30800000

#define GLL(gp, lp) __builtin_amdgcn_global_load_lds( \
    (const __attribute__((address_space(1))) unsigned int*)(gp), \
    (__attribute__((address_space(3))) unsigned int*)(lp), 16, 0, 0)

// ============ per-atom-type valence MLP + h0 rows ============
__global__ void k_type_mlp(const float* __restrict__ atom_emb,
                           const float* __restrict__ vp_w1, const float* __restrict__ vp_b1,
                           const float* __restrict__ vp_w2, const float* __restrict__ vp_b2,
                           int* __restrict__ pv_tab, float* __restrict__ vl_tab,
                           float* __restrict__ h0_tab)
{
    int tid = threadIdx.x;
    for (int i = tid; i < 11 * 256; i += 256) h0_tab[i] = 0.f;
    __syncthreads();
    if (tid < 11) {
        int t = tid;
        const float* ae = atom_emb + t * 64;
        float lg[8];
        #pragma unroll
        for (int c = 0; c < 8; ++c) lg[c] = vp_b2[c];
        for (int j = 0; j < 32; ++j) {
            float z = vp_b1[j];
            for (int d = 0; d < 64; ++d) z += ae[d] * vp_w1[d * 32 + j];
            z = fmaxf(z, 0.f);
            #pragma unroll
            for (int c = 0; c < 8; ++c) lg[c] += z * vp_w2[j * 8 + c];
        }
        int best = 0;
        #pragma unroll
        for (int c = 1; c < 8; ++c) if (lg[c] > lg[best]) best = c;
        pv_tab[t] = best + 1;
        for (int c = 0; c < 8; ++c) vl_tab[t * 8 + c] = lg[c];
        float* h0 = h0_tab + t * 256;
        for (int d = 0; d < 64; ++d) h0[d] = ae[d];
        h0[64 + best] = 1.f;
    }
}

// ============ layer-0 tables + bond tables for layers 1,2 ============
__global__ void k_tables(const float* __restrict__ bond_emb,
                         const float* __restrict__ gnn_wself, const float* __restrict__ gnn_bself,
                         const float* __restrict__ gnn_wmsg, const float* __restrict__ gnn_bmsg,
                         const float* __restrict__ h0_tab,
                         float* __restrict__ self0_tab, float* __restrict__ msg0_tab,
                         float* __restrict__ bondtab)
{
    int b = blockIdx.x, c = threadIdx.x;
    if (b < 11) {
        int t = b;
        const float* h0 = h0_tab + t * 256;
        float acc = gnn_bself[c];
        for (int k = 0; k < 256; ++k) acc += h0[k] * gnn_wself[k * 256 + c];
        self0_tab[t * 256 + c] = acc;
    } else if (b < 66) {
        int idx = b - 11; int t = idx / 5, bb = idx % 5;
        const float* h0 = h0_tab + t * 256;
        float acc = gnn_bmsg[c];
        for (int k = 0; k < 256; ++k) acc += h0[k] * gnn_wmsg[k * 256 + c];
        const float* be = bond_emb + bb * 64;
        for (int k = 0; k < 64; ++k) acc += be[k] * gnn_wmsg[(256 + k) * 256 + c];
        msg0_tab[idx * 256 + c] = fmaxf(acc, 0.f);
    } else {
        int idx = b - 66; int l = idx / 5 + 1, bb = idx % 5;
        const float* w = gnn_wmsg + (size_t)l * 320 * 256;
        const float* be = bond_emb + bb * 64;
        float acc = gnn_bmsg[l * 256 + c];
        for (int k = 0; k < 64; ++k) acc += be[k] * w[(256 + k) * 256 + c];
        bondtab[(l - 1) * 5 * 256 + bb * 256 + c] = acc;
    }
}

// ============ bf16-transposed weight tables ============
__global__ void k_wtrans(const float* __restrict__ wmsg, const float* __restrict__ wself,
                         const float* __restrict__ bcw1, const float* __restrict__ cpw1,
                         const float* __restrict__ bcw2, const float* __restrict__ cpw2,
                         u16* __restrict__ BtL1, u16* __restrict__ BtL2, u16* __restrict__ Bt3,
                         u16* __restrict__ BtW2, u16* __restrict__ BtCP2)
{
    int b = blockIdx.x, k = threadIdx.x;
    if (b < 512) {
        int n = b;
        float v = (n < 256) ? wmsg[(size_t)1 * 320 * 256 + (size_t)k * 256 + n]
                            : wself[(size_t)1 * 256 * 256 + (size_t)k * 256 + (n - 256)];
        BtL1[n * 256 + k] = f2bf(v);
    } else if (b < 1024) {
        int n = b - 512;
        float v = (n < 256) ? wmsg[(size_t)2 * 320 * 256 + (size_t)k * 256 + n]
                            : wself[(size_t)2 * 256 * 256 + (size_t)k * 256 + (n - 256)];
        BtL2[n * 256 + k] = f2bf(v);
    } else if (b < 1408) {
        int n = b - 1024;
        float v;
        if (n < 128)      v = bcw1[k * 128 + n];
        else if (n < 256) v = bcw1[(256 + k) * 128 + (n - 128)];
        else              v = cpw1[k * 128 + (n - 256)];
        Bt3[n * 256 + k] = f2bf(v);
    } else if (b < 1536) {
        int n = b - 1408;
        if (k < 128) BtW2[n * 128 + k] = f2bf(n < 64 ? bcw2[k * 64 + n] : 0.f);
    } else {
        int n = b - 1536;
        if (k < 128) BtCP2[n * 128 + k] = f2bf(n < 32 ? cpw2[k * 32 + n] : 0.f);
    }
}

__global__ void k_setup_bias(const float* __restrict__ bself, const float* __restrict__ bcb1,
                             const float* __restrict__ cpb1,
                             float* __restrict__ bias512, float* __restrict__ biasPost)
{
    int i = blockIdx.x * 256 + threadIdx.x;
    if (i < 1024) {
        int l = i >> 9, c = i & 511;
        bias512[l * 512 + c] = (c < 256) ? 0.f : bself[(l + 1) * 256 + (c - 256)];
    } else if (i < 1408) {
        int c = i - 1024;
        biasPost[c] = (c < 128) ? bcb1[c] : ((c < 256) ? 0.f : cpb1[c - 256]);
    }
}

// ============ node init ============
__global__ void k_node_init(const float* __restrict__ x, const int* __restrict__ pv_tab,
                            const float* __restrict__ vl_tab,
                            int* __restrict__ types, int* __restrict__ pvarr,
                            int* __restrict__ degree, float* __restrict__ vl_out)
{
    int i = blockIdx.x * blockDim.x + threadIdx.x;
    if (i >= N_NODES) return;
    int t = (int)x[i * 16];
    t = min(max(t, 0), 10);
    types[i] = t;
    pvarr[i] = pv_tab[t];
    degree[i] = 0;
    float4 v0 = *(const float4*)&vl_tab[t * 8];
    float4 v1 = *(const float4*)&vl_tab[t * 8 + 4];
    *(float4*)&vl_out[i * 8]     = v0;
    *(float4*)&vl_out[i * 8 + 4] = v1;
}

__global__ void k_edge_deg(const int* __restrict__ ei, int* __restrict__ degree)
{
    int e = blockIdx.x * blockDim.x + threadIdx.x;
    if (e >= N_EDGES) return;
    atomicAdd(&degree[ei[e]], 1);
}

// ============ scan ============
#define SCAN_B 1024
__global__ void k_scan1(const int* __restrict__ degree, int* __restrict__ part, int* __restrict__ bsum)
{
    __shared__ int s[SCAN_B];
    int tid = threadIdx.x;
    int i = blockIdx.x * SCAN_B + tid;
    int v = (i < N_NODES) ? degree[i] : 0;
    s[tid] = v; __syncthreads();
    for (int off = 1; off < SCAN_B; off <<= 1) {
        int t = (tid >= off) ? s[tid - off] : 0;
        __syncthreads();
        s[tid] += t;
        __syncthreads();
    }
    if (i < N_NODES) part[i] = s[tid] - v;
    if (tid == SCAN_B - 1) bsum[blockIdx.x] = s[tid];
}

__global__ void k_scan2(const int* __restrict__ bsum, int* __restrict__ bbase, int nb)
{
    __shared__ int s[128];
    int tid = threadIdx.x;
    int v = (tid < nb) ? bsum[tid] : 0;
    s[tid] = v; __syncthreads();
    for (int off = 1; off < 128; off <<= 1) {
        int t = (tid >= off) ? s[tid - off] : 0;
        __syncthreads();
        s[tid] += t;
        __syncthreads();
    }
    bbase[tid] = s[tid] - v;
}

__global__ void k_scan3(int* __restrict__ part, const int* __restrict__ bbase, int* __restrict__ cursor)
{
    int i = blockIdx.x * SCAN_B + threadIdx.x;
    if (i >= N_NODES) return;
    int o = part[i] + bbase[blockIdx.x];
    part[i] = o;
    cursor[i] = o;
}

// ============ CSR fill (+ row/eid side arrays for the bond pass) ============
__global__ void k_csr_fill(const int* __restrict__ ei, const float* __restrict__ edge_attr,
                           const int* __restrict__ types, int* __restrict__ cursor,
                           int* __restrict__ csr, int* __restrict__ rowcsr, int* __restrict__ eidarr)
{
    int e = blockIdx.x * blockDim.x + threadIdx.x;
    if (e >= N_EDGES) return;
    int row = ei[e], col = ei[N_EDGES + e];
    int bt = (int)edge_attr[e * 4];
    bt = min(max(bt, 0), 4);
    int pos = atomicAdd(&cursor[row], 1);
    csr[pos] = col | (bt << 20) | (types[col] << 24);
    rowcsr[pos] = row;
    eidarr[pos] = e;
}

// ============ layer-0 aggregation (tables) -> h bf16 ============
__global__ __launch_bounds__(256) void k_agg0(const int* __restrict__ offsets, const int* __restrict__ degree,
                       const int* __restrict__ types,
                       const float* __restrict__ self0_tab, const float* __restrict__ msg0_tab,
                       const int* __restrict__ csr, u16* __restrict__ h)
{
    int wid = threadIdx.x >> 6, lane = threadIdx.x & 63;
    int node = blockIdx.x * 4 + wid;
    if (node >= N_NODES) return;
    int t = types[node];
    float4 acc = *(const float4*)&self0_tab[t * 256 + lane * 4];
    int start = offsets[node], deg = degree[node];
    for (int j = 0; j < deg; ++j) {
        int p = csr[start + j];
        int combo = ((p >> 24) & 0xF) * 5 + ((p >> 20) & 7);
        float4 m = *(const float4*)&msg0_tab[combo * 256 + lane * 4];
        acc.x += m.x; acc.y += m.y; acc.z += m.z; acc.w += m.w;
    }
    ushort4 r;
    r.x = f2bf(fmaxf(acc.x, 0.f)); r.y = f2bf(fmaxf(acc.y, 0.f));
    r.z = f2bf(fmaxf(acc.z, 0.f)); r.w = f2bf(fmaxf(acc.w, 0.f));
    *(ushort4*)&h[(size_t)node * 256 + lane * 4] = r;
}

// ============ layers 1,2 aggregation; final layer fuses damp/viol/h_out ============
__global__ __launch_bounds__(256) void k_agg12(const int* __restrict__ offsets, const int* __restrict__ degree,
                        const u16* __restrict__ hs, const u16* __restrict__ hm,
                        const float* __restrict__ bondtab, const int* __restrict__ csr,
                        u16* __restrict__ h, int final_layer, const int* __restrict__ pvarr,
                        float* __restrict__ h_out, u16* __restrict__ hd_bf, float* __restrict__ viol_out)
{
    int wid = threadIdx.x >> 6, lane = threadIdx.x & 63;
    int node = blockIdx.x * 4 + wid;
    if (node >= N_NODES) return;
    ushort4 s4 = *(const ushort4*)&hs[(size_t)node * 256 + lane * 4];
    float ax = bf2f(s4.x), ay = bf2f(s4.y), az = bf2f(s4.z), aw = bf2f(s4.w);
    int start = offsets[node], deg = degree[node];
    for (int j = 0; j < deg; ++j) {
        int p = csr[start + j];
        int c = p & 0xFFFFF;
        int bt = (p >> 20) & 7;
        ushort4 m4 = *(const ushort4*)&hm[(size_t)c * 256 + lane * 4];
        float4 bb = *(const float4*)&bondtab[bt * 256 + lane * 4];
        ax += fmaxf(bf2f(m4.x) + bb.x, 0.f);
        ay += fmaxf(bf2f(m4.y) + bb.y, 0.f);
        az += fmaxf(bf2f(m4.z) + bb.z, 0.f);
        aw += fmaxf(bf2f(m4.w) + bb.w, 0.f);
    }
    ax = fmaxf(ax, 0.f); ay = fmaxf(ay, 0.f); az = fmaxf(az, 0.f); aw = fmaxf(aw, 0.f);
    if (!final_layer) {
        ushort4 r;
        r.x = f2bf(ax); r.y = f2bf(ay); r.z = f2bf(az); r.w = f2bf(aw);
        *(ushort4*)&h[(size_t)node * 256 + lane * 4] = r;
    } else {
        float viol = fmaxf((float)deg - (float)pvarr[node], 0.f);
        float s = 1.f / (1.f + viol);
        ax *= s; ay *= s; az *= s; aw *= s;
        float4 v = make_float4(ax, ay, az, aw);
        *(float4*)&h_out[(size_t)node * 256 + lane * 4] = v;
        ushort4 r;
        r.x = f2bf(ax); r.y = f2bf(ay); r.z = f2bf(az); r.w = f2bf(aw);
        *(ushort4*)&hd_bf[(size_t)node * 256 + lane * 4] = r;
        if (lane == 0) viol_out[node] = viol;
    }
}

// ================== layer GEMM: 3-buffer 2-DEEP pipeline + counted vmcnt + setprio ==================
// Per k-step: vmcnt(4) [buf(ks) landed; buf(ks+1) still in flight] -> s_barrier ->
// issue GLL(ks+2) into buf(ks+2)%3 -> ds_read(cur) -> setprio(1) 16 MFMA setprio(0).
// Issue-after-barrier makes 2-deep safe with 3 buffers: buf(ks+2)%3 == buf(ks-1)%3, whose
// ds_reads all retired before any wave passed barrier(ks) (MFMA's lgkmcnt forces them).
// vmcnt bookkeeping: outstanding at each wait = {GLL(ks), GLL(ks+1)} -> vmcnt(4) retires GLL(ks).
__global__ __launch_bounds__(256) void k_gemm_dual(
    const u16* __restrict__ A, const u16* __restrict__ Bt,
    const float* __restrict__ bias512,
    u16* __restrict__ Dm, u16* __restrict__ Ds, int M, int MT)
{
    __shared__ u16 S[24576];          // 48 KB: buf i at S + i*8192 (A) / +4096 (B), i=0..2
    u16* Cs = S;                      // epilogue reuse [128][128]
    int b = blockIdx.x;
    int rsub = b & 31;
    int nt = rsub >> 3, m8 = rsub & 7;
    int mt = (b >> 5) * 8 + m8;
    if (mt >= MT) return;
    int bm = mt * 128, bn = nt * 128;

    int t = threadIdx.x;
    int lane = t & 63, w = t >> 6;
    int wm = w & 1, wn = w >> 1;
    f32x4 zero = {0.f, 0.f, 0.f, 0.f};
    f32x4 acc[4][4];
    #pragma unroll
    for (int i = 0; i < 4; ++i)
        #pragma unroll
        for (int j = 0; j < 4; ++j) acc[i][j] = zero;

    int arow = t >> 2, acol = (t & 3) * 8;
    const u16* Ag = A + (size_t)(bm + arow) * 256 + acol;
    const u16* Bg = Bt + (size_t)(bn + arow) * 256 + acol;
    int q = lane >> 4, r = lane & 15;

    // prologue: stage k-steps 0 and 1 (2-deep)
    GLL(Ag,                 S + t * 8);
    GLL(Ag + 64 * 256,      S + 2048 + t * 8);
    GLL(Bg,                 S + 4096 + t * 8);
    GLL(Bg + 64 * 256,      S + 4096 + 2048 + t * 8);
    GLL(Ag + 32,            S + 8192 + t * 8);
    GLL(Ag + 64 * 256 + 32, S + 8192 + 2048 + t * 8);
    GLL(Bg + 32,            S + 8192 + 4096 + t * 8);
    GLL(Bg + 64 * 256 + 32, S + 8192 + 4096 + 2048 + t * 8);

    #pragma unroll
    for (int ks = 0; ks < 8; ++ks) {
        int cb = (ks % 3) * 8192;
        if (ks < 7) {
            asm volatile("s_waitcnt vmcnt(4)" ::: "memory");
        } else {
            asm volatile("s_waitcnt vmcnt(0)" ::: "memory");
        }
        __builtin_amdgcn_s_barrier();
        __builtin_amdgcn_sched_barrier(0);
        if (ks < 6) {
            int nb = ((ks + 2) % 3) * 8192;
            int k0 = (ks + 2) * 32;
            GLL(Ag + k0,            S + nb + t * 8);
            GLL(Ag + 64 * 256 + k0, S + nb + 2048 + t * 8);
            GLL(Bg + k0,            S + nb + 4096 + t * 8);
            GLL(Bg + 64 * 256 + k0, S + nb + 4096 + 2048 + t * 8);
        }
        bf16x8 af[4], bfr[4];
        #pragma unroll
        for (int i = 0; i < 4; ++i)
            af[i] = *(const bf16x8*)&S[cb + (wm * 64 + i * 16 + r) * 32 + q * 8];
        #pragma unroll
        for (int j = 0; j < 4; ++j)
            bfr[j] = *(const bf16x8*)&S[cb + 4096 + (wn * 64 + j * 16 + r) * 32 + q * 8];
        __builtin_amdgcn_s_setprio(1);
        #pragma unroll
        for (int i = 0; i < 4; ++i)
            #pragma unroll
            for (int j = 0; j < 4; ++j)
                acc[i][j] = __builtin_amdgcn_mfma_f32_16x16x32_bf16(af[i], bfr[j], acc[i][j], 0, 0, 0);
        __builtin_amdgcn_s_setprio(0);
    }
    __syncthreads();   // all last-buffer reads done before Cs overwrite (vmcnt already 0)

    // ---- epilogue: acc -> LDS C-tile (bias fused), then full-line stores ----
    #pragma unroll
    for (int i = 0; i < 4; ++i) {
        int rowl = wm * 64 + i * 16 + q * 4;
        #pragma unroll
        for (int j = 0; j < 4; ++j) {
            int coll = wn * 64 + j * 16 + r;
            float bv = bias512[bn + coll];
            #pragma unroll
            for (int rr = 0; rr < 4; ++rr)
                Cs[(rowl + rr) * 128 + coll] = f2bf(acc[i][j][rr] + bv);
        }
    }
    __syncthreads();
    u16* Dbase = (nt < 2) ? (Dm + bn) : (Ds + (bn - 256));
    int c16 = (t & 15) * 8, rbase = t >> 4;
    #pragma unroll
    for (int g = 0; g < 8; ++g) {
        int rowl = rbase + g * 16;
        int rowg = bm + rowl;
        if (rowg < M) {
            u16x8 v = *(const u16x8*)&Cs[rowl * 128 + c16];
            *(u16x8*)&Dbase[(size_t)rowg * 256 + c16] = v;
        }
    }
}

// ================== post GEMM (N=384): same 2-deep pipeline + setprio ==================
__global__ __launch_bounds__(256) void k_gemm_post(
    const u16* __restrict__ A, const u16* __restrict__ Bt3,
    const float* __restrict__ biasPost,
    u16* __restrict__ UV, u16* __restrict__ CP1, int M, int MT)
{
    __shared__ u16 S[24576];
    u16* Cs = S;
    int b = blockIdx.x;
    int rsub = b % 24;
    int nt = rsub >> 3, m8 = rsub & 7;
    int mt = (b / 24) * 8 + m8;
    if (mt >= MT) return;
    int bm = mt * 128, bn = nt * 128;

    int t = threadIdx.x;
    int lane = t & 63, w = t >> 6;
    int wm = w & 1, wn = w >> 1;
    f32x4 zero = {0.f, 0.f, 0.f, 0.f};
    f32x4 acc[4][4];
    #pragma unroll
    for (int i = 0; i < 4; ++i)
        #pragma unroll
        for (int j = 0; j < 4; ++j) acc[i][j] = zero;

    int arow = t >> 2, acol = (t & 3) * 8;
    const u16* Ag = A + (size_t)(bm + arow) * 256 + acol;
    const u16* Bg = Bt3 + (size_t)(bn + arow) * 256 + acol;
    int q = lane >> 4, r = lane & 15;

    GLL(Ag,                 S + t * 8);
    GLL(Ag + 64 * 256,      S + 2048 + t * 8);
    GLL(Bg,                 S + 4096 + t * 8);
    GLL(Bg + 64 * 256,      S + 4096 + 2048 + t * 8);
    GLL(Ag + 32,            S + 8192 + t * 8);
    GLL(Ag + 64 * 256 + 32, S + 8192 + 2048 + t * 8);
    GLL(Bg + 32,            S + 8192 + 4096 + t * 8);
    GLL(Bg + 64 * 256 + 32, S + 8192 + 4096 + 2048 + t * 8);

    #pragma unroll
    for (int ks = 0; ks < 8; ++ks) {
        int cb = (ks % 3) * 8192;
        if (ks < 7) {
            asm volatile("s_waitcnt vmcnt(4)" ::: "memory");
        } else {
            asm volatile("s_waitcnt vmcnt(0)" ::: "memory");
        }
        __builtin_amdgcn_s_barrier();
        __builtin_amdgcn_sched_barrier(0);
        if (ks < 6) {
            int nb = ((ks + 2) % 3) * 8192;
            int k0 = (ks + 2) * 32;
            GLL(Ag + k0,            S + nb + t * 8);
            GLL(Ag + 64 * 256 + k0, S + nb + 2048 + t * 8);
            GLL(Bg + k0,            S + nb + 4096 + t * 8);
            GLL(Bg + 64 * 256 + k0, S + nb + 4096 + 2048 + t * 8);
        }
        bf16x8 af[4], bfr[4];
        #pragma unroll
        for (int i = 0; i < 4; ++i)
            af[i] = *(const bf16x8*)&S[cb + (wm * 64 + i * 16 + r) * 32 + q * 8];
        #pragma unroll
        for (int j = 0; j < 4; ++j)
            bfr[j] = *(const bf16x8*)&S[cb + 4096 + (wn * 64 + j * 16 + r) * 32 + q * 8];
        __builtin_amdgcn_s_setprio(1);
        #pragma unroll
        for (int i = 0; i < 4; ++i)
            #pragma unroll
            for (int j = 0; j < 4; ++j)
                acc[i][j] = __builtin_amdgcn_mfma_f32_16x16x32_bf16(af[i], bfr[j], acc[i][j], 0, 0, 0);
        __builtin_amdgcn_s_setprio(0);
    }
    __syncthreads();

    // ---- epilogue: acc -> LDS (bias + relu for cp1 block), full-line stores ----
    #pragma unroll
    for (int i = 0; i < 4; ++i) {
        int rowl = wm * 64 + i * 16 + q * 4;
        #pragma unroll
        for (int j = 0; j < 4; ++j) {
            int coll = wn * 64 + j * 16 + r;
            float bv = biasPost[bn + coll];
            #pragma unroll
            for (int rr = 0; rr < 4; ++rr) {
                float val = acc[i][j][rr] + bv;
                if (nt == 2) val = fmaxf(val, 0.f);
                Cs[(rowl + rr) * 128 + coll] = f2bf(val);
            }
        }
    }
    __syncthreads();
    int c16 = (t & 15) * 8, rbase = t >> 4;
    #pragma unroll
    for (int g = 0; g < 8; ++g) {
        int rowl = rbase + g * 16;
        int rowg = bm + rowl;
        if (rowg < M) {
            u16x8 v = *(const u16x8*)&Cs[rowl * 128 + c16];
            if (nt < 2) *(u16x8*)&UV[(size_t)rowg * 256 + bn + c16] = v;
            else        *(u16x8*)&CP1[(size_t)rowg * 128 + c16] = v;
        }
    }
}

// ================== small K=128 MFMA GEMM (cp2 only) ==================
__global__ __launch_bounds__(256) void k_gemm_k128(
    const u16* __restrict__ A, const u16* __restrict__ Bt,
    const float* __restrict__ bias, float* __restrict__ C,
    int ldc, int M, int N)
{
    __shared__ u16 As[4096];
    __shared__ u16 Bs[4096];
    int t = threadIdx.x;
    int lane = t & 63, w = t >> 6;
    int wm = w & 1, wn = w >> 1;
    int bm = blockIdx.x * 128;
    int arow = t >> 2, acol = (t & 3) * 8;
    int q = lane >> 4, r = lane & 15;
    const u16* Ag = A + (size_t)(bm + arow) * 128 + acol;
    const u16* Bg = Bt + (size_t)arow * 128 + acol;
    f32x4 zero = {0.f, 0.f, 0.f, 0.f};
    f32x4 acc[4][4];
    #pragma unroll
    for (int i = 0; i < 4; ++i)
        #pragma unroll
        for (int j = 0; j < 4; ++j) acc[i][j] = zero;

    for (int kc = 0; kc < 4; ++kc) {
        __syncthreads();
        GLL(Ag + kc * 32,            As + t * 8);
        GLL(Ag + 64 * 128 + kc * 32, As + 2048 + t * 8);
        GLL(Bg + kc * 32,            Bs + t * 8);
        GLL(Bg + 64 * 128 + kc * 32, Bs + 2048 + t * 8);
        __syncthreads();
        bf16x8 af[4], bfr[4];
        #pragma unroll
        for (int i = 0; i < 4; ++i)
            af[i] = *(const bf16x8*)&As[(wm * 64 + i * 16 + r) * 32 + q * 8];
        #pragma unroll
        for (int j = 0; j < 4; ++j)
            bfr[j] = *(const bf16x8*)&Bs[(wn * 64 + j * 16 + r) * 32 + q * 8];
        #pragma unroll
        for (int i = 0; i < 4; ++i)
            #pragma unroll
            for (int j = 0; j < 4; ++j)
                acc[i][j] = __builtin_amdgcn_mfma_f32_16x16x32_bf16(af[i], bfr[j], acc[i][j], 0, 0, 0);
    }
    #pragma unroll
    for (int i = 0; i < 4; ++i) {
        int rowb = bm + wm * 64 + i * 16 + q * 4;
        #pragma unroll
        for (int j = 0; j < 4; ++j) {
            int colg = wn * 64 + j * 16 + r;
            if (colg >= N) continue;
            float bv = bias[colg];
            #pragma unroll
            for (int rr = 0; rr < 4; ++rr) {
                int rowg = rowb + rr;
                if (rowg < M) C[(size_t)rowg * ldc + colg] = acc[i][j][rr] + bv;
            }
        }
    }
}

// ================== fused bond kernel ==================
__global__ __launch_bounds__(256) void k_bond_fused(
    const int* __restrict__ csr, const int* __restrict__ rowcsr, const int* __restrict__ eidarr,
    const int* __restrict__ types, const int* __restrict__ pvarr, const int* __restrict__ pv_tab,
    const u16* __restrict__ uv, const float* __restrict__ bc_w1,
    const u16* __restrict__ BtW2, const float* __restrict__ bc_b2,
    const float* __restrict__ bc_w3, const float* __restrict__ bc_b3,
    float* __restrict__ bl_out)
{
    __shared__ u16 T1s[16384];     // 32 KB: 4 chunks x [128 rows][32 k]; reused as f32 T2 [128][64]
    __shared__ u16 Bs[16384];      // 32 KB: 4 chunks x [128 cols][32 k]
    __shared__ float w5s[128], w6s[128], W3s[256], b2s[64], b3s[4];
    __shared__ int pvts[16];

    int t = threadIdx.x;
    int p0 = blockIdx.x * 128;

    if (t < 128) { w5s[t] = bc_w1[512 * 128 + t]; w6s[t] = bc_w1[513 * 128 + t]; }
    if (t < 256) W3s[t] = bc_w3[t];
    if (t < 64) b2s[t] = bc_b2[t];
    if (t < 4)  b3s[t] = bc_b3[t];
    if (t < 11) pvts[t] = pv_tab[t];
    #pragma unroll
    for (int c = 0; c < 4; ++c) {
        GLL(BtW2 + (size_t)(t >> 2) * 128 + c * 32 + (t & 3) * 8,        Bs + c * 4096 + t * 8);
        GLL(BtW2 + (size_t)(64 + (t >> 2)) * 128 + c * 32 + (t & 3) * 8, Bs + c * 4096 + 2048 + t * 8);
    }

    int l = t >> 1;            // local row 0..127
    int half = t & 1;          // which 64-col half
    int pos = p0 + l;
    int prow = 0, pk = 0;
    if (pos < N_EDGES) { prow = rowcsr[pos]; pk = csr[pos]; }
    int pcol = pk & 0xFFFFF;
    float pvr = (float)pvarr[prow];
    __syncthreads();   // w5s/w6s/pvts ready (pvts must not be read before this barrier)
    float pvc = (float)pvts[(pk >> 24) & 0xF];

    const u16* up = uv + (size_t)prow * 256 + half * 64;
    const u16* vp = uv + (size_t)pcol * 256 + 128 + half * 64;
    #pragma unroll
    for (int j = 0; j < 8; ++j) {
        int c = half * 64 + j * 8;
        ushort4 ua = *(const ushort4*)(up + j * 8);
        ushort4 ub = *(const ushort4*)(up + j * 8 + 4);
        ushort4 va = *(const ushort4*)(vp + j * 8);
        ushort4 vb = *(const ushort4*)(vp + j * 8 + 4);
        int chunk = c >> 5, kk = c & 31;
        u16* dst = T1s + chunk * 4096 + l * 32 + kk;
        dst[0] = f2bf(fmaxf(bf2f(ua.x) + bf2f(va.x) + pvr * w5s[c+0] + pvc * w6s[c+0], 0.f));
        dst[1] = f2bf(fmaxf(bf2f(ua.y) + bf2f(va.y) + pvr * w5s[c+1] + pvc * w6s[c+1], 0.f));
        dst[2] = f2bf(fmaxf(bf2f(ua.z) + bf2f(va.z) + pvr * w5s[c+2] + pvc * w6s[c+2], 0.f));
        dst[3] = f2bf(fmaxf(bf2f(ua.w) + bf2f(va.w) + pvr * w5s[c+3] + pvc * w6s[c+3], 0.f));
        dst[4] = f2bf(fmaxf(bf2f(ub.x) + bf2f(vb.x) + pvr * w5s[c+4] + pvc * w6s[c+4], 0.f));
        dst[5] = f2bf(fmaxf(bf2f(ub.y) + bf2f(vb.y) + pvr * w5s[c+5] + pvc * w6s[c+5], 0.f));
        dst[6] = f2bf(fmaxf(bf2f(ub.z) + bf2f(vb.z) + pvr * w5s[c+6] + pvc * w6s[c+6], 0.f));
        dst[7] = f2bf(fmaxf(bf2f(ub.w) + bf2f(vb.w) + pvr * w5s[c+7] + pvc * w6s[c+7], 0.f));
    }
    __syncthreads();   // T1s + Bs (GLL drained by barrier) ready

    int lane = t & 63, w = t >> 6;
    int wm = w & 1, wn = w >> 1;
    int q = lane >> 4, r = lane & 15;
    f32x4 zero = {0.f, 0.f, 0.f, 0.f};
    f32x4 acc[4][4];
    #pragma unroll
    for (int i = 0; i < 4; ++i)
        #pragma unroll
        for (int j = 0; j < 4; ++j) acc[i][j] = zero;
    #pragma unroll
    for (int c = 0; c < 4; ++c) {
        bf16x8 af[4], bfr[4];
        #pragma unroll
        for (int i = 0; i < 4; ++i)
            af[i] = *(const bf16x8*)&T1s[c * 4096 + (wm * 64 + i * 16 + r) * 32 + q * 8];
        #pragma unroll
        for (int j = 0; j < 4; ++j)
            bfr[j] = *(const bf16x8*)&Bs[c * 4096 + (wn * 64 + j * 16 + r) * 32 + q * 8];
        #pragma unroll
        for (int i = 0; i < 4; ++i)
            #pragma unroll
            for (int j = 0; j < 4; ++j)
                acc[i][j] = __builtin_amdgcn_mfma_f32_16x16x32_bf16(af[i], bfr[j], acc[i][j], 0, 0, 0);
    }
    __syncthreads();   // all T1s reads done; reuse as f32 T2

    float* T2f = (float*)T1s;   // [128][64]
    if (wn == 0) {
        #pragma unroll
        for (int i = 0; i < 4; ++i) {
            int row = wm * 64 + i * 16 + q * 4;
            #pragma unroll
            for (int j = 0; j < 4; ++j) {
                int col = j * 16 + r;
                float bv = b2s[col];
                #pragma unroll
                for (int rr = 0; rr < 4; ++rr)
                    T2f[(row + rr) * 64 + col] = fmaxf(acc[i][j][rr] + bv, 0.f);
            }
        }
    }
    __syncthreads();

    if (t < 128) {
        int pos3 = p0 + t;
        if (pos3 < N_EDGES) {
            float a0 = b3s[0], a1 = b3s[1], a2 = b3s[2], a3 = b3s[3];
            const float* trow = &T2f[t * 64];
            #pragma unroll 8
            for (int kk = 0; kk < 64; ++kk) {
                int k = (kk + t) & 63;           // rotate start: spread banks across lanes
                float tv = trow[k];
                a0 += tv * W3s[k * 4 + 0];
                a1 += tv * W3s[k * 4 + 1];
                a2 += tv * W3s[k * 4 + 2];
                a3 += tv * W3s[k * 4 + 3];
            }
            int prow3 = rowcsr[pos3];
            int pk3 = csr[pos3];
            int tc = (pk3 >> 24) & 0xF;
            int tr = types[prow3];
            int pr = pvarr[prow3];
            int pc = pvts[tc];
            float halogen = (tr == 4 || tr == 5 || tc == 4 || tc == 5) ? 1.f : 0.f;
            float l1 = (pr <= 1 || pc <= 1) ? 1.f : 0.f;
            float l2 = (pr <= 2 || pc <= 2) ? 1.f : 0.f;
            float pen13 = -100.f * halogen - 50.f * l1;
            a1 += pen13;
            a3 += pen13;
            a2 += pen13 - 50.f * l2;
            int eid = eidarr[pos3];
            *(float4*)&bl_out[(size_t)eid * 4] = make_float4(a0, a1, a2, a3);
        }
    }
}

// ================================================================
extern "C" void kernel_launch(void* const* d_in, const int* in_sizes, int n_in,
                              void* d_out, int out_size, void* d_ws, size_t ws_size,
                              hipStream_t stream)
{
    const float* x          = (const float*)d_in[0];
    const float* edge_attr  = (const float*)d_in[1];
    const float* atom_emb   = (const float*)d_in[2];
    const float* bond_emb   = (const float*)d_in[3];
    const float* vp_w1      = (const float*)d_in[4];
    const float* vp_b1      = (const float*)d_in[5];
    const float* vp_w2      = (const float*)d_in[6];
    const float* vp_b2      = (const float*)d_in[7];
    const float* gnn_wself  = (const float*)d_in[8];
    const float* gnn_bself  = (const float*)d_in[9];
    const float* gnn_wmsg   = (const float*)d_in[10];
    const float* gnn_bmsg   = (const float*)d_in[11];
    const float* bc_w1      = (const float*)d_in[12];
    const float* bc_b1      = (const float*)d_in[13];
    const float* bc_w2      = (const float*)d_in[14];
    const float* bc_b2      = (const float*)d_in[15];
    const float* bc_w3      = (const float*)d_in[16];
    const float* bc_b3      = (const float*)d_in[17];
    const float* cp_w1      = (const float*)d_in[18];
    const float* cp_b1      = (const float*)d_in[19];
    const float* cp_w2      = (const float*)d_in[20];
    const float* cp_b2      = (const float*)d_in[21];
    const int*   ei         = (const int*)d_in[22];

    float* out    = (float*)d_out;
    float* h_out  = out + H_OFF;
    float* cp_out = out + CP_OFF;
    float* vl_out = out + VL_OFF;
    float* bl_out = out + BL_OFF;
    float* vi_out = out + VI_OFF;

    // ---- workspace layout ----
    char* base = (char*)d_ws;
    const size_t S = (size_t)M_PAD * 256 * 2;   // 51,249,152 B
    u16* h_bf  = (u16*)(base + 0 * S);           // R0: h ; later uv
    u16* uv_bf = (u16*)(base + 0 * S);
    u16* hm_bf = (u16*)(base + 1 * S);           // R1: hm
    u16* hs_bf = (u16*)(base + 2 * S);           // R2: hs
    u16* hd_bf = (u16*)(base + 3 * S);           // R3: damped h bf16
    u16* cp1_bf= (u16*)(base + 4 * S);           // R4: [M_PAD][128] bf16
    char* w    = base + 4 * S + (size_t)M_PAD * 128 * 2;
    int* degree  = (int*)w; w += (size_t)N_NODES * 4;
    int* offsets = (int*)w; w += (size_t)N_NODES * 4;
    int* cursor  = (int*)w; w += (size_t)N_NODES * 4;
    int* types   = (int*)w; w += (size_t)N_NODES * 4;
    int* pvarr   = (int*)w; w += (size_t)N_NODES * 4;
    int* csr     = (int*)w; w += (size_t)E_PAD * 4;
    int* rowcsr  = (int*)w; w += (size_t)E_PAD * 4;
    int* eidarr  = (int*)w; w += (size_t)E_PAD * 4;
    int* bsum    = (int*)w; w += 4096;
    int* bbase   = (int*)w; w += 4096;
    int* pv_tab  = (int*)w; w += 1024;
    float* vl_tab    = (float*)w; w += 2048;
    float* h0_tab    = (float*)w; w += 11 * 256 * 4;
    float* self0_tab = (float*)w; w += 11 * 256 * 4;
    float* msg0_tab  = (float*)w; w += 55 * 256 * 4;
    float* bondtab   = (float*)w; w += 2 * 5 * 256 * 4;
    u16* BtL1  = (u16*)w; w += 512 * 256 * 2;
    u16* BtL2  = (u16*)w; w += 512 * 256 * 2;
    u16* Bt3   = (u16*)w; w += 384 * 256 * 2;
    u16* BtW2  = (u16*)w; w += 128 * 128 * 2;
    u16* BtCP2 = (u16*)w; w += 128 * 128 * 2;
    float* bias512  = (float*)w; w += 2 * 512 * 4;
    float* biasPost = (float*)w; w += 384 * 4;

    // ---- setup ----
    k_type_mlp<<<1, 256, 0, stream>>>(atom_emb, vp_w1, vp_b1, vp_w2, vp_b2, pv_tab, vl_tab, h0_tab);
    k_tables<<<76, 256, 0, stream>>>(bond_emb, gnn_wself, gnn_bself, gnn_wmsg, gnn_bmsg,
                                     h0_tab, self0_tab, msg0_tab, bondtab);
    k_wtrans<<<1664, 256, 0, stream>>>(gnn_wmsg, gnn_wself, bc_w1, cp_w1, bc_w2, cp_w2,
                                       BtL1, BtL2, Bt3, BtW2, BtCP2);
    k_setup_bias<<<6, 256, 0, stream>>>(gnn_bself, bc_b1, cp_b1, bias512, biasPost);
    k_node_init<<<(N_NODES + 255) / 256, 256, 0, stream>>>(x, pv_tab, vl_tab, types, pvarr, degree, vl_out);
    k_edge_deg<<<(N_EDGES + 255) / 256, 256, 0, stream>>>(ei, degree);
    int nb = (N_NODES + SCAN_B - 1) / SCAN_B;
    k_scan1<<<nb, SCAN_B, 0, stream>>>(degree, offsets, bsum);
    k_scan2<<<1, 128, 0, stream>>>(bsum, bbase, nb);
    k_scan3<<<nb, SCAN_B, 0, stream>>>(offsets, bbase, cursor);
    k_csr_fill<<<(N_EDGES + 255) / 256, 256, 0, stream>>>(ei, edge_attr, types, cursor, csr, rowcsr, eidarr);
    k_agg0<<<N_NODES / 4, 256, 0, stream>>>(offsets, degree, types, self0_tab, msg0_tab, csr, h_bf);

    // ---- GNN layers 1,2 (l=2 fuses damp/viol/h_out) ----
    const int MT = M_PAD / 128;           // 782
    const int QB = (MT + 7) / 8;          // 98
    for (int l = 1; l <= 2; ++l) {
        const u16* BtL = (l == 1) ? BtL1 : BtL2;
        k_gemm_dual<<<QB * 32, 256, 0, stream>>>(h_bf, BtL, bias512 + (size_t)(l - 1) * 512,
                                                 hm_bf, hs_bf, N_NODES, MT);
        k_agg12<<<N_NODES / 4, 256, 0, stream>>>(offsets, degree, hs_bf, hm_bf,
                                                 bondtab + (size_t)(l - 1) * 5 * 256, csr, h_bf,
                                                 (l == 2) ? 1 : 0, pvarr, h_out, hd_bf, vi_out);
    }

    // ---- uv + cp1 fused; then cp2 ----
    k_gemm_post<<<QB * 24, 256, 0, stream>>>(hd_bf, Bt3, biasPost, uv_bf, cp1_bf, N_NODES, MT);
    k_gemm_k128<<<MT, 256, 0, stream>>>(cp1_bf, BtCP2, cp_b2, cp_out, 32, N_NODES, 32);

    // ---- fused bond chain ----
    k_bond_fused<<<E_PAD / 128, 256, 0, stream>>>(csr, rowcsr, eidarr, types, pvarr, pv_tab,
                                                  uv_bf, bc_w1, BtW2, bc_b2, bc_w3, bc_b3, bl_out);
}

// Round 9
// 584.324 us; speedup vs baseline: 1.3094x; 1.0392x over previous
//
#include <hip/hip_runtime.h>

#define N_NODES 100000
#define N_EDGES 300000
#define M_PAD   100096   // 782*128
#define E_PAD   300032   // 2344*128

typedef unsigned short u16;
typedef short bf16x8 __attribute__((ext_vector_type(8)));
typedef float f32x4  __attribute__((ext_vector_type(4)));
typedef unsigned short u16x8 __attribute__((ext_vector_type(8)));

__device__ __forceinline__ float bf2f(u16 u) {
    unsigned x = ((unsigned)u) << 16;
    return __builtin_bit_cast(float, x);
}
__device__ __forceinline__ u16 f2bf(float f) {
    unsigned u = __builtin_bit_cast(unsigned, f);
    unsigned r = (u + 0x7FFF + ((u >> 16) & 1)) >> 16;
    return (u16)r;
}

// ---------------- output layout (floats) ----------------
#define H_OFF   0
#define CP_OFF  25600000
#define VL_OFF  28800000
#define BL_OFF  29600000
#define VI_OFF  30800000

#define GLL(gp, lp) __builtin_amdgcn_global_load_lds( \
    (const __attribute__((address_space(1))) unsigned int*)(gp), \
    (__attribute__((address_space(3))) unsigned int*)(lp), 16, 0, 0)

// ============ per-atom-type valence MLP + h0 rows ============
__global__ void k_type_mlp(const float* __restrict__ atom_emb,
                           const float* __restrict__ vp_w1, const float* __restrict__ vp_b1,
                           const float* __restrict__ vp_w2, const float* __restrict__ vp_b2,
                           int* __restrict__ pv_tab, float* __restrict__ vl_tab,
                           float* __restrict__ h0_tab)
{
    int tid = threadIdx.x;
    for (int i = tid; i < 11 * 256; i += 256) h0_tab[i] = 0.f;
    __syncthreads();
    if (tid < 11) {
        int t = tid;
        const float* ae = atom_emb + t * 64;
        float lg[8];
        #pragma unroll
        for (int c = 0; c < 8; ++c) lg[c] = vp_b2[c];
        for (int j = 0; j < 32; ++j) {
            float z = vp_b1[j];
            for (int d = 0; d < 64; ++d) z += ae[d] * vp_w1[d * 32 + j];
            z = fmaxf(z, 0.f);
            #pragma unroll
            for (int c = 0; c < 8; ++c) lg[c] += z * vp_w2[j * 8 + c];
        }
        int best = 0;
        #pragma unroll
        for (int c = 1; c < 8; ++c) if (lg[c] > lg[best]) best = c;
        pv_tab[t] = best + 1;
        for (int c = 0; c < 8; ++c) vl_tab[t * 8 + c] = lg[c];
        float* h0 = h0_tab + t * 256;
        for (int d = 0; d < 64; ++d) h0[d] = ae[d];
        h0[64 + best] = 1.f;
    }
}

// ============ layer-0 tables + bond tables for layers 1,2 ============
__global__ void k_tables(const float* __restrict__ bond_emb,
                         const float* __restrict__ gnn_wself, const float* __restrict__ gnn_bself,
                         const float* __restrict__ gnn_wmsg, const float* __restrict__ gnn_bmsg,
                         const float* __restrict__ h0_tab,
                         float* __restrict__ self0_tab, float* __restrict__ msg0_tab,
                         float* __restrict__ bondtab)
{
    int b = blockIdx.x, c = threadIdx.x;
    if (b < 11) {
        int t = b;
        const float* h0 = h0_tab + t * 256;
        float acc = gnn_bself[c];
        for (int k = 0; k < 256; ++k) acc += h0[k] * gnn_wself[k * 256 + c];
        self0_tab[t * 256 + c] = acc;
    } else if (b < 66) {
        int idx = b - 11; int t = idx / 5, bb = idx % 5;
        const float* h0 = h0_tab + t * 256;
        float acc = gnn_bmsg[c];
        for (int k = 0; k < 256; ++k) acc += h0[k] * gnn_wmsg[k * 256 + c];
        const float* be = bond_emb + bb * 64;
        for (int k = 0; k < 64; ++k) acc += be[k] * gnn_wmsg[(256 + k) * 256 + c];
        msg0_tab[idx * 256 + c] = fmaxf(acc, 0.f);
    } else {
        int idx = b - 66; int l = idx / 5 + 1, bb = idx % 5;
        const float* w = gnn_wmsg + (size_t)l * 320 * 256;
        const float* be = bond_emb + bb * 64;
        float acc = gnn_bmsg[l * 256 + c];
        for (int k = 0; k < 64; ++k) acc += be[k] * w[(256 + k) * 256 + c];
        bondtab[(l - 1) * 5 * 256 + bb * 256 + c] = acc;
    }
}

// ============ bf16-transposed weight tables ============
__global__ void k_wtrans(const float* __restrict__ wmsg, const float* __restrict__ wself,
                         const float* __restrict__ bcw1, const float* __restrict__ cpw1,
                         const float* __restrict__ bcw2, const float* __restrict__ cpw2,
                         u16* __restrict__ BtL1, u16* __restrict__ BtL2, u16* __restrict__ Bt3,
                         u16* __restrict__ BtW2, u16* __restrict__ BtCP2)
{
    int b = blockIdx.x, k = threadIdx.x;
    if (b < 512) {
        int n = b;
        float v = (n < 256) ? wmsg[(size_t)1 * 320 * 256 + (size_t)k * 256 + n]
                            : wself[(size_t)1 * 256 * 256 + (size_t)k * 256 + (n - 256)];
        BtL1[n * 256 + k] = f2bf(v);
    } else if (b < 1024) {
        int n = b - 512;
        float v = (n < 256) ? wmsg[(size_t)2 * 320 * 256 + (size_t)k * 256 + n]
                            : wself[(size_t)2 * 256 * 256 + (size_t)k * 256 + (n - 256)];
        BtL2[n * 256 + k] = f2bf(v);
    } else if (b < 1408) {
        int n = b - 1024;
        float v;
        if (n < 128)      v = bcw1[k * 128 + n];
        else if (n < 256) v = bcw1[(256 + k) * 128 + (n - 128)];
        else              v = cpw1[k * 128 + (n - 256)];
        Bt3[n * 256 + k] = f2bf(v);
    } else if (b < 1536) {
        int n = b - 1408;
        if (k < 128) BtW2[n * 128 + k] = f2bf(n < 64 ? bcw2[k * 64 + n] : 0.f);
    } else {
        int n = b - 1536;
        if (k < 128) BtCP2[n * 128 + k] = f2bf(n < 32 ? cpw2[k * 32 + n] : 0.f);
    }
}

__global__ void k_setup_bias(const float* __restrict__ bself, const float* __restrict__ bcb1,
                             const float* __restrict__ cpb1,
                             float* __restrict__ bias512, float* __restrict__ biasPost)
{
    int i = blockIdx.x * 256 + threadIdx.x;
    if (i < 1024) {
        int l = i >> 9, c = i & 511;
        bias512[l * 512 + c] = (c < 256) ? 0.f : bself[(l + 1) * 256 + (c - 256)];
    } else if (i < 1408) {
        int c = i - 1024;
        biasPost[c] = (c < 128) ? bcb1[c] : ((c < 256) ? 0.f : cpb1[c - 256]);
    }
}

// ============ node init ============
__global__ void k_node_init(const float* __restrict__ x, const int* __restrict__ pv_tab,
                            const float* __restrict__ vl_tab,
                            int* __restrict__ types, int* __restrict__ pvarr,
                            int* __restrict__ degree, float* __restrict__ vl_out)
{
    int i = blockIdx.x * blockDim.x + threadIdx.x;
    if (i >= N_NODES) return;
    int t = (int)x[i * 16];
    t = min(max(t, 0), 10);
    types[i] = t;
    pvarr[i] = pv_tab[t];
    degree[i] = 0;
    float4 v0 = *(const float4*)&vl_tab[t * 8];
    float4 v1 = *(const float4*)&vl_tab[t * 8 + 4];
    *(float4*)&vl_out[i * 8]     = v0;
    *(float4*)&vl_out[i * 8 + 4] = v1;
}

__global__ void k_edge_deg(const int* __restrict__ ei, int* __restrict__ degree)
{
    int e = blockIdx.x * blockDim.x + threadIdx.x;
    if (e >= N_EDGES) return;
    atomicAdd(&degree[ei[e]], 1);
}

// ============ scan ============
#define SCAN_B 1024
__global__ void k_scan1(const int* __restrict__ degree, int* __restrict__ part, int* __restrict__ bsum)
{
    __shared__ int s[SCAN_B];
    int tid = threadIdx.x;
    int i = blockIdx.x * SCAN_B + tid;
    int v = (i < N_NODES) ? degree[i] : 0;
    s[tid] = v; __syncthreads();
    for (int off = 1; off < SCAN_B; off <<= 1) {
        int t = (tid >= off) ? s[tid - off] : 0;
        __syncthreads();
        s[tid] += t;
        __syncthreads();
    }
    if (i < N_NODES) part[i] = s[tid] - v;
    if (tid == SCAN_B - 1) bsum[blockIdx.x] = s[tid];
}

__global__ void k_scan2(const int* __restrict__ bsum, int* __restrict__ bbase, int nb)
{
    __shared__ int s[128];
    int tid = threadIdx.x;
    int v = (tid < nb) ? bsum[tid] : 0;
    s[tid] = v; __syncthreads();
    for (int off = 1; off < 128; off <<= 1) {
        int t = (tid >= off) ? s[tid - off] : 0;
        __syncthreads();
        s[tid] += t;
        __syncthreads();
    }
    bbase[tid] = s[tid] - v;
}

__global__ void k_scan3(int* __restrict__ part, const int* __restrict__ bbase, int* __restrict__ cursor)
{
    int i = blockIdx.x * SCAN_B + threadIdx.x;
    if (i >= N_NODES) return;
    int o = part[i] + bbase[blockIdx.x];
    part[i] = o;
    cursor[i] = o;
}

// ============ CSR fill (+ row/eid side arrays for the bond pass) ============
__global__ void k_csr_fill(const int* __restrict__ ei, const float* __restrict__ edge_attr,
                           const int* __restrict__ types, int* __restrict__ cursor,
                           int* __restrict__ csr, int* __restrict__ rowcsr, int* __restrict__ eidarr)
{
    int e = blockIdx.x * blockDim.x + threadIdx.x;
    if (e >= N_EDGES) return;
    int row = ei[e], col = ei[N_EDGES + e];
    int bt = (int)edge_attr[e * 4];
    bt = min(max(bt, 0), 4);
    int pos = atomicAdd(&cursor[row], 1);
    csr[pos] = col | (bt << 20) | (types[col] << 24);
    rowcsr[pos] = row;
    eidarr[pos] = e;
}

// ============ layer-0 aggregation (tables) -> h bf16 ============
// csr entries prefetched lane-parallel, broadcast via shfl (kills dependent csr load chain).
__global__ __launch_bounds__(256) void k_agg0(const int* __restrict__ offsets, const int* __restrict__ degree,
                       const int* __restrict__ types,
                       const float* __restrict__ self0_tab, const float* __restrict__ msg0_tab,
                       const int* __restrict__ csr, u16* __restrict__ h)
{
    int wid = threadIdx.x >> 6, lane = threadIdx.x & 63;
    int node = blockIdx.x * 4 + wid;
    if (node >= N_NODES) return;
    int t = types[node];
    float4 acc = *(const float4*)&self0_tab[t * 256 + lane * 4];
    int start = offsets[node], deg = degree[node];
    int pj = (lane < deg) ? csr[start + lane] : 0;
    int dmax = min(deg, 64);
    for (int j = 0; j < dmax; ++j) {
        int p = __shfl(pj, j);
        int combo = ((p >> 24) & 0xF) * 5 + ((p >> 20) & 7);
        float4 m = *(const float4*)&msg0_tab[combo * 256 + lane * 4];
        acc.x += m.x; acc.y += m.y; acc.z += m.z; acc.w += m.w;
    }
    for (int j = 64; j < deg; ++j) {   // practically unreachable (Poisson(3))
        int p = csr[start + j];
        int combo = ((p >> 24) & 0xF) * 5 + ((p >> 20) & 7);
        float4 m = *(const float4*)&msg0_tab[combo * 256 + lane * 4];
        acc.x += m.x; acc.y += m.y; acc.z += m.z; acc.w += m.w;
    }
    ushort4 r;
    r.x = f2bf(fmaxf(acc.x, 0.f)); r.y = f2bf(fmaxf(acc.y, 0.f));
    r.z = f2bf(fmaxf(acc.z, 0.f)); r.w = f2bf(fmaxf(acc.w, 0.f));
    *(ushort4*)&h[(size_t)node * 256 + lane * 4] = r;
}

// ============ layers 1,2 aggregation; shfl-prefetched csr + 1-deep hm pipeline ============
__global__ __launch_bounds__(256) void k_agg12(const int* __restrict__ offsets, const int* __restrict__ degree,
                        const u16* __restrict__ hs, const u16* __restrict__ hm,
                        const float* __restrict__ bondtab, const int* __restrict__ csr,
                        u16* __restrict__ h, int final_layer, const int* __restrict__ pvarr,
                        float* __restrict__ h_out, u16* __restrict__ hd_bf, float* __restrict__ viol_out)
{
    int wid = threadIdx.x >> 6, lane = threadIdx.x & 63;
    int node = blockIdx.x * 4 + wid;
    if (node >= N_NODES) return;
    ushort4 s4 = *(const ushort4*)&hs[(size_t)node * 256 + lane * 4];
    float ax = bf2f(s4.x), ay = bf2f(s4.y), az = bf2f(s4.z), aw = bf2f(s4.w);
    int start = offsets[node], deg = degree[node];
    int pj = (lane < deg) ? csr[start + lane] : 0;
    int dmax = min(deg, 64);
    if (dmax > 0) {
        int p0 = __shfl(pj, 0);
        ushort4 m0 = *(const ushort4*)&hm[(size_t)(p0 & 0xFFFFF) * 256 + lane * 4];
        for (int j = 1; j < dmax; ++j) {
            int p1 = __shfl(pj, j);
            ushort4 m1 = *(const ushort4*)&hm[(size_t)(p1 & 0xFFFFF) * 256 + lane * 4];  // in flight during j-1 math
            float4 bb = *(const float4*)&bondtab[((p0 >> 20) & 7) * 256 + lane * 4];
            ax += fmaxf(bf2f(m0.x) + bb.x, 0.f);
            ay += fmaxf(bf2f(m0.y) + bb.y, 0.f);
            az += fmaxf(bf2f(m0.z) + bb.z, 0.f);
            aw += fmaxf(bf2f(m0.w) + bb.w, 0.f);
            m0 = m1; p0 = p1;
        }
        float4 bb = *(const float4*)&bondtab[((p0 >> 20) & 7) * 256 + lane * 4];
        ax += fmaxf(bf2f(m0.x) + bb.x, 0.f);
        ay += fmaxf(bf2f(m0.y) + bb.y, 0.f);
        az += fmaxf(bf2f(m0.z) + bb.z, 0.f);
        aw += fmaxf(bf2f(m0.w) + bb.w, 0.f);
    }
    for (int j = 64; j < deg; ++j) {   // practically unreachable
        int p = csr[start + j];
        int c = p & 0xFFFFF;
        int bt = (p >> 20) & 7;
        ushort4 m4 = *(const ushort4*)&hm[(size_t)c * 256 + lane * 4];
        float4 bb = *(const float4*)&bondtab[bt * 256 + lane * 4];
        ax += fmaxf(bf2f(m4.x) + bb.x, 0.f);
        ay += fmaxf(bf2f(m4.y) + bb.y, 0.f);
        az += fmaxf(bf2f(m4.z) + bb.z, 0.f);
        aw += fmaxf(bf2f(m4.w) + bb.w, 0.f);
    }
    ax = fmaxf(ax, 0.f); ay = fmaxf(ay, 0.f); az = fmaxf(az, 0.f); aw = fmaxf(aw, 0.f);
    if (!final_layer) {
        ushort4 r;
        r.x = f2bf(ax); r.y = f2bf(ay); r.z = f2bf(az); r.w = f2bf(aw);
        *(ushort4*)&h[(size_t)node * 256 + lane * 4] = r;
    } else {
        float viol = fmaxf((float)deg - (float)pvarr[node], 0.f);
        float s = 1.f / (1.f + viol);
        ax *= s; ay *= s; az *= s; aw *= s;
        float4 v = make_float4(ax, ay, az, aw);
        *(float4*)&h_out[(size_t)node * 256 + lane * 4] = v;
        ushort4 r;
        r.x = f2bf(ax); r.y = f2bf(ay); r.z = f2bf(az); r.w = f2bf(aw);
        *(ushort4*)&hd_bf[(size_t)node * 256 + lane * 4] = r;
        if (lane == 0) viol_out[node] = viol;
    }
}

// ================== layer GEMM: 3-buffer 2-DEEP pipeline + counted vmcnt + setprio ==================
__global__ __launch_bounds__(256) void k_gemm_dual(
    const u16* __restrict__ A, const u16* __restrict__ Bt,
    const float* __restrict__ bias512,
    u16* __restrict__ Dm, u16* __restrict__ Ds, int M, int MT)
{
    __shared__ u16 S[24576];          // 48 KB: buf i at S + i*8192 (A) / +4096 (B), i=0..2
    u16* Cs = S;                      // epilogue reuse [128][128]
    int b = blockIdx.x;
    int rsub = b & 31;
    int nt = rsub >> 3, m8 = rsub & 7;
    int mt = (b >> 5) * 8 + m8;
    if (mt >= MT) return;
    int bm = mt * 128, bn = nt * 128;

    int t = threadIdx.x;
    int lane = t & 63, w = t >> 6;
    int wm = w & 1, wn = w >> 1;
    f32x4 zero = {0.f, 0.f, 0.f, 0.f};
    f32x4 acc[4][4];
    #pragma unroll
    for (int i = 0; i < 4; ++i)
        #pragma unroll
        for (int j = 0; j < 4; ++j) acc[i][j] = zero;

    int arow = t >> 2, acol = (t & 3) * 8;
    const u16* Ag = A + (size_t)(bm + arow) * 256 + acol;
    const u16* Bg = Bt + (size_t)(bn + arow) * 256 + acol;
    int q = lane >> 4, r = lane & 15;

    // prologue: stage k-steps 0 and 1 (2-deep)
    GLL(Ag,                 S + t * 8);
    GLL(Ag + 64 * 256,      S + 2048 + t * 8);
    GLL(Bg,                 S + 4096 + t * 8);
    GLL(Bg + 64 * 256,      S + 4096 + 2048 + t * 8);
    GLL(Ag + 32,            S + 8192 + t * 8);
    GLL(Ag + 64 * 256 + 32, S + 8192 + 2048 + t * 8);
    GLL(Bg + 32,            S + 8192 + 4096 + t * 8);
    GLL(Bg + 64 * 256 + 32, S + 8192 + 4096 + 2048 + t * 8);

    #pragma unroll
    for (int ks = 0; ks < 8; ++ks) {
        int cb = (ks % 3) * 8192;
        if (ks < 7) {
            asm volatile("s_waitcnt vmcnt(4)" ::: "memory");
        } else {
            asm volatile("s_waitcnt vmcnt(0)" ::: "memory");
        }
        __builtin_amdgcn_s_barrier();
        __builtin_amdgcn_sched_barrier(0);
        if (ks < 6) {
            int nb = ((ks + 2) % 3) * 8192;
            int k0 = (ks + 2) * 32;
            GLL(Ag + k0,            S + nb + t * 8);
            GLL(Ag + 64 * 256 + k0, S + nb + 2048 + t * 8);
            GLL(Bg + k0,            S + nb + 4096 + t * 8);
            GLL(Bg + 64 * 256 + k0, S + nb + 4096 + 2048 + t * 8);
        }
        bf16x8 af[4], bfr[4];
        #pragma unroll
        for (int i = 0; i < 4; ++i)
            af[i] = *(const bf16x8*)&S[cb + (wm * 64 + i * 16 + r) * 32 + q * 8];
        #pragma unroll
        for (int j = 0; j < 4; ++j)
            bfr[j] = *(const bf16x8*)&S[cb + 4096 + (wn * 64 + j * 16 + r) * 32 + q * 8];
        __builtin_amdgcn_s_setprio(1);
        #pragma unroll
        for (int i = 0; i < 4; ++i)
            #pragma unroll
            for (int j = 0; j < 4; ++j)
                acc[i][j] = __builtin_amdgcn_mfma_f32_16x16x32_bf16(af[i], bfr[j], acc[i][j], 0, 0, 0);
        __builtin_amdgcn_s_setprio(0);
    }
    __syncthreads();   // all last-buffer reads done before Cs overwrite (vmcnt already 0)

    // ---- epilogue: acc -> LDS C-tile (bias fused), then full-line stores ----
    #pragma unroll
    for (int i = 0; i < 4; ++i) {
        int rowl = wm * 64 + i * 16 + q * 4;
        #pragma unroll
        for (int j = 0; j < 4; ++j) {
            int coll = wn * 64 + j * 16 + r;
            float bv = bias512[bn + coll];
            #pragma unroll
            for (int rr = 0; rr < 4; ++rr)
                Cs[(rowl + rr) * 128 + coll] = f2bf(acc[i][j][rr] + bv);
        }
    }
    __syncthreads();
    u16* Dbase = (nt < 2) ? (Dm + bn) : (Ds + (bn - 256));
    int c16 = (t & 15) * 8, rbase = t >> 4;
    #pragma unroll
    for (int g = 0; g < 8; ++g) {
        int rowl = rbase + g * 16;
        int rowg = bm + rowl;
        if (rowg < M) {
            u16x8 v = *(const u16x8*)&Cs[rowl * 128 + c16];
            *(u16x8*)&Dbase[(size_t)rowg * 256 + c16] = v;
        }
    }
}

// ================== post GEMM (N=384): same 2-deep pipeline + setprio ==================
__global__ __launch_bounds__(256) void k_gemm_post(
    const u16* __restrict__ A, const u16* __restrict__ Bt3,
    const float* __restrict__ biasPost,
    u16* __restrict__ UV, u16* __restrict__ CP1, int M, int MT)
{
    __shared__ u16 S[24576];
    u16* Cs = S;
    int b = blockIdx.x;
    int rsub = b % 24;
    int nt = rsub >> 3, m8 = rsub & 7;
    int mt = (b / 24) * 8 + m8;
    if (mt >= MT) return;
    int bm = mt * 128, bn = nt * 128;

    int t = threadIdx.x;
    int lane = t & 63, w = t >> 6;
    int wm = w & 1, wn = w >> 1;
    f32x4 zero = {0.f, 0.f, 0.f, 0.f};
    f32x4 acc[4][4];
    #pragma unroll
    for (int i = 0; i < 4; ++i)
        #pragma unroll
        for (int j = 0; j < 4; ++j) acc[i][j] = zero;

    int arow = t >> 2, acol = (t & 3) * 8;
    const u16* Ag = A + (size_t)(bm + arow) * 256 + acol;
    const u16* Bg = Bt3 + (size_t)(bn + arow) * 256 + acol;
    int q = lane >> 4, r = lane & 15;

    GLL(Ag,                 S + t * 8);
    GLL(Ag + 64 * 256,      S + 2048 + t * 8);
    GLL(Bg,                 S + 4096 + t * 8);
    GLL(Bg + 64 * 256,      S + 4096 + 2048 + t * 8);
    GLL(Ag + 32,            S + 8192 + t * 8);
    GLL(Ag + 64 * 256 + 32, S + 8192 + 2048 + t * 8);
    GLL(Bg + 32,            S + 8192 + 4096 + t * 8);
    GLL(Bg + 64 * 256 + 32, S + 8192 + 4096 + 2048 + t * 8);

    #pragma unroll
    for (int ks = 0; ks < 8; ++ks) {
        int cb = (ks % 3) * 8192;
        if (ks < 7) {
            asm volatile("s_waitcnt vmcnt(4)" ::: "memory");
        } else {
            asm volatile("s_waitcnt vmcnt(0)" ::: "memory");
        }
        __builtin_amdgcn_s_barrier();
        __builtin_amdgcn_sched_barrier(0);
        if (ks < 6) {
            int nb = ((ks + 2) % 3) * 8192;
            int k0 = (ks + 2) * 32;
            GLL(Ag + k0,            S + nb + t * 8);
            GLL(Ag + 64 * 256 + k0, S + nb + 2048 + t * 8);
            GLL(Bg + k0,            S + nb + 4096 + t * 8);
            GLL(Bg + 64 * 256 + k0, S + nb + 4096 + 2048 + t * 8);
        }
        bf16x8 af[4], bfr[4];
        #pragma unroll
        for (int i = 0; i < 4; ++i)
            af[i] = *(const bf16x8*)&S[cb + (wm * 64 + i * 16 + r) * 32 + q * 8];
        #pragma unroll
        for (int j = 0; j < 4; ++j)
            bfr[j] = *(const bf16x8*)&S[cb + 4096 + (wn * 64 + j * 16 + r) * 32 + q * 8];
        __builtin_amdgcn_s_setprio(1);
        #pragma unroll
        for (int i = 0; i < 4; ++i)
            #pragma unroll
            for (int j = 0; j < 4; ++j)
                acc[i][j] = __builtin_amdgcn_mfma_f32_16x16x32_bf16(af[i], bfr[j], acc[i][j], 0, 0, 0);
        __builtin_amdgcn_s_setprio(0);
    }
    __syncthreads();

    // ---- epilogue: acc -> LDS (bias + relu for cp1 block), full-line stores ----
    #pragma unroll
    for (int i = 0; i < 4; ++i) {
        int rowl = wm * 64 + i * 16 + q * 4;
        #pragma unroll
        for (int j = 0; j < 4; ++j) {
            int coll = wn * 64 + j * 16 + r;
            float bv = biasPost[bn + coll];
            #pragma unroll
            for (int rr = 0; rr < 4; ++rr) {
                float val = acc[i][j][rr] + bv;
                if (nt == 2) val = fmaxf(val, 0.f);
                Cs[(rowl + rr) * 128 + coll] = f2bf(val);
            }
        }
    }
    __syncthreads();
    int c16 = (t & 15) * 8, rbase = t >> 4;
    #pragma unroll
    for (int g = 0; g < 8; ++g) {
        int rowl = rbase + g * 16;
        int rowg = bm + rowl;
        if (rowg < M) {
            u16x8 v = *(const u16x8*)&Cs[rowl * 128 + c16];
            if (nt < 2) *(u16x8*)&UV[(size_t)rowg * 256 + bn + c16] = v;
            else        *(u16x8*)&CP1[(size_t)rowg * 128 + c16] = v;
        }
    }
}

// ================== small K=128 MFMA GEMM (cp2 only) ==================
__global__ __launch_bounds__(256) void k_gemm_k128(
    const u16* __restrict__ A, const u16* __restrict__ Bt,
    const float* __restrict__ bias, float* __restrict__ C,
    int ldc, int M, int N)
{
    __shared__ u16 As[4096];
    __shared__ u16 Bs[4096];
    int t = threadIdx.x;
    int lane = t & 63, w = t >> 6;
    int wm = w & 1, wn = w >> 1;
    int bm = blockIdx.x * 128;
    int arow = t >> 2, acol = (t & 3) * 8;
    int q = lane >> 4, r = lane & 15;
    const u16* Ag = A + (size_t)(bm + arow) * 128 + acol;
    const u16* Bg = Bt + (size_t)arow * 128 + acol;
    f32x4 zero = {0.f, 0.f, 0.f, 0.f};
    f32x4 acc[4][4];
    #pragma unroll
    for (int i = 0; i < 4; ++i)
        #pragma unroll
        for (int j = 0; j < 4; ++j) acc[i][j] = zero;

    for (int kc = 0; kc < 4; ++kc) {
        __syncthreads();
        GLL(Ag + kc * 32,            As + t * 8);
        GLL(Ag + 64 * 128 + kc * 32, As + 2048 + t * 8);
        GLL(Bg + kc * 32,            Bs + t * 8);
        GLL(Bg + 64 * 128 + kc * 32, Bs + 2048 + t * 8);
        __syncthreads();
        bf16x8 af[4], bfr[4];
        #pragma unroll
        for (int i = 0; i < 4; ++i)
            af[i] = *(const bf16x8*)&As[(wm * 64 + i * 16 + r) * 32 + q * 8];
        #pragma unroll
        for (int j = 0; j < 4; ++j)
            bfr[j] = *(const bf16x8*)&Bs[(wn * 64 + j * 16 + r) * 32 + q * 8];
        #pragma unroll
        for (int i = 0; i < 4; ++i)
            #pragma unroll
            for (int j = 0; j < 4; ++j)
                acc[i][j] = __builtin_amdgcn_mfma_f32_16x16x32_bf16(af[i], bfr[j], acc[i][j], 0, 0, 0);
    }
    #pragma unroll
    for (int i = 0; i < 4; ++i) {
        int rowb = bm + wm * 64 + i * 16 + q * 4;
        #pragma unroll
        for (int j = 0; j < 4; ++j) {
            int colg = wn * 64 + j * 16 + r;
            if (colg >= N) continue;
            float bv = bias[colg];
            #pragma unroll
            for (int rr = 0; rr < 4; ++rr) {
                int rowg = rowb + rr;
                if (rowg < M) C[(size_t)rowg * ldc + colg] = acc[i][j][rr] + bv;
            }
        }
    }
}

// ================== fused bond kernel ==================
__global__ __launch_bounds__(256) void k_bond_fused(
    const int* __restrict__ csr, const int* __restrict__ rowcsr, const int* __restrict__ eidarr,
    const int* __restrict__ types, const int* __restrict__ pvarr, const int* __restrict__ pv_tab,
    const u16* __restrict__ uv, const float* __restrict__ bc_w1,
    const u16* __restrict__ BtW2, const float* __restrict__ bc_b2,
    const float* __restrict__ bc_w3, const float* __restrict__ bc_b3,
    float* __restrict__ bl_out)
{
    __shared__ u16 T1s[16384];     // 32 KB: 4 chunks x [128 rows][32 k]; reused as f32 T2 [128][64]
    __shared__ u16 Bs[16384];      // 32 KB: 4 chunks x [128 cols][32 k]
    __shared__ float w5s[128], w6s[128], W3s[256], b2s[64], b3s[4];
    __shared__ int pvts[16];

    int t = threadIdx.x;
    int p0 = blockIdx.x * 128;

    if (t < 128) { w5s[t] = bc_w1[512 * 128 + t]; w6s[t] = bc_w1[513 * 128 + t]; }
    if (t < 256) W3s[t] = bc_w3[t];
    if (t < 64) b2s[t] = bc_b2[t];
    if (t < 4)  b3s[t] = bc_b3[t];
    if (t < 11) pvts[t] = pv_tab[t];
    #pragma unroll
    for (int c = 0; c < 4; ++c) {
        GLL(BtW2 + (size_t)(t >> 2) * 128 + c * 32 + (t & 3) * 8,        Bs + c * 4096 + t * 8);
        GLL(BtW2 + (size_t)(64 + (t >> 2)) * 128 + c * 32 + (t & 3) * 8, Bs + c * 4096 + 2048 + t * 8);
    }

    int l = t >> 1;            // local row 0..127
    int half = t & 1;          // which 64-col half
    int pos = p0 + l;
    int prow = 0, pk = 0;
    if (pos < N_EDGES) { prow = rowcsr[pos]; pk = csr[pos]; }
    int pcol = pk & 0xFFFFF;
    float pvr = (float)pvarr[prow];
    __syncthreads();   // w5s/w6s/pvts ready (pvts must not be read before this barrier)
    float pvc = (float)pvts[(pk >> 24) & 0xF];

    const u16* up = uv + (size_t)prow * 256 + half * 64;
    const u16* vp = uv + (size_t)pcol * 256 + 128 + half * 64;
    #pragma unroll
    for (int j = 0; j < 8; ++j) {
        int c = half * 64 + j * 8;
        u16x8 uu = *(const u16x8*)(up + j * 8);      // 16 B load
        u16x8 vv = *(const u16x8*)(vp + j * 8);      // 16 B load
        int chunk = c >> 5, kk = c & 31;
        u16x8 o;
        #pragma unroll
        for (int e = 0; e < 8; ++e)
            o[e] = f2bf(fmaxf(bf2f(uu[e]) + bf2f(vv[e]) + pvr * w5s[c + e] + pvc * w6s[c + e], 0.f));
        *(u16x8*)(T1s + chunk * 4096 + l * 32 + kk) = o;   // one ds_write_b128
    }
    __syncthreads();   // T1s + Bs (GLL drained by barrier) ready

    int lane = t & 63, w = t >> 6;
    int wm = w & 1, wn = w >> 1;
    int q = lane >> 4, r = lane & 15;
    f32x4 zero = {0.f, 0.f, 0.f, 0.f};
    f32x4 acc[4][4];
    #pragma unroll
    for (int i = 0; i < 4; ++i)
        #pragma unroll
        for (int j = 0; j < 4; ++j) acc[i][j] = zero;
    #pragma unroll
    for (int c = 0; c < 4; ++c) {
        bf16x8 af[4], bfr[4];
        #pragma unroll
        for (int i = 0; i < 4; ++i)
            af[i] = *(const bf16x8*)&T1s[c * 4096 + (wm * 64 + i * 16 + r) * 32 + q * 8];
        #pragma unroll
        for (int j = 0; j < 4; ++j)
            bfr[j] = *(const bf16x8*)&Bs[c * 4096 + (wn * 64 + j * 16 + r) * 32 + q * 8];
        #pragma unroll
        for (int i = 0; i < 4; ++i)
            #pragma unroll
            for (int j = 0; j < 4; ++j)
                acc[i][j] = __builtin_amdgcn_mfma_f32_16x16x32_bf16(af[i], bfr[j], acc[i][j], 0, 0, 0);
    }
    __syncthreads();   // all T1s reads done; reuse as f32 T2

    float* T2f = (float*)T1s;   // [128][64]
    if (wn == 0) {
        #pragma unroll
        for (int i = 0; i < 4; ++i) {
            int row = wm * 64 + i * 16 + q * 4;
            #pragma unroll
            for (int j = 0; j < 4; ++j) {
                int col = j * 16 + r;
                float bv = b2s[col];
                #pragma unroll
                for (int rr = 0; rr < 4; ++rr)
                    T2f[(row + rr) * 64 + col] = fmaxf(acc[i][j][rr] + bv, 0.f);
            }
        }
    }
    __syncthreads();

    if (t < 128) {
        int pos3 = p0 + t;
        if (pos3 < N_EDGES) {
            float a0 = b3s[0], a1 = b3s[1], a2 = b3s[2], a3 = b3s[3];
            const float* trow = &T2f[t * 64];
            #pragma unroll 8
            for (int kk = 0; kk < 64; ++kk) {
                int k = (kk + t) & 63;           // rotate start: spread banks across lanes
                float tv = trow[k];
                float4 w3 = *(const float4*)&W3s[k * 4];   // one b128 LDS read
                a0 += tv * w3.x;
                a1 += tv * w3.y;
                a2 += tv * w3.z;
                a3 += tv * w3.w;
            }
            int prow3 = rowcsr[pos3];
            int pk3 = csr[pos3];
            int tc = (pk3 >> 24) & 0xF;
            int tr = types[prow3];
            int pr = pvarr[prow3];
            int pc = pvts[tc];
            float halogen = (tr == 4 || tr == 5 || tc == 4 || tc == 5) ? 1.f : 0.f;
            float l1 = (pr <= 1 || pc <= 1) ? 1.f : 0.f;
            float l2 = (pr <= 2 || pc <= 2) ? 1.f : 0.f;
            float pen13 = -100.f * halogen - 50.f * l1;
            a1 += pen13;
            a3 += pen13;
            a2 += pen13 - 50.f * l2;
            int eid = eidarr[pos3];
            *(float4*)&bl_out[(size_t)eid * 4] = make_float4(a0, a1, a2, a3);
        }
    }
}

// ================================================================
extern "C" void kernel_launch(void* const* d_in, const int* in_sizes, int n_in,
                              void* d_out, int out_size, void* d_ws, size_t ws_size,
                              hipStream_t stream)
{
    const float* x          = (const float*)d_in[0];
    const float* edge_attr  = (const float*)d_in[1];
    const float* atom_emb   = (const float*)d_in[2];
    const float* bond_emb   = (const float*)d_in[3];
    const float* vp_w1      = (const float*)d_in[4];
    const float* vp_b1      = (const float*)d_in[5];
    const float* vp_w2      = (const float*)d_in[6];
    const float* vp_b2      = (const float*)d_in[7];
    const float* gnn_wself  = (const float*)d_in[8];
    const float* gnn_bself  = (const float*)d_in[9];
    const float* gnn_wmsg   = (const float*)d_in[10];
    const float* gnn_bmsg   = (const float*)d_in[11];
    const float* bc_w1      = (const float*)d_in[12];
    const float* bc_b1      = (const float*)d_in[13];
    const float* bc_w2      = (const float*)d_in[14];
    const float* bc_b2      = (const float*)d_in[15];
    const float* bc_w3      = (const float*)d_in[16];
    const float* bc_b3      = (const float*)d_in[17];
    const float* cp_w1      = (const float*)d_in[18];
    const float* cp_b1      = (const float*)d_in[19];
    const float* cp_w2      = (const float*)d_in[20];
    const float* cp_b2      = (const float*)d_in[21];
    const int*   ei         = (const int*)d_in[22];

    float* out    = (float*)d_out;
    float* h_out  = out + H_OFF;
    float* cp_out = out + CP_OFF;
    float* vl_out = out + VL_OFF;
    float* bl_out = out + BL_OFF;
    float* vi_out = out + VI_OFF;

    // ---- workspace layout ----
    char* base = (char*)d_ws;
    const size_t S = (size_t)M_PAD * 256 * 2;   // 51,249,152 B
    u16* h_bf  = (u16*)(base + 0 * S);           // R0: h ; later uv
    u16* uv_bf = (u16*)(base + 0 * S);
    u16* hm_bf = (u16*)(base + 1 * S);           // R1: hm
    u16* hs_bf = (u16*)(base + 2 * S);           // R2: hs
    u16* hd_bf = (u16*)(base + 3 * S);           // R3: damped h bf16
    u16* cp1_bf= (u16*)(base + 4 * S);           // R4: [M_PAD][128] bf16
    char* w    = base + 4 * S + (size_t)M_PAD * 128 * 2;
    int* degree  = (int*)w; w += (size_t)N_NODES * 4;
    int* offsets = (int*)w; w += (size_t)N_NODES * 4;
    int* cursor  = (int*)w; w += (size_t)N_NODES * 4;
    int* types   = (int*)w; w += (size_t)N_NODES * 4;
    int* pvarr   = (int*)w; w += (size_t)N_NODES * 4;
    int* csr     = (int*)w; w += (size_t)E_PAD * 4;
    int* rowcsr  = (int*)w; w += (size_t)E_PAD * 4;
    int* eidarr  = (int*)w; w += (size_t)E_PAD * 4;
    int* bsum    = (int*)w; w += 4096;
    int* bbase   = (int*)w; w += 4096;
    int* pv_tab  = (int*)w; w += 1024;
    float* vl_tab    = (float*)w; w += 2048;
    float* h0_tab    = (float*)w; w += 11 * 256 * 4;
    float* self0_tab = (float*)w; w += 11 * 256 * 4;
    float* msg0_tab  = (float*)w; w += 55 * 256 * 4;
    float* bondtab   = (float*)w; w += 2 * 5 * 256 * 4;
    u16* BtL1  = (u16*)w; w += 512 * 256 * 2;
    u16* BtL2  = (u16*)w; w += 512 * 256 * 2;
    u16* Bt3   = (u16*)w; w += 384 * 256 * 2;
    u16* BtW2  = (u16*)w; w += 128 * 128 * 2;
    u16* BtCP2 = (u16*)w; w += 128 * 128 * 2;
    float* bias512  = (float*)w; w += 2 * 512 * 4;
    float* biasPost = (float*)w; w += 384 * 4;

    // ---- setup ----
    k_type_mlp<<<1, 256, 0, stream>>>(atom_emb, vp_w1, vp_b1, vp_w2, vp_b2, pv_tab, vl_tab, h0_tab);
    k_tables<<<76, 256, 0, stream>>>(bond_emb, gnn_wself, gnn_bself, gnn_wmsg, gnn_bmsg,
                                     h0_tab, self0_tab, msg0_tab, bondtab);
    k_wtrans<<<1664, 256, 0, stream>>>(gnn_wmsg, gnn_wself, bc_w1, cp_w1, bc_w2, cp_w2,
                                       BtL1, BtL2, Bt3, BtW2, BtCP2);
    k_setup_bias<<<6, 256, 0, stream>>>(gnn_bself, bc_b1, cp_b1, bias512, biasPost);
    k_node_init<<<(N_NODES + 255) / 256, 256, 0, stream>>>(x, pv_tab, vl_tab, types, pvarr, degree, vl_out);
    k_edge_deg<<<(N_EDGES + 255) / 256, 256, 0, stream>>>(ei, degree);
    int nb = (N_NODES + SCAN_B - 1) / SCAN_B;
    k_scan1<<<nb, SCAN_B, 0, stream>>>(degree, offsets, bsum);
    k_scan2<<<1, 128, 0, stream>>>(bsum, bbase, nb);
    k_scan3<<<nb, SCAN_B, 0, stream>>>(offsets, bbase, cursor);
    k_csr_fill<<<(N_EDGES + 255) / 256, 256, 0, stream>>>(ei, edge_attr, types, cursor, csr, rowcsr, eidarr);
    k_agg0<<<N_NODES / 4, 256, 0, stream>>>(offsets, degree, types, self0_tab, msg0_tab, csr, h_bf);

    // ---- GNN layers 1,2 (l=2 fuses damp/viol/h_out) ----
    const int MT = M_PAD / 128;           // 782
    const int QB = (MT + 7) / 8;          // 98
    for (int l = 1; l <= 2; ++l) {
        const u16* BtL = (l == 1) ? BtL1 : BtL2;
        k_gemm_dual<<<QB * 32, 256, 0, stream>>>(h_bf, BtL, bias512 + (size_t)(l - 1) * 512,
                                                 hm_bf, hs_bf, N_NODES, MT);
        k_agg12<<<N_NODES / 4, 256, 0, stream>>>(offsets, degree, hs_bf, hm_bf,
                                                 bondtab + (size_t)(l - 1) * 5 * 256, csr, h_bf,
                                                 (l == 2) ? 1 : 0, pvarr, h_out, hd_bf, vi_out);
    }

    // ---- uv + cp1 fused; then cp2 ----
    k_gemm_post<<<QB * 24, 256, 0, stream>>>(hd_bf, Bt3, biasPost, uv_bf, cp1_bf, N_NODES, MT);
    k_gemm_k128<<<MT, 256, 0, stream>>>(cp1_bf, BtCP2, cp_b2, cp_out, 32, N_NODES, 32);

    // ---- fused bond chain ----
    k_bond_fused<<<E_PAD / 128, 256, 0, stream>>>(csr, rowcsr, eidarr, types, pvarr, pv_tab,
                                                  uv_bf, bc_w1, BtW2, bc_b2, bc_w3, bc_b3, bl_out);
}

// Round 10
// 576.024 us; speedup vs baseline: 1.3283x; 1.0144x over previous
//
#include <hip/hip_runtime.h>

#define N_NODES 100000
#define N_EDGES 300000
#define M_PAD   100096   // 782*128
#define E_PAD   300032   // 2344*128

typedef unsigned short u16;
typedef short bf16x8 __attribute__((ext_vector_type(8)));
typedef float f32x4  __attribute__((ext_vector_type(4)));
typedef unsigned short u16x8 __attribute__((ext_vector_type(8)));

__device__ __forceinline__ float bf2f(u16 u) {
    unsigned x = ((unsigned)u) << 16;
    return __builtin_bit_cast(float, x);
}
__device__ __forceinline__ u16 f2bf(float f) {
    unsigned u = __builtin_bit_cast(unsigned, f);
    unsigned r = (u + 0x7FFF + ((u >> 16) & 1)) >> 16;
    return (u16)r;
}

// ---------------- output layout (floats) ----------------
#define H_OFF   0
#define CP_OFF  25600000
#define VL_OFF  28800000
#define BL_OFF  29600000
#define VI_OFF  30800000

#define GLL(gp, lp) __builtin_amdgcn_global_load_lds( \
    (const __attribute__((address_space(1))) unsigned int*)(gp), \
    (__attribute__((address_space(3))) unsigned int*)(lp), 16, 0, 0)

// ============ per-atom-type valence MLP + h0 rows ============
__global__ void k_type_mlp(const float* __restrict__ atom_emb,
                           const float* __restrict__ vp_w1, const float* __restrict__ vp_b1,
                           const float* __restrict__ vp_w2, const float* __restrict__ vp_b2,
                           int* __restrict__ pv_tab, float* __restrict__ vl_tab,
                           float* __restrict__ h0_tab)
{
    int tid = threadIdx.x;
    for (int i = tid; i < 11 * 256; i += 256) h0_tab[i] = 0.f;
    __syncthreads();
    if (tid < 11) {
        int t = tid;
        const float* ae = atom_emb + t * 64;
        float lg[8];
        #pragma unroll
        for (int c = 0; c < 8; ++c) lg[c] = vp_b2[c];
        for (int j = 0; j < 32; ++j) {
            float z = vp_b1[j];
            for (int d = 0; d < 64; ++d) z += ae[d] * vp_w1[d * 32 + j];
            z = fmaxf(z, 0.f);
            #pragma unroll
            for (int c = 0; c < 8; ++c) lg[c] += z * vp_w2[j * 8 + c];
        }
        int best = 0;
        #pragma unroll
        for (int c = 1; c < 8; ++c) if (lg[c] > lg[best]) best = c;
        pv_tab[t] = best + 1;
        for (int c = 0; c < 8; ++c) vl_tab[t * 8 + c] = lg[c];
        float* h0 = h0_tab + t * 256;
        for (int d = 0; d < 64; ++d) h0[d] = ae[d];
        h0[64 + best] = 1.f;
    }
}

// ============ layer-0 tables + bond tables for layers 1,2 ============
__global__ void k_tables(const float* __restrict__ bond_emb,
                         const float* __restrict__ gnn_wself, const float* __restrict__ gnn_bself,
                         const float* __restrict__ gnn_wmsg, const float* __restrict__ gnn_bmsg,
                         const float* __restrict__ h0_tab,
                         float* __restrict__ self0_tab, float* __restrict__ msg0_tab,
                         float* __restrict__ bondtab)
{
    int b = blockIdx.x, c = threadIdx.x;
    if (b < 11) {
        int t = b;
        const float* h0 = h0_tab + t * 256;
        float acc = gnn_bself[c];
        for (int k = 0; k < 256; ++k) acc += h0[k] * gnn_wself[k * 256 + c];
        self0_tab[t * 256 + c] = acc;
    } else if (b < 66) {
        int idx = b - 11; int t = idx / 5, bb = idx % 5;
        const float* h0 = h0_tab + t * 256;
        float acc = gnn_bmsg[c];
        for (int k = 0; k < 256; ++k) acc += h0[k] * gnn_wmsg[k * 256 + c];
        const float* be = bond_emb + bb * 64;
        for (int k = 0; k < 64; ++k) acc += be[k] * gnn_wmsg[(256 + k) * 256 + c];
        msg0_tab[idx * 256 + c] = fmaxf(acc, 0.f);
    } else {
        int idx = b - 66; int l = idx / 5 + 1, bb = idx % 5;
        const float* w = gnn_wmsg + (size_t)l * 320 * 256;
        const float* be = bond_emb + bb * 64;
        float acc = gnn_bmsg[l * 256 + c];
        for (int k = 0; k < 64; ++k) acc += be[k] * w[(256 + k) * 256 + c];
        bondtab[(l - 1) * 5 * 256 + bb * 256 + c] = acc;
    }
}

// ============ bf16-transposed weight tables ============
__global__ void k_wtrans(const float* __restrict__ wmsg, const float* __restrict__ wself,
                         const float* __restrict__ bcw1, const float* __restrict__ cpw1,
                         const float* __restrict__ bcw2, const float* __restrict__ cpw2,
                         u16* __restrict__ BtL1, u16* __restrict__ BtL2, u16* __restrict__ Bt3,
                         u16* __restrict__ BtW2, u16* __restrict__ BtCP2)
{
    int b = blockIdx.x, k = threadIdx.x;
    if (b < 512) {
        int n = b;
        float v = (n < 256) ? wmsg[(size_t)1 * 320 * 256 + (size_t)k * 256 + n]
                            : wself[(size_t)1 * 256 * 256 + (size_t)k * 256 + (n - 256)];
        BtL1[n * 256 + k] = f2bf(v);
    } else if (b < 1024) {
        int n = b - 512;
        float v = (n < 256) ? wmsg[(size_t)2 * 320 * 256 + (size_t)k * 256 + n]
                            : wself[(size_t)2 * 256 * 256 + (size_t)k * 256 + (n - 256)];
        BtL2[n * 256 + k] = f2bf(v);
    } else if (b < 1408) {
        int n = b - 1024;
        float v;
        if (n < 128)      v = bcw1[k * 128 + n];
        else if (n < 256) v = bcw1[(256 + k) * 128 + (n - 128)];
        else              v = cpw1[k * 128 + (n - 256)];
        Bt3[n * 256 + k] = f2bf(v);
    } else if (b < 1536) {
        int n = b - 1408;
        if (k < 128) BtW2[n * 128 + k] = f2bf(n < 64 ? bcw2[k * 64 + n] : 0.f);
    } else {
        int n = b - 1536;
        if (k < 128) BtCP2[n * 128 + k] = f2bf(n < 32 ? cpw2[k * 32 + n] : 0.f);
    }
}

__global__ void k_setup_bias(const float* __restrict__ bself, const float* __restrict__ bcb1,
                             const float* __restrict__ cpb1,
                             float* __restrict__ bias512, float* __restrict__ biasPost)
{
    int i = blockIdx.x * 256 + threadIdx.x;
    if (i < 1024) {
        int l = i >> 9, c = i & 511;
        bias512[l * 512 + c] = (c < 256) ? 0.f : bself[(l + 1) * 256 + (c - 256)];
    } else if (i < 1408) {
        int c = i - 1024;
        biasPost[c] = (c < 128) ? bcb1[c] : ((c < 256) ? 0.f : cpb1[c - 256]);
    }
}

// ============ node init ============
__global__ void k_node_init(const float* __restrict__ x, const int* __restrict__ pv_tab,
                            const float* __restrict__ vl_tab,
                            int* __restrict__ types, int* __restrict__ pvarr,
                            int* __restrict__ degree, float* __restrict__ vl_out)
{
    int i = blockIdx.x * blockDim.x + threadIdx.x;
    if (i >= N_NODES) return;
    int t = (int)x[i * 16];
    t = min(max(t, 0), 10);
    types[i] = t;
    pvarr[i] = pv_tab[t];
    degree[i] = 0;
    float4 v0 = *(const float4*)&vl_tab[t * 8];
    float4 v1 = *(const float4*)&vl_tab[t * 8 + 4];
    *(float4*)&vl_out[i * 8]     = v0;
    *(float4*)&vl_out[i * 8 + 4] = v1;
}

__global__ void k_edge_deg(const int* __restrict__ ei, int* __restrict__ degree)
{
    int e = blockIdx.x * blockDim.x + threadIdx.x;
    if (e >= N_EDGES) return;
    atomicAdd(&degree[ei[e]], 1);
}

// ============ scan ============
#define SCAN_B 1024
__global__ void k_scan1(const int* __restrict__ degree, int* __restrict__ part, int* __restrict__ bsum)
{
    __shared__ int s[SCAN_B];
    int tid = threadIdx.x;
    int i = blockIdx.x * SCAN_B + tid;
    int v = (i < N_NODES) ? degree[i] : 0;
    s[tid] = v; __syncthreads();
    for (int off = 1; off < SCAN_B; off <<= 1) {
        int t = (tid >= off) ? s[tid - off] : 0;
        __syncthreads();
        s[tid] += t;
        __syncthreads();
    }
    if (i < N_NODES) part[i] = s[tid] - v;
    if (tid == SCAN_B - 1) bsum[blockIdx.x] = s[tid];
}

__global__ void k_scan2(const int* __restrict__ bsum, int* __restrict__ bbase, int nb)
{
    __shared__ int s[128];
    int tid = threadIdx.x;
    int v = (tid < nb) ? bsum[tid] : 0;
    s[tid] = v; __syncthreads();
    for (int off = 1; off < 128; off <<= 1) {
        int t = (tid >= off) ? s[tid - off] : 0;
        __syncthreads();
        s[tid] += t;
        __syncthreads();
    }
    bbase[tid] = s[tid] - v;
}

__global__ void k_scan3(int* __restrict__ part, const int* __restrict__ bbase, int* __restrict__ cursor)
{
    int i = blockIdx.x * SCAN_B + threadIdx.x;
    if (i >= N_NODES) return;
    int o = part[i] + bbase[blockIdx.x];
    part[i] = o;
    cursor[i] = o;
}

// ============ CSR fill (+ row/eid side arrays for the bond pass) ============
__global__ void k_csr_fill(const int* __restrict__ ei, const float* __restrict__ edge_attr,
                           const int* __restrict__ types, int* __restrict__ cursor,
                           int* __restrict__ csr, int* __restrict__ rowcsr, int* __restrict__ eidarr)
{
    int e = blockIdx.x * blockDim.x + threadIdx.x;
    if (e >= N_EDGES) return;
    int row = ei[e], col = ei[N_EDGES + e];
    int bt = (int)edge_attr[e * 4];
    bt = min(max(bt, 0), 4);
    int pos = atomicAdd(&cursor[row], 1);
    csr[pos] = col | (bt << 20) | (types[col] << 24);
    rowcsr[pos] = row;
    eidarr[pos] = e;
}

// ============ layer-0 aggregation (tables) -> h bf16 ============
__global__ __launch_bounds__(256) void k_agg0(const int* __restrict__ offsets, const int* __restrict__ degree,
                       const int* __restrict__ types,
                       const float* __restrict__ self0_tab, const float* __restrict__ msg0_tab,
                       const int* __restrict__ csr, u16* __restrict__ h)
{
    int wid = threadIdx.x >> 6, lane = threadIdx.x & 63;
    int node = blockIdx.x * 4 + wid;
    if (node >= N_NODES) return;
    int t = types[node];
    float4 acc = *(const float4*)&self0_tab[t * 256 + lane * 4];
    int start = offsets[node], deg = degree[node];
    int pj = (lane < deg) ? csr[start + lane] : 0;
    int dmax = min(deg, 64);
    for (int j = 0; j < dmax; ++j) {
        int p = __shfl(pj, j);
        int combo = ((p >> 24) & 0xF) * 5 + ((p >> 20) & 7);
        float4 m = *(const float4*)&msg0_tab[combo * 256 + lane * 4];
        acc.x += m.x; acc.y += m.y; acc.z += m.z; acc.w += m.w;
    }
    for (int j = 64; j < deg; ++j) {   // practically unreachable (Poisson(3))
        int p = csr[start + j];
        int combo = ((p >> 24) & 0xF) * 5 + ((p >> 20) & 7);
        float4 m = *(const float4*)&msg0_tab[combo * 256 + lane * 4];
        acc.x += m.x; acc.y += m.y; acc.z += m.z; acc.w += m.w;
    }
    ushort4 r;
    r.x = f2bf(fmaxf(acc.x, 0.f)); r.y = f2bf(fmaxf(acc.y, 0.f));
    r.z = f2bf(fmaxf(acc.z, 0.f)); r.w = f2bf(fmaxf(acc.w, 0.f));
    *(ushort4*)&h[(size_t)node * 256 + lane * 4] = r;
}

// ============ layers 1,2 aggregation; shfl-prefetched csr + 1-deep hm pipeline ============
__global__ __launch_bounds__(256) void k_agg12(const int* __restrict__ offsets, const int* __restrict__ degree,
                        const u16* __restrict__ hs, const u16* __restrict__ hm,
                        const float* __restrict__ bondtab, const int* __restrict__ csr,
                        u16* __restrict__ h, int final_layer, const int* __restrict__ pvarr,
                        float* __restrict__ h_out, u16* __restrict__ hd_bf, float* __restrict__ viol_out)
{
    int wid = threadIdx.x >> 6, lane = threadIdx.x & 63;
    int node = blockIdx.x * 4 + wid;
    if (node >= N_NODES) return;
    ushort4 s4 = *(const ushort4*)&hs[(size_t)node * 256 + lane * 4];
    float ax = bf2f(s4.x), ay = bf2f(s4.y), az = bf2f(s4.z), aw = bf2f(s4.w);
    int start = offsets[node], deg = degree[node];
    int pj = (lane < deg) ? csr[start + lane] : 0;
    int dmax = min(deg, 64);
    if (dmax > 0) {
        int p0 = __shfl(pj, 0);
        ushort4 m0 = *(const ushort4*)&hm[(size_t)(p0 & 0xFFFFF) * 256 + lane * 4];
        for (int j = 1; j < dmax; ++j) {
            int p1 = __shfl(pj, j);
            ushort4 m1 = *(const ushort4*)&hm[(size_t)(p1 & 0xFFFFF) * 256 + lane * 4];  // in flight during j-1 math
            float4 bb = *(const float4*)&bondtab[((p0 >> 20) & 7) * 256 + lane * 4];
            ax += fmaxf(bf2f(m0.x) + bb.x, 0.f);
            ay += fmaxf(bf2f(m0.y) + bb.y, 0.f);
            az += fmaxf(bf2f(m0.z) + bb.z, 0.f);
            aw += fmaxf(bf2f(m0.w) + bb.w, 0.f);
            m0 = m1; p0 = p1;
        }
        float4 bb = *(const float4*)&bondtab[((p0 >> 20) & 7) * 256 + lane * 4];
        ax += fmaxf(bf2f(m0.x) + bb.x, 0.f);
        ay += fmaxf(bf2f(m0.y) + bb.y, 0.f);
        az += fmaxf(bf2f(m0.z) + bb.z, 0.f);
        aw += fmaxf(bf2f(m0.w) + bb.w, 0.f);
    }
    for (int j = 64; j < deg; ++j) {   // practically unreachable
        int p = csr[start + j];
        int c = p & 0xFFFFF;
        int bt = (p >> 20) & 7;
        ushort4 m4 = *(const ushort4*)&hm[(size_t)c * 256 + lane * 4];
        float4 bb = *(const float4*)&bondtab[bt * 256 + lane * 4];
        ax += fmaxf(bf2f(m4.x) + bb.x, 0.f);
        ay += fmaxf(bf2f(m4.y) + bb.y, 0.f);
        az += fmaxf(bf2f(m4.z) + bb.z, 0.f);
        aw += fmaxf(bf2f(m4.w) + bb.w, 0.f);
    }
    ax = fmaxf(ax, 0.f); ay = fmaxf(ay, 0.f); az = fmaxf(az, 0.f); aw = fmaxf(aw, 0.f);
    if (!final_layer) {
        ushort4 r;
        r.x = f2bf(ax); r.y = f2bf(ay); r.z = f2bf(az); r.w = f2bf(aw);
        *(ushort4*)&h[(size_t)node * 256 + lane * 4] = r;
    } else {
        float viol = fmaxf((float)deg - (float)pvarr[node], 0.f);
        float s = 1.f / (1.f + viol);
        ax *= s; ay *= s; az *= s; aw *= s;
        float4 v = make_float4(ax, ay, az, aw);
        *(float4*)&h_out[(size_t)node * 256 + lane * 4] = v;
        ushort4 r;
        r.x = f2bf(ax); r.y = f2bf(ay); r.z = f2bf(az); r.w = f2bf(aw);
        *(ushort4*)&hd_bf[(size_t)node * 256 + lane * 4] = r;
        if (lane == 0) viol_out[node] = viol;
    }
}

// ================== layer GEMM: 3-buffer 2-DEEP pipeline + counted vmcnt + setprio ==================
__global__ __launch_bounds__(256) void k_gemm_dual(
    const u16* __restrict__ A, const u16* __restrict__ Bt,
    const float* __restrict__ bias512,
    u16* __restrict__ Dm, u16* __restrict__ Ds, int M, int MT)
{
    __shared__ u16 S[24576];          // 48 KB: buf i at S + i*8192 (A) / +4096 (B), i=0..2
    u16* Cs = S;                      // epilogue reuse [128][128]
    int b = blockIdx.x;
    int rsub = b & 31;
    int nt = rsub >> 3, m8 = rsub & 7;
    int mt = (b >> 5) * 8 + m8;
    if (mt >= MT) return;
    int bm = mt * 128, bn = nt * 128;

    int t = threadIdx.x;
    int lane = t & 63, w = t >> 6;
    int wm = w & 1, wn = w >> 1;
    f32x4 zero = {0.f, 0.f, 0.f, 0.f};
    f32x4 acc[4][4];
    #pragma unroll
    for (int i = 0; i < 4; ++i)
        #pragma unroll
        for (int j = 0; j < 4; ++j) acc[i][j] = zero;

    int arow = t >> 2, acol = (t & 3) * 8;
    const u16* Ag = A + (size_t)(bm + arow) * 256 + acol;
    const u16* Bg = Bt + (size_t)(bn + arow) * 256 + acol;
    int q = lane >> 4, r = lane & 15;

    // prologue: stage k-steps 0 and 1 (2-deep)
    GLL(Ag,                 S + t * 8);
    GLL(Ag + 64 * 256,      S + 2048 + t * 8);
    GLL(Bg,                 S + 4096 + t * 8);
    GLL(Bg + 64 * 256,      S + 4096 + 2048 + t * 8);
    GLL(Ag + 32,            S + 8192 + t * 8);
    GLL(Ag + 64 * 256 + 32, S + 8192 + 2048 + t * 8);
    GLL(Bg + 32,            S + 8192 + 4096 + t * 8);
    GLL(Bg + 64 * 256 + 32, S + 8192 + 4096 + 2048 + t * 8);

    #pragma unroll
    for (int ks = 0; ks < 8; ++ks) {
        int cb = (ks % 3) * 8192;
        if (ks < 7) {
            asm volatile("s_waitcnt vmcnt(4)" ::: "memory");
        } else {
            asm volatile("s_waitcnt vmcnt(0)" ::: "memory");
        }
        __builtin_amdgcn_s_barrier();
        __builtin_amdgcn_sched_barrier(0);
        if (ks < 6) {
            int nb = ((ks + 2) % 3) * 8192;
            int k0 = (ks + 2) * 32;
            GLL(Ag + k0,            S + nb + t * 8);
            GLL(Ag + 64 * 256 + k0, S + nb + 2048 + t * 8);
            GLL(Bg + k0,            S + nb + 4096 + t * 8);
            GLL(Bg + 64 * 256 + k0, S + nb + 4096 + 2048 + t * 8);
        }
        bf16x8 af[4], bfr[4];
        #pragma unroll
        for (int i = 0; i < 4; ++i)
            af[i] = *(const bf16x8*)&S[cb + (wm * 64 + i * 16 + r) * 32 + q * 8];
        #pragma unroll
        for (int j = 0; j < 4; ++j)
            bfr[j] = *(const bf16x8*)&S[cb + 4096 + (wn * 64 + j * 16 + r) * 32 + q * 8];
        __builtin_amdgcn_s_setprio(1);
        #pragma unroll
        for (int i = 0; i < 4; ++i)
            #pragma unroll
            for (int j = 0; j < 4; ++j)
                acc[i][j] = __builtin_amdgcn_mfma_f32_16x16x32_bf16(af[i], bfr[j], acc[i][j], 0, 0, 0);
        __builtin_amdgcn_s_setprio(0);
    }
    __syncthreads();   // all last-buffer reads done before Cs overwrite (vmcnt already 0)

    // ---- epilogue: acc -> LDS C-tile (bias fused), then full-line stores ----
    #pragma unroll
    for (int i = 0; i < 4; ++i) {
        int rowl = wm * 64 + i * 16 + q * 4;
        #pragma unroll
        for (int j = 0; j < 4; ++j) {
            int coll = wn * 64 + j * 16 + r;
            float bv = bias512[bn + coll];
            #pragma unroll
            for (int rr = 0; rr < 4; ++rr)
                Cs[(rowl + rr) * 128 + coll] = f2bf(acc[i][j][rr] + bv);
        }
    }
    __syncthreads();
    u16* Dbase = (nt < 2) ? (Dm + bn) : (Ds + (bn - 256));
    int c16 = (t & 15) * 8, rbase = t >> 4;
    #pragma unroll
    for (int g = 0; g < 8; ++g) {
        int rowl = rbase + g * 16;
        int rowg = bm + rowl;
        if (rowg < M) {
            u16x8 v = *(const u16x8*)&Cs[rowl * 128 + c16];
            *(u16x8*)&Dbase[(size_t)rowg * 256 + c16] = v;
        }
    }
}

// ================== post GEMM (N=384): 2-deep pipeline; nt==2 fuses cp2 ==================
// nt<2 blocks: uv tile as before. nt==2 blocks: cp1 tile stays in LDS (no global store);
// cp2 = relu-cp1[128][128] @ BtCP2 (K=128) computed in-place by waves wn<2, output f32 direct.
__global__ __launch_bounds__(256) void k_gemm_post(
    const u16* __restrict__ A, const u16* __restrict__ Bt3,
    const float* __restrict__ biasPost,
    u16* __restrict__ UV, const u16* __restrict__ BtCP2, const float* __restrict__ cp_b2,
    float* __restrict__ CPOUT, int M, int MT)
{
    __shared__ u16 S[24576];
    u16* Cs = S;
    int b = blockIdx.x;
    int rsub = b % 24;
    int nt = rsub >> 3, m8 = rsub & 7;
    int mt = (b / 24) * 8 + m8;
    if (mt >= MT) return;
    int bm = mt * 128, bn = nt * 128;

    int t = threadIdx.x;
    int lane = t & 63, w = t >> 6;
    int wm = w & 1, wn = w >> 1;
    f32x4 zero = {0.f, 0.f, 0.f, 0.f};
    f32x4 acc[4][4];
    #pragma unroll
    for (int i = 0; i < 4; ++i)
        #pragma unroll
        for (int j = 0; j < 4; ++j) acc[i][j] = zero;

    int arow = t >> 2, acol = (t & 3) * 8;
    const u16* Ag = A + (size_t)(bm + arow) * 256 + acol;
    const u16* Bg = Bt3 + (size_t)(bn + arow) * 256 + acol;
    int q = lane >> 4, r = lane & 15;

    GLL(Ag,                 S + t * 8);
    GLL(Ag + 64 * 256,      S + 2048 + t * 8);
    GLL(Bg,                 S + 4096 + t * 8);
    GLL(Bg + 64 * 256,      S + 4096 + 2048 + t * 8);
    GLL(Ag + 32,            S + 8192 + t * 8);
    GLL(Ag + 64 * 256 + 32, S + 8192 + 2048 + t * 8);
    GLL(Bg + 32,            S + 8192 + 4096 + t * 8);
    GLL(Bg + 64 * 256 + 32, S + 8192 + 4096 + 2048 + t * 8);

    #pragma unroll
    for (int ks = 0; ks < 8; ++ks) {
        int cb = (ks % 3) * 8192;
        if (ks < 7) {
            asm volatile("s_waitcnt vmcnt(4)" ::: "memory");
        } else {
            asm volatile("s_waitcnt vmcnt(0)" ::: "memory");
        }
        __builtin_amdgcn_s_barrier();
        __builtin_amdgcn_sched_barrier(0);
        if (ks < 6) {
            int nb = ((ks + 2) % 3) * 8192;
            int k0 = (ks + 2) * 32;
            GLL(Ag + k0,            S + nb + t * 8);
            GLL(Ag + 64 * 256 + k0, S + nb + 2048 + t * 8);
            GLL(Bg + k0,            S + nb + 4096 + t * 8);
            GLL(Bg + 64 * 256 + k0, S + nb + 4096 + 2048 + t * 8);
        }
        bf16x8 af[4], bfr[4];
        #pragma unroll
        for (int i = 0; i < 4; ++i)
            af[i] = *(const bf16x8*)&S[cb + (wm * 64 + i * 16 + r) * 32 + q * 8];
        #pragma unroll
        for (int j = 0; j < 4; ++j)
            bfr[j] = *(const bf16x8*)&S[cb + 4096 + (wn * 64 + j * 16 + r) * 32 + q * 8];
        __builtin_amdgcn_s_setprio(1);
        #pragma unroll
        for (int i = 0; i < 4; ++i)
            #pragma unroll
            for (int j = 0; j < 4; ++j)
                acc[i][j] = __builtin_amdgcn_mfma_f32_16x16x32_bf16(af[i], bfr[j], acc[i][j], 0, 0, 0);
        __builtin_amdgcn_s_setprio(0);
    }
    __syncthreads();

    // ---- epilogue: acc -> LDS (bias + relu for cp1 block) ----
    #pragma unroll
    for (int i = 0; i < 4; ++i) {
        int rowl = wm * 64 + i * 16 + q * 4;
        #pragma unroll
        for (int j = 0; j < 4; ++j) {
            int coll = wn * 64 + j * 16 + r;
            float bv = biasPost[bn + coll];
            #pragma unroll
            for (int rr = 0; rr < 4; ++rr) {
                float val = acc[i][j][rr] + bv;
                if (nt == 2) val = fmaxf(val, 0.f);
                Cs[(rowl + rr) * 128 + coll] = f2bf(val);
            }
        }
    }
    __syncthreads();
    if (nt < 2) {
        int c16 = (t & 15) * 8, rbase = t >> 4;
        #pragma unroll
        for (int g = 0; g < 8; ++g) {
            int rowl = rbase + g * 16;
            int rowg = bm + rowl;
            if (rowg < M) {
                u16x8 v = *(const u16x8*)&Cs[rowl * 128 + c16];
                *(u16x8*)&UV[(size_t)rowg * 256 + bn + c16] = v;
            }
        }
    } else if (wn < 2) {
        // ---- fused cp2: Cs (relu cp1 tile, bf16) @ BtCP2 -> CPOUT[128][32] ----
        f32x4 a2[4];
        #pragma unroll
        for (int i = 0; i < 4; ++i) a2[i] = zero;
        #pragma unroll
        for (int kc = 0; kc < 4; ++kc) {
            bf16x8 af2[4];
            #pragma unroll
            for (int i = 0; i < 4; ++i)
                af2[i] = *(const bf16x8*)&Cs[(wm * 64 + i * 16 + r) * 128 + kc * 32 + q * 8];
            bf16x8 bfr2 = *(const bf16x8*)&BtCP2[(size_t)(wn * 16 + r) * 128 + kc * 32 + q * 8];
            #pragma unroll
            for (int i = 0; i < 4; ++i)
                a2[i] = __builtin_amdgcn_mfma_f32_16x16x32_bf16(af2[i], bfr2, a2[i], 0, 0, 0);
        }
        int colg = wn * 16 + r;
        float bv2 = cp_b2[colg];
        #pragma unroll
        for (int i = 0; i < 4; ++i) {
            #pragma unroll
            for (int rr = 0; rr < 4; ++rr) {
                int rowg = bm + wm * 64 + i * 16 + q * 4 + rr;
                if (rowg < M) CPOUT[(size_t)rowg * 32 + colg] = a2[i][rr] + bv2;
            }
        }
    }
}

// ================== fused bond kernel ==================
__global__ __launch_bounds__(256) void k_bond_fused(
    const int* __restrict__ csr, const int* __restrict__ rowcsr, const int* __restrict__ eidarr,
    const int* __restrict__ types, const int* __restrict__ pvarr, const int* __restrict__ pv_tab,
    const u16* __restrict__ uv, const float* __restrict__ bc_w1,
    const u16* __restrict__ BtW2, const float* __restrict__ bc_b2,
    const float* __restrict__ bc_w3, const float* __restrict__ bc_b3,
    float* __restrict__ bl_out)
{
    __shared__ u16 T1s[16384];     // 32 KB: 4 chunks x [128 rows][32 k]; reused as f32 T2 [128][64]
    __shared__ u16 Bs[16384];      // 32 KB: 4 chunks x [128 cols][32 k]
    __shared__ float w5s[128], w6s[128], W3s[256], b2s[64], b3s[4];
    __shared__ int pvts[16];

    int t = threadIdx.x;
    int p0 = blockIdx.x * 128;

    if (t < 128) { w5s[t] = bc_w1[512 * 128 + t]; w6s[t] = bc_w1[513 * 128 + t]; }
    if (t < 256) W3s[t] = bc_w3[t];
    if (t < 64) b2s[t] = bc_b2[t];
    if (t < 4)  b3s[t] = bc_b3[t];
    if (t < 11) pvts[t] = pv_tab[t];
    #pragma unroll
    for (int c = 0; c < 4; ++c) {
        GLL(BtW2 + (size_t)(t >> 2) * 128 + c * 32 + (t & 3) * 8,        Bs + c * 4096 + t * 8);
        GLL(BtW2 + (size_t)(64 + (t >> 2)) * 128 + c * 32 + (t & 3) * 8, Bs + c * 4096 + 2048 + t * 8);
    }

    int l = t >> 1;            // local row 0..127
    int half = t & 1;          // which 64-col half
    int pos = p0 + l;
    int prow = 0, pk = 0;
    if (pos < N_EDGES) { prow = rowcsr[pos]; pk = csr[pos]; }
    int pcol = pk & 0xFFFFF;
    float pvr = (float)pvarr[prow];
    __syncthreads();   // w5s/w6s/pvts ready (pvts must not be read before this barrier)
    float pvc = (float)pvts[(pk >> 24) & 0xF];

    const u16* up = uv + (size_t)prow * 256 + half * 64;
    const u16* vp = uv + (size_t)pcol * 256 + 128 + half * 64;
    #pragma unroll
    for (int j = 0; j < 8; ++j) {
        int c = half * 64 + j * 8;
        u16x8 uu = *(const u16x8*)(up + j * 8);      // 16 B load
        u16x8 vv = *(const u16x8*)(vp + j * 8);      // 16 B load
        int chunk = c >> 5, kk = c & 31;
        u16x8 o;
        #pragma unroll
        for (int e = 0; e < 8; ++e)
            o[e] = f2bf(fmaxf(bf2f(uu[e]) + bf2f(vv[e]) + pvr * w5s[c + e] + pvc * w6s[c + e], 0.f));
        *(u16x8*)(T1s + chunk * 4096 + l * 32 + kk) = o;   // one ds_write_b128
    }
    __syncthreads();   // T1s + Bs (GLL drained by barrier) ready

    int lane = t & 63, w = t >> 6;
    int wm = w & 1, wn = w >> 1;
    int q = lane >> 4, r = lane & 15;
    f32x4 zero = {0.f, 0.f, 0.f, 0.f};
    f32x4 acc[4][4];
    #pragma unroll
    for (int i = 0; i < 4; ++i)
        #pragma unroll
        for (int j = 0; j < 4; ++j) acc[i][j] = zero;
    #pragma unroll
    for (int c = 0; c < 4; ++c) {
        bf16x8 af[4], bfr[4];
        #pragma unroll
        for (int i = 0; i < 4; ++i)
            af[i] = *(const bf16x8*)&T1s[c * 4096 + (wm * 64 + i * 16 + r) * 32 + q * 8];
        #pragma unroll
        for (int j = 0; j < 4; ++j)
            bfr[j] = *(const bf16x8*)&Bs[c * 4096 + (wn * 64 + j * 16 + r) * 32 + q * 8];
        #pragma unroll
        for (int i = 0; i < 4; ++i)
            #pragma unroll
            for (int j = 0; j < 4; ++j)
                acc[i][j] = __builtin_amdgcn_mfma_f32_16x16x32_bf16(af[i], bfr[j], acc[i][j], 0, 0, 0);
    }
    __syncthreads();   // all T1s reads done; reuse as f32 T2

    float* T2f = (float*)T1s;   // [128][64]
    if (wn == 0) {
        #pragma unroll
        for (int i = 0; i < 4; ++i) {
            int row = wm * 64 + i * 16 + q * 4;
            #pragma unroll
            for (int j = 0; j < 4; ++j) {
                int col = j * 16 + r;
                float bv = b2s[col];
                #pragma unroll
                for (int rr = 0; rr < 4; ++rr)
                    T2f[(row + rr) * 64 + col] = fmaxf(acc[i][j][rr] + bv, 0.f);
            }
        }
    }
    __syncthreads();

    if (t < 128) {
        int pos3 = p0 + t;
        if (pos3 < N_EDGES) {
            float a0 = b3s[0], a1 = b3s[1], a2 = b3s[2], a3 = b3s[3];
            const float* trow = &T2f[t * 64];
            #pragma unroll 8
            for (int kk = 0; kk < 64; ++kk) {
                int k = (kk + t) & 63;           // rotate start: spread banks across lanes
                float tv = trow[k];
                float4 w3 = *(const float4*)&W3s[k * 4];   // one b128 LDS read
                a0 += tv * w3.x;
                a1 += tv * w3.y;
                a2 += tv * w3.z;
                a3 += tv * w3.w;
            }
            int prow3 = rowcsr[pos3];
            int pk3 = csr[pos3];
            int tc = (pk3 >> 24) & 0xF;
            int tr = types[prow3];
            int pr = pvarr[prow3];
            int pc = pvts[tc];
            float halogen = (tr == 4 || tr == 5 || tc == 4 || tc == 5) ? 1.f : 0.f;
            float l1 = (pr <= 1 || pc <= 1) ? 1.f : 0.f;
            float l2 = (pr <= 2 || pc <= 2) ? 1.f : 0.f;
            float pen13 = -100.f * halogen - 50.f * l1;
            a1 += pen13;
            a3 += pen13;
            a2 += pen13 - 50.f * l2;
            int eid = eidarr[pos3];
            *(float4*)&bl_out[(size_t)eid * 4] = make_float4(a0, a1, a2, a3);
        }
    }
}

// ================================================================
extern "C" void kernel_launch(void* const* d_in, const int* in_sizes, int n_in,
                              void* d_out, int out_size, void* d_ws, size_t ws_size,
                              hipStream_t stream)
{
    const float* x          = (const float*)d_in[0];
    const float* edge_attr  = (const float*)d_in[1];
    const float* atom_emb   = (const float*)d_in[2];
    const float* bond_emb   = (const float*)d_in[3];
    const float* vp_w1      = (const float*)d_in[4];
    const float* vp_b1      = (const float*)d_in[5];
    const float* vp_w2      = (const float*)d_in[6];
    const float* vp_b2      = (const float*)d_in[7];
    const float* gnn_wself  = (const float*)d_in[8];
    const float* gnn_bself  = (const float*)d_in[9];
    const float* gnn_wmsg   = (const float*)d_in[10];
    const float* gnn_bmsg   = (const float*)d_in[11];
    const float* bc_w1      = (const float*)d_in[12];
    const float* bc_b1      = (const float*)d_in[13];
    const float* bc_w2      = (const float*)d_in[14];
    const float* bc_b2      = (const float*)d_in[15];
    const float* bc_w3      = (const float*)d_in[16];
    const float* bc_b3      = (const float*)d_in[17];
    const float* cp_w1      = (const float*)d_in[18];
    const float* cp_b1      = (const float*)d_in[19];
    const float* cp_w2      = (const float*)d_in[20];
    const float* cp_b2      = (const float*)d_in[21];
    const int*   ei         = (const int*)d_in[22];

    float* out    = (float*)d_out;
    float* h_out  = out + H_OFF;
    float* cp_out = out + CP_OFF;
    float* vl_out = out + VL_OFF;
    float* bl_out = out + BL_OFF;
    float* vi_out = out + VI_OFF;

    // ---- workspace layout ----
    char* base = (char*)d_ws;
    const size_t S = (size_t)M_PAD * 256 * 2;   // 51,249,152 B
    u16* h_bf  = (u16*)(base + 0 * S);           // R0: h ; later uv
    u16* uv_bf = (u16*)(base + 0 * S);
    u16* hm_bf = (u16*)(base + 1 * S);           // R1: hm
    u16* hs_bf = (u16*)(base + 2 * S);           // R2: hs
    u16* hd_bf = (u16*)(base + 3 * S);           // R3: damped h bf16
    u16* cp1_bf= (u16*)(base + 4 * S);           // R4: unused (cp2 fused)
    char* w    = base + 4 * S + (size_t)M_PAD * 128 * 2;
    int* degree  = (int*)w; w += (size_t)N_NODES * 4;
    int* offsets = (int*)w; w += (size_t)N_NODES * 4;
    int* cursor  = (int*)w; w += (size_t)N_NODES * 4;
    int* types   = (int*)w; w += (size_t)N_NODES * 4;
    int* pvarr   = (int*)w; w += (size_t)N_NODES * 4;
    int* csr     = (int*)w; w += (size_t)E_PAD * 4;
    int* rowcsr  = (int*)w; w += (size_t)E_PAD * 4;
    int* eidarr  = (int*)w; w += (size_t)E_PAD * 4;
    int* bsum    = (int*)w; w += 4096;
    int* bbase   = (int*)w; w += 4096;
    int* pv_tab  = (int*)w; w += 1024;
    float* vl_tab    = (float*)w; w += 2048;
    float* h0_tab    = (float*)w; w += 11 * 256 * 4;
    float* self0_tab = (float*)w; w += 11 * 256 * 4;
    float* msg0_tab  = (float*)w; w += 55 * 256 * 4;
    float* bondtab   = (float*)w; w += 2 * 5 * 256 * 4;
    u16* BtL1  = (u16*)w; w += 512 * 256 * 2;
    u16* BtL2  = (u16*)w; w += 512 * 256 * 2;
    u16* Bt3   = (u16*)w; w += 384 * 256 * 2;
    u16* BtW2  = (u16*)w; w += 128 * 128 * 2;
    u16* BtCP2 = (u16*)w; w += 128 * 128 * 2;
    float* bias512  = (float*)w; w += 2 * 512 * 4;
    float* biasPost = (float*)w; w += 384 * 4;

    // ---- setup ----
    k_type_mlp<<<1, 256, 0, stream>>>(atom_emb, vp_w1, vp_b1, vp_w2, vp_b2, pv_tab, vl_tab, h0_tab);
    k_tables<<<76, 256, 0, stream>>>(bond_emb, gnn_wself, gnn_bself, gnn_wmsg, gnn_bmsg,
                                     h0_tab, self0_tab, msg0_tab, bondtab);
    k_wtrans<<<1664, 256, 0, stream>>>(gnn_wmsg, gnn_wself, bc_w1, cp_w1, bc_w2, cp_w2,
                                       BtL1, BtL2, Bt3, BtW2, BtCP2);
    k_setup_bias<<<6, 256, 0, stream>>>(gnn_bself, bc_b1, cp_b1, bias512, biasPost);
    k_node_init<<<(N_NODES + 255) / 256, 256, 0, stream>>>(x, pv_tab, vl_tab, types, pvarr, degree, vl_out);
    k_edge_deg<<<(N_EDGES + 255) / 256, 256, 0, stream>>>(ei, degree);
    int nb = (N_NODES + SCAN_B - 1) / SCAN_B;
    k_scan1<<<nb, SCAN_B, 0, stream>>>(degree, offsets, bsum);
    k_scan2<<<1, 128, 0, stream>>>(bsum, bbase, nb);
    k_scan3<<<nb, SCAN_B, 0, stream>>>(offsets, bbase, cursor);
    k_csr_fill<<<(N_EDGES + 255) / 256, 256, 0, stream>>>(ei, edge_attr, types, cursor, csr, rowcsr, eidarr);
    k_agg0<<<N_NODES / 4, 256, 0, stream>>>(offsets, degree, types, self0_tab, msg0_tab, csr, h_bf);

    // ---- GNN layers 1,2 (l=2 fuses damp/viol/h_out) ----
    const int MT = M_PAD / 128;           // 782
    const int QB = (MT + 7) / 8;          // 98
    for (int l = 1; l <= 2; ++l) {
        const u16* BtL = (l == 1) ? BtL1 : BtL2;
        k_gemm_dual<<<QB * 32, 256, 0, stream>>>(h_bf, BtL, bias512 + (size_t)(l - 1) * 512,
                                                 hm_bf, hs_bf, N_NODES, MT);
        k_agg12<<<N_NODES / 4, 256, 0, stream>>>(offsets, degree, hs_bf, hm_bf,
                                                 bondtab + (size_t)(l - 1) * 5 * 256, csr, h_bf,
                                                 (l == 2) ? 1 : 0, pvarr, h_out, hd_bf, vi_out);
    }

    // ---- uv + cp1 + cp2 fully fused ----
    k_gemm_post<<<QB * 24, 256, 0, stream>>>(hd_bf, Bt3, biasPost, uv_bf, BtCP2, cp_b2, cp_out, N_NODES, MT);

    // ---- fused bond chain ----
    k_bond_fused<<<E_PAD / 128, 256, 0, stream>>>(csr, rowcsr, eidarr, types, pvarr, pv_tab,
                                                  uv_bf, bc_w1, BtW2, bc_b2, bc_w3, bc_b3, bl_out);
}

// Round 11
// 550.087 us; speedup vs baseline: 1.3909x; 1.0471x over previous
//
#include <hip/hip_runtime.h>

#define N_NODES 100000
#define N_EDGES 300000
#define M_PAD   100096   // 782*128
#define E_PAD   300032   // 2344*128

typedef unsigned short u16;
typedef short bf16x8 __attribute__((ext_vector_type(8)));
typedef float f32x4  __attribute__((ext_vector_type(4)));
typedef unsigned short u16x8 __attribute__((ext_vector_type(8)));

__device__ __forceinline__ float bf2f(u16 u) {
    unsigned x = ((unsigned)u) << 16;
    return __builtin_bit_cast(float, x);
}
__device__ __forceinline__ u16 f2bf(float f) {
    unsigned u = __builtin_bit_cast(unsigned, f);
    unsigned r = (u + 0x7FFF + ((u >> 16) & 1)) >> 16;
    return (u16)r;
}

// ---------------- output layout (floats) ----------------
#define H_OFF   0
#define CP_OFF  25600000
#define VL_OFF  28800000
#define BL_OFF  29600000
#define VI_OFF  30800000

#define GLL(gp, lp) __builtin_amdgcn_global_load_lds( \
    (const __attribute__((address_space(1))) unsigned int*)(gp), \
    (__attribute__((address_space(3))) unsigned int*)(lp), 16, 0, 0)

// ============ per-atom-type valence MLP (parallelized) + bias tables ============
__global__ void k_type_mlp(const float* __restrict__ atom_emb,
                           const float* __restrict__ vp_w1, const float* __restrict__ vp_b1,
                           const float* __restrict__ vp_w2, const float* __restrict__ vp_b2,
                           const float* __restrict__ bself, const float* __restrict__ bcb1,
                           const float* __restrict__ cpb1,
                           int* __restrict__ pv_tab, float* __restrict__ vl_tab,
                           float* __restrict__ h0_tab,
                           float* __restrict__ bias512, float* __restrict__ biasPost)
{
    __shared__ float zs[11][32];
    __shared__ float lgs[11][8];
    int tid = threadIdx.x;
    // independent bias-table setup (was k_setup_bias)
    for (int i = tid; i < 1024; i += 256) {
        int l = i >> 9, c = i & 511;
        bias512[l * 512 + c] = (c < 256) ? 0.f : bself[(l + 1) * 256 + (c - 256)];
    }
    for (int i = tid; i < 384; i += 256)
        biasPost[i] = (i < 128) ? bcb1[i] : ((i < 256) ? 0.f : cpb1[i - 256]);
    for (int i = tid; i < 11 * 256; i += 256) h0_tab[i] = 0.f;
    // hidden layer: 11 types x 32 units
    for (int u = tid; u < 352; u += 256) {
        int t = u >> 5, j = u & 31;
        const float* ae = atom_emb + t * 64;
        float z = vp_b1[j];
        for (int d = 0; d < 64; ++d) z += ae[d] * vp_w1[d * 32 + j];
        zs[t][j] = fmaxf(z, 0.f);
    }
    __syncthreads();
    // logits: 11 x 8
    if (tid < 88) {
        int t = tid >> 3, c = tid & 7;
        float lg = vp_b2[c];
        #pragma unroll
        for (int j = 0; j < 32; ++j) lg += zs[t][j] * vp_w2[j * 8 + c];
        lgs[t][c] = lg;
        vl_tab[t * 8 + c] = lg;
    }
    __syncthreads();
    if (tid < 11) {
        int t = tid;
        int best = 0;
        #pragma unroll
        for (int c = 1; c < 8; ++c) if (lgs[t][c] > lgs[t][best]) best = c;
        pv_tab[t] = best + 1;
        float* h0 = h0_tab + t * 256;
        const float* ae = atom_emb + t * 64;
        for (int d = 0; d < 64; ++d) h0[d] = ae[d];
        h0[64 + best] = 1.f;
    }
}

// ============ layer-0 tables + bond tables for layers 1,2 ============
__global__ void k_tables(const float* __restrict__ bond_emb,
                         const float* __restrict__ gnn_wself, const float* __restrict__ gnn_bself,
                         const float* __restrict__ gnn_wmsg, const float* __restrict__ gnn_bmsg,
                         const float* __restrict__ h0_tab,
                         float* __restrict__ self0_tab, float* __restrict__ msg0_tab,
                         float* __restrict__ bondtab)
{
    int b = blockIdx.x, c = threadIdx.x;
    if (b < 11) {
        int t = b;
        const float* h0 = h0_tab + t * 256;
        float acc = gnn_bself[c];
        for (int k = 0; k < 256; ++k) acc += h0[k] * gnn_wself[k * 256 + c];
        self0_tab[t * 256 + c] = acc;
    } else if (b < 66) {
        int idx = b - 11; int t = idx / 5, bb = idx % 5;
        const float* h0 = h0_tab + t * 256;
        float acc = gnn_bmsg[c];
        for (int k = 0; k < 256; ++k) acc += h0[k] * gnn_wmsg[k * 256 + c];
        const float* be = bond_emb + bb * 64;
        for (int k = 0; k < 64; ++k) acc += be[k] * gnn_wmsg[(256 + k) * 256 + c];
        msg0_tab[idx * 256 + c] = fmaxf(acc, 0.f);
    } else {
        int idx = b - 66; int l = idx / 5 + 1, bb = idx % 5;
        const float* w = gnn_wmsg + (size_t)l * 320 * 256;
        const float* be = bond_emb + bb * 64;
        float acc = gnn_bmsg[l * 256 + c];
        for (int k = 0; k < 64; ++k) acc += be[k] * w[(256 + k) * 256 + c];
        bondtab[(l - 1) * 5 * 256 + bb * 256 + c] = acc;
    }
}

// ============ bf16-transposed weight tables ============
__global__ void k_wtrans(const float* __restrict__ wmsg, const float* __restrict__ wself,
                         const float* __restrict__ bcw1, const float* __restrict__ cpw1,
                         const float* __restrict__ bcw2, const float* __restrict__ cpw2,
                         u16* __restrict__ BtL1, u16* __restrict__ BtL2, u16* __restrict__ Bt3,
                         u16* __restrict__ BtW2, u16* __restrict__ BtCP2)
{
    int b = blockIdx.x, k = threadIdx.x;
    if (b < 512) {
        int n = b;
        float v = (n < 256) ? wmsg[(size_t)1 * 320 * 256 + (size_t)k * 256 + n]
                            : wself[(size_t)1 * 256 * 256 + (size_t)k * 256 + (n - 256)];
        BtL1[n * 256 + k] = f2bf(v);
    } else if (b < 1024) {
        int n = b - 512;
        float v = (n < 256) ? wmsg[(size_t)2 * 320 * 256 + (size_t)k * 256 + n]
                            : wself[(size_t)2 * 256 * 256 + (size_t)k * 256 + (n - 256)];
        BtL2[n * 256 + k] = f2bf(v);
    } else if (b < 1408) {
        int n = b - 1024;
        float v;
        if (n < 128)      v = bcw1[k * 128 + n];
        else if (n < 256) v = bcw1[(256 + k) * 128 + (n - 128)];
        else              v = cpw1[k * 128 + (n - 256)];
        Bt3[n * 256 + k] = f2bf(v);
    } else if (b < 1536) {
        int n = b - 1408;
        if (k < 128) BtW2[n * 128 + k] = f2bf(n < 64 ? bcw2[k * 64 + n] : 0.f);
    } else {
        int n = b - 1536;
        if (k < 128) BtCP2[n * 128 + k] = f2bf(n < 32 ? cpw2[k * 32 + n] : 0.f);
    }
}

// ============ node init + edge degree (merged; degree zeroed by memset before) ============
#define NB_NODE ((N_NODES + 255) / 256)
#define NB_EDGE ((N_EDGES + 255) / 256)
__global__ void k_init_deg(const float* __restrict__ x, const int* __restrict__ pv_tab,
                           const float* __restrict__ vl_tab,
                           int* __restrict__ types, int* __restrict__ pvarr,
                           float* __restrict__ vl_out,
                           const int* __restrict__ ei, int* __restrict__ degree)
{
    int b = blockIdx.x;
    if (b < NB_NODE) {
        int i = b * 256 + threadIdx.x;
        if (i >= N_NODES) return;
        int t = (int)x[i * 16];
        t = min(max(t, 0), 10);
        types[i] = t;
        pvarr[i] = pv_tab[t];
        float4 v0 = *(const float4*)&vl_tab[t * 8];
        float4 v1 = *(const float4*)&vl_tab[t * 8 + 4];
        *(float4*)&vl_out[i * 8]     = v0;
        *(float4*)&vl_out[i * 8 + 4] = v1;
    } else {
        int e = (b - NB_NODE) * 256 + threadIdx.x;
        if (e >= N_EDGES) return;
        atomicAdd(&degree[ei[e]], 1);
    }
}

// ============ scan ============
#define SCAN_B 1024
__global__ void k_scan1(const int* __restrict__ degree, int* __restrict__ part, int* __restrict__ bsum)
{
    __shared__ int s[SCAN_B];
    int tid = threadIdx.x;
    int i = blockIdx.x * SCAN_B + tid;
    int v = (i < N_NODES) ? degree[i] : 0;
    s[tid] = v; __syncthreads();
    for (int off = 1; off < SCAN_B; off <<= 1) {
        int t = (tid >= off) ? s[tid - off] : 0;
        __syncthreads();
        s[tid] += t;
        __syncthreads();
    }
    if (i < N_NODES) part[i] = s[tid] - v;
    if (tid == SCAN_B - 1) bsum[blockIdx.x] = s[tid];
}

__global__ void k_scan2(const int* __restrict__ bsum, int* __restrict__ bbase, int nb)
{
    __shared__ int s[128];
    int tid = threadIdx.x;
    int v = (tid < nb) ? bsum[tid] : 0;
    s[tid] = v; __syncthreads();
    for (int off = 1; off < 128; off <<= 1) {
        int t = (tid >= off) ? s[tid - off] : 0;
        __syncthreads();
        s[tid] += t;
        __syncthreads();
    }
    bbase[tid] = s[tid] - v;
}

__global__ void k_scan3(int* __restrict__ part, const int* __restrict__ bbase, int* __restrict__ cursor)
{
    int i = blockIdx.x * SCAN_B + threadIdx.x;
    if (i >= N_NODES) return;
    int o = part[i] + bbase[blockIdx.x];
    part[i] = o;
    cursor[i] = o;
}

// ============ CSR fill (+ row/eid side arrays for the bond pass) ============
__global__ void k_csr_fill(const int* __restrict__ ei, const float* __restrict__ edge_attr,
                           const int* __restrict__ types, int* __restrict__ cursor,
                           int* __restrict__ csr, int* __restrict__ rowcsr, int* __restrict__ eidarr)
{
    int e = blockIdx.x * blockDim.x + threadIdx.x;
    if (e >= N_EDGES) return;
    int row = ei[e], col = ei[N_EDGES + e];
    int bt = (int)edge_attr[e * 4];
    bt = min(max(bt, 0), 4);
    int pos = atomicAdd(&cursor[row], 1);
    csr[pos] = col | (bt << 20) | (types[col] << 24);
    rowcsr[pos] = row;
    eidarr[pos] = e;
}

// ============ layer-0 aggregation (tables) -> h bf16 ============
__global__ __launch_bounds__(256) void k_agg0(const int* __restrict__ offsets, const int* __restrict__ degree,
                       const int* __restrict__ types,
                       const float* __restrict__ self0_tab, const float* __restrict__ msg0_tab,
                       const int* __restrict__ csr, u16* __restrict__ h)
{
    int wid = threadIdx.x >> 6, lane = threadIdx.x & 63;
    int node = blockIdx.x * 4 + wid;
    if (node >= N_NODES) return;
    int t = types[node];
    float4 acc = *(const float4*)&self0_tab[t * 256 + lane * 4];
    int start = offsets[node], deg = degree[node];
    int pj = (lane < deg) ? csr[start + lane] : 0;
    int dmax = min(deg, 64);
    for (int j = 0; j < dmax; ++j) {
        int p = __shfl(pj, j);
        int combo = ((p >> 24) & 0xF) * 5 + ((p >> 20) & 7);
        float4 m = *(const float4*)&msg0_tab[combo * 256 + lane * 4];
        acc.x += m.x; acc.y += m.y; acc.z += m.z; acc.w += m.w;
    }
    for (int j = 64; j < deg; ++j) {   // practically unreachable (Poisson(3))
        int p = csr[start + j];
        int combo = ((p >> 24) & 0xF) * 5 + ((p >> 20) & 7);
        float4 m = *(const float4*)&msg0_tab[combo * 256 + lane * 4];
        acc.x += m.x; acc.y += m.y; acc.z += m.z; acc.w += m.w;
    }
    ushort4 r;
    r.x = f2bf(fmaxf(acc.x, 0.f)); r.y = f2bf(fmaxf(acc.y, 0.f));
    r.z = f2bf(fmaxf(acc.z, 0.f)); r.w = f2bf(fmaxf(acc.w, 0.f));
    *(ushort4*)&h[(size_t)node * 256 + lane * 4] = r;
}

// ============ layers 1,2 aggregation; shfl-prefetched csr + 1-deep hm pipeline ============
__global__ __launch_bounds__(256) void k_agg12(const int* __restrict__ offsets, const int* __restrict__ degree,
                        const u16* __restrict__ hs, const u16* __restrict__ hm,
                        const float* __restrict__ bondtab, const int* __restrict__ csr,
                        u16* __restrict__ h, int final_layer, const int* __restrict__ pvarr,
                        float* __restrict__ h_out, u16* __restrict__ hd_bf, float* __restrict__ viol_out)
{
    int wid = threadIdx.x >> 6, lane = threadIdx.x & 63;
    int node = blockIdx.x * 4 + wid;
    if (node >= N_NODES) return;
    ushort4 s4 = *(const ushort4*)&hs[(size_t)node * 256 + lane * 4];
    float ax = bf2f(s4.x), ay = bf2f(s4.y), az = bf2f(s4.z), aw = bf2f(s4.w);
    int start = offsets[node], deg = degree[node];
    int pj = (lane < deg) ? csr[start + lane] : 0;
    int dmax = min(deg, 64);
    if (dmax > 0) {
        int p0 = __shfl(pj, 0);
        ushort4 m0 = *(const ushort4*)&hm[(size_t)(p0 & 0xFFFFF) * 256 + lane * 4];
        for (int j = 1; j < dmax; ++j) {
            int p1 = __shfl(pj, j);
            ushort4 m1 = *(const ushort4*)&hm[(size_t)(p1 & 0xFFFFF) * 256 + lane * 4];  // in flight during j-1 math
            float4 bb = *(const float4*)&bondtab[((p0 >> 20) & 7) * 256 + lane * 4];
            ax += fmaxf(bf2f(m0.x) + bb.x, 0.f);
            ay += fmaxf(bf2f(m0.y) + bb.y, 0.f);
            az += fmaxf(bf2f(m0.z) + bb.z, 0.f);
            aw += fmaxf(bf2f(m0.w) + bb.w, 0.f);
            m0 = m1; p0 = p1;
        }
        float4 bb = *(const float4*)&bondtab[((p0 >> 20) & 7) * 256 + lane * 4];
        ax += fmaxf(bf2f(m0.x) + bb.x, 0.f);
        ay += fmaxf(bf2f(m0.y) + bb.y, 0.f);
        az += fmaxf(bf2f(m0.z) + bb.z, 0.f);
        aw += fmaxf(bf2f(m0.w) + bb.w, 0.f);
    }
    for (int j = 64; j < deg; ++j) {   // practically unreachable
        int p = csr[start + j];
        int c = p & 0xFFFFF;
        int bt = (p >> 20) & 7;
        ushort4 m4 = *(const ushort4*)&hm[(size_t)c * 256 + lane * 4];
        float4 bb = *(const float4*)&bondtab[bt * 256 + lane * 4];
        ax += fmaxf(bf2f(m4.x) + bb.x, 0.f);
        ay += fmaxf(bf2f(m4.y) + bb.y, 0.f);
        az += fmaxf(bf2f(m4.z) + bb.z, 0.f);
        aw += fmaxf(bf2f(m4.w) + bb.w, 0.f);
    }
    ax = fmaxf(ax, 0.f); ay = fmaxf(ay, 0.f); az = fmaxf(az, 0.f); aw = fmaxf(aw, 0.f);
    if (!final_layer) {
        ushort4 r;
        r.x = f2bf(ax); r.y = f2bf(ay); r.z = f2bf(az); r.w = f2bf(aw);
        *(ushort4*)&h[(size_t)node * 256 + lane * 4] = r;
    } else {
        float viol = fmaxf((float)deg - (float)pvarr[node], 0.f);
        float s = 1.f / (1.f + viol);
        ax *= s; ay *= s; az *= s; aw *= s;
        float4 v = make_float4(ax, ay, az, aw);
        *(float4*)&h_out[(size_t)node * 256 + lane * 4] = v;
        ushort4 r;
        r.x = f2bf(ax); r.y = f2bf(ay); r.z = f2bf(az); r.w = f2bf(aw);
        *(ushort4*)&hd_bf[(size_t)node * 256 + lane * 4] = r;
        if (lane == 0) viol_out[node] = viol;
    }
}

// ================== layer GEMM: 3-buffer 2-DEEP pipeline + counted vmcnt + setprio ==================
__global__ __launch_bounds__(256) void k_gemm_dual(
    const u16* __restrict__ A, const u16* __restrict__ Bt,
    const float* __restrict__ bias512,
    u16* __restrict__ Dm, u16* __restrict__ Ds, int M, int MT)
{
    __shared__ u16 S[24576];          // 48 KB: buf i at S + i*8192 (A) / +4096 (B), i=0..2
    u16* Cs = S;                      // epilogue reuse [128][128]
    int b = blockIdx.x;
    int rsub = b & 31;
    int nt = rsub >> 3, m8 = rsub & 7;
    int mt = (b >> 5) * 8 + m8;
    if (mt >= MT) return;
    int bm = mt * 128, bn = nt * 128;

    int t = threadIdx.x;
    int lane = t & 63, w = t >> 6;
    int wm = w & 1, wn = w >> 1;
    f32x4 zero = {0.f, 0.f, 0.f, 0.f};
    f32x4 acc[4][4];
    #pragma unroll
    for (int i = 0; i < 4; ++i)
        #pragma unroll
        for (int j = 0; j < 4; ++j) acc[i][j] = zero;

    int arow = t >> 2, acol = (t & 3) * 8;
    const u16* Ag = A + (size_t)(bm + arow) * 256 + acol;
    const u16* Bg = Bt + (size_t)(bn + arow) * 256 + acol;
    int q = lane >> 4, r = lane & 15;

    // prologue: stage k-steps 0 and 1 (2-deep)
    GLL(Ag,                 S + t * 8);
    GLL(Ag + 64 * 256,      S + 2048 + t * 8);
    GLL(Bg,                 S + 4096 + t * 8);
    GLL(Bg + 64 * 256,      S + 4096 + 2048 + t * 8);
    GLL(Ag + 32,            S + 8192 + t * 8);
    GLL(Ag + 64 * 256 + 32, S + 8192 + 2048 + t * 8);
    GLL(Bg + 32,            S + 8192 + 4096 + t * 8);
    GLL(Bg + 64 * 256 + 32, S + 8192 + 4096 + 2048 + t * 8);

    #pragma unroll
    for (int ks = 0; ks < 8; ++ks) {
        int cb = (ks % 3) * 8192;
        if (ks < 7) {
            asm volatile("s_waitcnt vmcnt(4)" ::: "memory");
        } else {
            asm volatile("s_waitcnt vmcnt(0)" ::: "memory");
        }
        __builtin_amdgcn_s_barrier();
        __builtin_amdgcn_sched_barrier(0);
        if (ks < 6) {
            int nb = ((ks + 2) % 3) * 8192;
            int k0 = (ks + 2) * 32;
            GLL(Ag + k0,            S + nb + t * 8);
            GLL(Ag + 64 * 256 + k0, S + nb + 2048 + t * 8);
            GLL(Bg + k0,            S + nb + 4096 + t * 8);
            GLL(Bg + 64 * 256 + k0, S + nb + 4096 + 2048 + t * 8);
        }
        bf16x8 af[4], bfr[4];
        #pragma unroll
        for (int i = 0; i < 4; ++i)
            af[i] = *(const bf16x8*)&S[cb + (wm * 64 + i * 16 + r) * 32 + q * 8];
        #pragma unroll
        for (int j = 0; j < 4; ++j)
            bfr[j] = *(const bf16x8*)&S[cb + 4096 + (wn * 64 + j * 16 + r) * 32 + q * 8];
        __builtin_amdgcn_s_setprio(1);
        #pragma unroll
        for (int i = 0; i < 4; ++i)
            #pragma unroll
            for (int j = 0; j < 4; ++j)
                acc[i][j] = __builtin_amdgcn_mfma_f32_16x16x32_bf16(af[i], bfr[j], acc[i][j], 0, 0, 0);
        __builtin_amdgcn_s_setprio(0);
    }
    __syncthreads();   // all last-buffer reads done before Cs overwrite (vmcnt already 0)

    // ---- epilogue: acc -> LDS C-tile (bias fused), then full-line stores ----
    #pragma unroll
    for (int i = 0; i < 4; ++i) {
        int rowl = wm * 64 + i * 16 + q * 4;
        #pragma unroll
        for (int j = 0; j < 4; ++j) {
            int coll = wn * 64 + j * 16 + r;
            float bv = bias512[bn + coll];
            #pragma unroll
            for (int rr = 0; rr < 4; ++rr)
                Cs[(rowl + rr) * 128 + coll] = f2bf(acc[i][j][rr] + bv);
        }
    }
    __syncthreads();
    u16* Dbase = (nt < 2) ? (Dm + bn) : (Ds + (bn - 256));
    int c16 = (t & 15) * 8, rbase = t >> 4;
    #pragma unroll
    for (int g = 0; g < 8; ++g) {
        int rowl = rbase + g * 16;
        int rowg = bm + rowl;
        if (rowg < M) {
            u16x8 v = *(const u16x8*)&Cs[rowl * 128 + c16];
            *(u16x8*)&Dbase[(size_t)rowg * 256 + c16] = v;
        }
    }
}

// ================== post GEMM (N=384): 2-deep pipeline; nt==2 fuses cp2 ==================
__global__ __launch_bounds__(256) void k_gemm_post(
    const u16* __restrict__ A, const u16* __restrict__ Bt3,
    const float* __restrict__ biasPost,
    u16* __restrict__ UV, const u16* __restrict__ BtCP2, const float* __restrict__ cp_b2,
    float* __restrict__ CPOUT, int M, int MT)
{
    __shared__ u16 S[24576];
    u16* Cs = S;
    int b = blockIdx.x;
    int rsub = b % 24;
    int nt = rsub >> 3, m8 = rsub & 7;
    int mt = (b / 24) * 8 + m8;
    if (mt >= MT) return;
    int bm = mt * 128, bn = nt * 128;

    int t = threadIdx.x;
    int lane = t & 63, w = t >> 6;
    int wm = w & 1, wn = w >> 1;
    f32x4 zero = {0.f, 0.f, 0.f, 0.f};
    f32x4 acc[4][4];
    #pragma unroll
    for (int i = 0; i < 4; ++i)
        #pragma unroll
        for (int j = 0; j < 4; ++j) acc[i][j] = zero;

    int arow = t >> 2, acol = (t & 3) * 8;
    const u16* Ag = A + (size_t)(bm + arow) * 256 + acol;
    const u16* Bg = Bt3 + (size_t)(bn + arow) * 256 + acol;
    int q = lane >> 4, r = lane & 15;

    GLL(Ag,                 S + t * 8);
    GLL(Ag + 64 * 256,      S + 2048 + t * 8);
    GLL(Bg,                 S + 4096 + t * 8);
    GLL(Bg + 64 * 256,      S + 4096 + 2048 + t * 8);
    GLL(Ag + 32,            S + 8192 + t * 8);
    GLL(Ag + 64 * 256 + 32, S + 8192 + 2048 + t * 8);
    GLL(Bg + 32,            S + 8192 + 4096 + t * 8);
    GLL(Bg + 64 * 256 + 32, S + 8192 + 4096 + 2048 + t * 8);

    #pragma unroll
    for (int ks = 0; ks < 8; ++ks) {
        int cb = (ks % 3) * 8192;
        if (ks < 7) {
            asm volatile("s_waitcnt vmcnt(4)" ::: "memory");
        } else {
            asm volatile("s_waitcnt vmcnt(0)" ::: "memory");
        }
        __builtin_amdgcn_s_barrier();
        __builtin_amdgcn_sched_barrier(0);
        if (ks < 6) {
            int nb = ((ks + 2) % 3) * 8192;
            int k0 = (ks + 2) * 32;
            GLL(Ag + k0,            S + nb + t * 8);
            GLL(Ag + 64 * 256 + k0, S + nb + 2048 + t * 8);
            GLL(Bg + k0,            S + nb + 4096 + t * 8);
            GLL(Bg + 64 * 256 + k0, S + nb + 4096 + 2048 + t * 8);
        }
        bf16x8 af[4], bfr[4];
        #pragma unroll
        for (int i = 0; i < 4; ++i)
            af[i] = *(const bf16x8*)&S[cb + (wm * 64 + i * 16 + r) * 32 + q * 8];
        #pragma unroll
        for (int j = 0; j < 4; ++j)
            bfr[j] = *(const bf16x8*)&S[cb + 4096 + (wn * 64 + j * 16 + r) * 32 + q * 8];
        __builtin_amdgcn_s_setprio(1);
        #pragma unroll
        for (int i = 0; i < 4; ++i)
            #pragma unroll
            for (int j = 0; j < 4; ++j)
                acc[i][j] = __builtin_amdgcn_mfma_f32_16x16x32_bf16(af[i], bfr[j], acc[i][j], 0, 0, 0);
        __builtin_amdgcn_s_setprio(0);
    }
    __syncthreads();

    // ---- epilogue: acc -> LDS (bias + relu for cp1 block) ----
    #pragma unroll
    for (int i = 0; i < 4; ++i) {
        int rowl = wm * 64 + i * 16 + q * 4;
        #pragma unroll
        for (int j = 0; j < 4; ++j) {
            int coll = wn * 64 + j * 16 + r;
            float bv = biasPost[bn + coll];
            #pragma unroll
            for (int rr = 0; rr < 4; ++rr) {
                float val = acc[i][j][rr] + bv;
                if (nt == 2) val = fmaxf(val, 0.f);
                Cs[(rowl + rr) * 128 + coll] = f2bf(val);
            }
        }
    }
    __syncthreads();
    if (nt < 2) {
        int c16 = (t & 15) * 8, rbase = t >> 4;
        #pragma unroll
        for (int g = 0; g < 8; ++g) {
            int rowl = rbase + g * 16;
            int rowg = bm + rowl;
            if (rowg < M) {
                u16x8 v = *(const u16x8*)&Cs[rowl * 128 + c16];
                *(u16x8*)&UV[(size_t)rowg * 256 + bn + c16] = v;
            }
        }
    } else if (wn < 2) {
        // ---- fused cp2: Cs (relu cp1 tile, bf16) @ BtCP2 -> CPOUT[128][32] ----
        f32x4 a2[4];
        #pragma unroll
        for (int i = 0; i < 4; ++i) a2[i] = zero;
        #pragma unroll
        for (int kc = 0; kc < 4; ++kc) {
            bf16x8 af2[4];
            #pragma unroll
            for (int i = 0; i < 4; ++i)
                af2[i] = *(const bf16x8*)&Cs[(wm * 64 + i * 16 + r) * 128 + kc * 32 + q * 8];
            bf16x8 bfr2 = *(const bf16x8*)&BtCP2[(size_t)(wn * 16 + r) * 128 + kc * 32 + q * 8];
            #pragma unroll
            for (int i = 0; i < 4; ++i)
                a2[i] = __builtin_amdgcn_mfma_f32_16x16x32_bf16(af2[i], bfr2, a2[i], 0, 0, 0);
        }
        int colg = wn * 16 + r;
        float bv2 = cp_b2[colg];
        #pragma unroll
        for (int i = 0; i < 4; ++i) {
            #pragma unroll
            for (int rr = 0; rr < 4; ++rr) {
                int rowg = bm + wm * 64 + i * 16 + q * 4 + rr;
                if (rowg < M) CPOUT[(size_t)rowg * 32 + colg] = a2[i][rr] + bv2;
            }
        }
    }
}

// ================== fused bond kernel ==================
__global__ __launch_bounds__(256) void k_bond_fused(
    const int* __restrict__ csr, const int* __restrict__ rowcsr, const int* __restrict__ eidarr,
    const int* __restrict__ types, const int* __restrict__ pvarr, const int* __restrict__ pv_tab,
    const u16* __restrict__ uv, const float* __restrict__ bc_w1,
    const u16* __restrict__ BtW2, const float* __restrict__ bc_b2,
    const float* __restrict__ bc_w3, const float* __restrict__ bc_b3,
    float* __restrict__ bl_out)
{
    __shared__ u16 T1s[16384];     // 32 KB: 4 chunks x [128 rows][32 k]; reused as f32 T2 [128][64]
    __shared__ u16 Bs[16384];      // 32 KB: 4 chunks x [128 cols][32 k]
    __shared__ float w5s[128], w6s[128], W3s[256], b2s[64], b3s[4];
    __shared__ int pvts[16];

    int t = threadIdx.x;
    int p0 = blockIdx.x * 128;

    if (t < 128) { w5s[t] = bc_w1[512 * 128 + t]; w6s[t] = bc_w1[513 * 128 + t]; }
    if (t < 256) W3s[t] = bc_w3[t];
    if (t < 64) b2s[t] = bc_b2[t];
    if (t < 4)  b3s[t] = bc_b3[t];
    if (t < 11) pvts[t] = pv_tab[t];
    #pragma unroll
    for (int c = 0; c < 4; ++c) {
        GLL(BtW2 + (size_t)(t >> 2) * 128 + c * 32 + (t & 3) * 8,        Bs + c * 4096 + t * 8);
        GLL(BtW2 + (size_t)(64 + (t >> 2)) * 128 + c * 32 + (t & 3) * 8, Bs + c * 4096 + 2048 + t * 8);
    }

    int l = t >> 1;            // local row 0..127
    int half = t & 1;          // which 64-col half
    int pos = p0 + l;
    int prow = 0, pk = 0;
    if (pos < N_EDGES) { prow = rowcsr[pos]; pk = csr[pos]; }
    int pcol = pk & 0xFFFFF;
    float pvr = (float)pvarr[prow];
    __syncthreads();   // w5s/w6s/pvts ready (pvts must not be read before this barrier)
    float pvc = (float)pvts[(pk >> 24) & 0xF];

    const u16* up = uv + (size_t)prow * 256 + half * 64;
    const u16* vp = uv + (size_t)pcol * 256 + 128 + half * 64;
    #pragma unroll
    for (int j = 0; j < 8; ++j) {
        int c = half * 64 + j * 8;
        u16x8 uu = *(const u16x8*)(up + j * 8);      // 16 B load
        u16x8 vv = *(const u16x8*)(vp + j * 8);      // 16 B load
        int chunk = c >> 5, kk = c & 31;
        u16x8 o;
        #pragma unroll
        for (int e = 0; e < 8; ++e)
            o[e] = f2bf(fmaxf(bf2f(uu[e]) + bf2f(vv[e]) + pvr * w5s[c + e] + pvc * w6s[c + e], 0.f));
        *(u16x8*)(T1s + chunk * 4096 + l * 32 + kk) = o;   // one ds_write_b128
    }
    __syncthreads();   // T1s + Bs (GLL drained by barrier) ready

    int lane = t & 63, w = t >> 6;
    int wm = w & 1, wn = w >> 1;
    int q = lane >> 4, r = lane & 15;
    f32x4 zero = {0.f, 0.f, 0.f, 0.f};
    f32x4 acc[4][4];
    #pragma unroll
    for (int i = 0; i < 4; ++i)
        #pragma unroll
        for (int j = 0; j < 4; ++j) acc[i][j] = zero;
    #pragma unroll
    for (int c = 0; c < 4; ++c) {
        bf16x8 af[4], bfr[4];
        #pragma unroll
        for (int i = 0; i < 4; ++i)
            af[i] = *(const bf16x8*)&T1s[c * 4096 + (wm * 64 + i * 16 + r) * 32 + q * 8];
        #pragma unroll
        for (int j = 0; j < 4; ++j)
            bfr[j] = *(const bf16x8*)&Bs[c * 4096 + (wn * 64 + j * 16 + r) * 32 + q * 8];
        #pragma unroll
        for (int i = 0; i < 4; ++i)
            #pragma unroll
            for (int j = 0; j < 4; ++j)
                acc[i][j] = __builtin_amdgcn_mfma_f32_16x16x32_bf16(af[i], bfr[j], acc[i][j], 0, 0, 0);
    }
    __syncthreads();   // all T1s reads done; reuse as f32 T2

    float* T2f = (float*)T1s;   // [128][64]
    if (wn == 0) {
        #pragma unroll
        for (int i = 0; i < 4; ++i) {
            int row = wm * 64 + i * 16 + q * 4;
            #pragma unroll
            for (int j = 0; j < 4; ++j) {
                int col = j * 16 + r;
                float bv = b2s[col];
                #pragma unroll
                for (int rr = 0; rr < 4; ++rr)
                    T2f[(row + rr) * 64 + col] = fmaxf(acc[i][j][rr] + bv, 0.f);
            }
        }
    }
    __syncthreads();

    if (t < 128) {
        int pos3 = p0 + t;
        if (pos3 < N_EDGES) {
            float a0 = b3s[0], a1 = b3s[1], a2 = b3s[2], a3 = b3s[3];
            const float* trow = &T2f[t * 64];
            #pragma unroll 8
            for (int kk = 0; kk < 64; ++kk) {
                int k = (kk + t) & 63;           // rotate start: spread banks across lanes
                float tv = trow[k];
                float4 w3 = *(const float4*)&W3s[k * 4];   // one b128 LDS read
                a0 += tv * w3.x;
                a1 += tv * w3.y;
                a2 += tv * w3.z;
                a3 += tv * w3.w;
            }
            int prow3 = rowcsr[pos3];
            int pk3 = csr[pos3];
            int tc = (pk3 >> 24) & 0xF;
            int tr = types[prow3];
            int pr = pvarr[prow3];
            int pc = pvts[tc];
            float halogen = (tr == 4 || tr == 5 || tc == 4 || tc == 5) ? 1.f : 0.f;
            float l1 = (pr <= 1 || pc <= 1) ? 1.f : 0.f;
            float l2 = (pr <= 2 || pc <= 2) ? 1.f : 0.f;
            float pen13 = -100.f * halogen - 50.f * l1;
            a1 += pen13;
            a3 += pen13;
            a2 += pen13 - 50.f * l2;
            int eid = eidarr[pos3];
            *(float4*)&bl_out[(size_t)eid * 4] = make_float4(a0, a1, a2, a3);
        }
    }
}

// ================================================================
extern "C" void kernel_launch(void* const* d_in, const int* in_sizes, int n_in,
                              void* d_out, int out_size, void* d_ws, size_t ws_size,
                              hipStream_t stream)
{
    const float* x          = (const float*)d_in[0];
    const float* edge_attr  = (const float*)d_in[1];
    const float* atom_emb   = (const float*)d_in[2];
    const float* bond_emb   = (const float*)d_in[3];
    const float* vp_w1      = (const float*)d_in[4];
    const float* vp_b1      = (const float*)d_in[5];
    const float* vp_w2      = (const float*)d_in[6];
    const float* vp_b2      = (const float*)d_in[7];
    const float* gnn_wself  = (const float*)d_in[8];
    const float* gnn_bself  = (const float*)d_in[9];
    const float* gnn_wmsg   = (const float*)d_in[10];
    const float* gnn_bmsg   = (const float*)d_in[11];
    const float* bc_w1      = (const float*)d_in[12];
    const float* bc_b1      = (const float*)d_in[13];
    const float* bc_w2      = (const float*)d_in[14];
    const float* bc_b2      = (const float*)d_in[15];
    const float* bc_w3      = (const float*)d_in[16];
    const float* bc_b3      = (const float*)d_in[17];
    const float* cp_w1      = (const float*)d_in[18];
    const float* cp_b1      = (const float*)d_in[19];
    const float* cp_w2      = (const float*)d_in[20];
    const float* cp_b2      = (const float*)d_in[21];
    const int*   ei         = (const int*)d_in[22];

    float* out    = (float*)d_out;
    float* h_out  = out + H_OFF;
    float* cp_out = out + CP_OFF;
    float* vl_out = out + VL_OFF;
    float* bl_out = out + BL_OFF;
    float* vi_out = out + VI_OFF;

    // ---- workspace layout ----
    char* base = (char*)d_ws;
    const size_t S = (size_t)M_PAD * 256 * 2;   // 51,249,152 B
    u16* h_bf  = (u16*)(base + 0 * S);           // R0: h ; later uv
    u16* uv_bf = (u16*)(base + 0 * S);
    u16* hm_bf = (u16*)(base + 1 * S);           // R1: hm
    u16* hs_bf = (u16*)(base + 2 * S);           // R2: hs
    u16* hd_bf = (u16*)(base + 3 * S);           // R3: damped h bf16
    u16* cp1_bf= (u16*)(base + 4 * S);           // R4: unused (cp2 fused)
    char* w    = base + 4 * S + (size_t)M_PAD * 128 * 2;
    int* degree  = (int*)w; w += (size_t)N_NODES * 4;
    int* offsets = (int*)w; w += (size_t)N_NODES * 4;
    int* cursor  = (int*)w; w += (size_t)N_NODES * 4;
    int* types   = (int*)w; w += (size_t)N_NODES * 4;
    int* pvarr   = (int*)w; w += (size_t)N_NODES * 4;
    int* csr     = (int*)w; w += (size_t)E_PAD * 4;
    int* rowcsr  = (int*)w; w += (size_t)E_PAD * 4;
    int* eidarr  = (int*)w; w += (size_t)E_PAD * 4;
    int* bsum    = (int*)w; w += 4096;
    int* bbase   = (int*)w; w += 4096;
    int* pv_tab  = (int*)w; w += 1024;
    float* vl_tab    = (float*)w; w += 2048;
    float* h0_tab    = (float*)w; w += 11 * 256 * 4;
    float* self0_tab = (float*)w; w += 11 * 256 * 4;
    float* msg0_tab  = (float*)w; w += 55 * 256 * 4;
    float* bondtab   = (float*)w; w += 2 * 5 * 256 * 4;
    u16* BtL1  = (u16*)w; w += 512 * 256 * 2;
    u16* BtL2  = (u16*)w; w += 512 * 256 * 2;
    u16* Bt3   = (u16*)w; w += 384 * 256 * 2;
    u16* BtW2  = (u16*)w; w += 128 * 128 * 2;
    u16* BtCP2 = (u16*)w; w += 128 * 128 * 2;
    float* bias512  = (float*)w; w += 2 * 512 * 4;
    float* biasPost = (float*)w; w += 384 * 4;

    // ---- setup ----
    hipMemsetAsync(degree, 0, (size_t)N_NODES * 4, stream);
    k_type_mlp<<<1, 256, 0, stream>>>(atom_emb, vp_w1, vp_b1, vp_w2, vp_b2,
                                      gnn_bself, bc_b1, cp_b1,
                                      pv_tab, vl_tab, h0_tab, bias512, biasPost);
    k_tables<<<76, 256, 0, stream>>>(bond_emb, gnn_wself, gnn_bself, gnn_wmsg, gnn_bmsg,
                                     h0_tab, self0_tab, msg0_tab, bondtab);
    k_wtrans<<<1664, 256, 0, stream>>>(gnn_wmsg, gnn_wself, bc_w1, cp_w1, bc_w2, cp_w2,
                                       BtL1, BtL2, Bt3, BtW2, BtCP2);
    k_init_deg<<<NB_NODE + NB_EDGE, 256, 0, stream>>>(x, pv_tab, vl_tab, types, pvarr, vl_out, ei, degree);
    int nb = (N_NODES + SCAN_B - 1) / SCAN_B;
    k_scan1<<<nb, SCAN_B, 0, stream>>>(degree, offsets, bsum);
    k_scan2<<<1, 128, 0, stream>>>(bsum, bbase, nb);
    k_scan3<<<nb, SCAN_B, 0, stream>>>(offsets, bbase, cursor);
    k_csr_fill<<<(N_EDGES + 255) / 256, 256, 0, stream>>>(ei, edge_attr, types, cursor, csr, rowcsr, eidarr);
    k_agg0<<<N_NODES / 4, 256, 0, stream>>>(offsets, degree, types, self0_tab, msg0_tab, csr, h_bf);

    // ---- GNN layers 1,2 (l=2 fuses damp/viol/h_out) ----
    const int MT = M_PAD / 128;           // 782
    const int QB = (MT + 7) / 8;          // 98
    for (int l = 1; l <= 2; ++l) {
        const u16* BtL = (l == 1) ? BtL1 : BtL2;
        k_gemm_dual<<<QB * 32, 256, 0, stream>>>(h_bf, BtL, bias512 + (size_t)(l - 1) * 512,
                                                 hm_bf, hs_bf, N_NODES, MT);
        k_agg12<<<N_NODES / 4, 256, 0, stream>>>(offsets, degree, hs_bf, hm_bf,
                                                 bondtab + (size_t)(l - 1) * 5 * 256, csr, h_bf,
                                                 (l == 2) ? 1 : 0, pvarr, h_out, hd_bf, vi_out);
    }

    // ---- uv + cp1 + cp2 fully fused ----
    k_gemm_post<<<QB * 24, 256, 0, stream>>>(hd_bf, Bt3, biasPost, uv_bf, BtCP2, cp_b2, cp_out, N_NODES, MT);

    // ---- fused bond chain ----
    k_bond_fused<<<E_PAD / 128, 256, 0, stream>>>(csr, rowcsr, eidarr, types, pvarr, pv_tab,
                                                  uv_bf, bc_w1, BtW2, bc_b2, bc_w3, bc_b3, bl_out);
}

// Round 12
// 545.028 us; speedup vs baseline: 1.4039x; 1.0093x over previous
//
#include <hip/hip_runtime.h>

#define N_NODES 100000
#define N_EDGES 300000
#define M_PAD   100096   // 782*128
#define E_PAD   300032   // 2344*128

typedef unsigned short u16;
typedef short bf16x8 __attribute__((ext_vector_type(8)));
typedef float f32x4  __attribute__((ext_vector_type(4)));
typedef unsigned short u16x8 __attribute__((ext_vector_type(8)));

__device__ __forceinline__ float bf2f(u16 u) {
    unsigned x = ((unsigned)u) << 16;
    return __builtin_bit_cast(float, x);
}
__device__ __forceinline__ u16 f2bf(float f) {
    unsigned u = __builtin_bit_cast(unsigned, f);
    unsigned r = (u + 0x7FFF + ((u >> 16) & 1)) >> 16;
    return (u16)r;
}

// ---------------- output layout (floats) ----------------
#define H_OFF   0
#define CP_OFF  25600000
#define VL_OFF  28800000
#define BL_OFF  29600000
#define VI_OFF  30800000

#define GLL(gp, lp) __builtin_amdgcn_global_load_lds( \
    (const __attribute__((address_space(1))) unsigned int*)(gp), \
    (__attribute__((address_space(3))) unsigned int*)(lp), 16, 0, 0)

// ============ per-atom-type valence MLP (parallelized) + bias tables ============
__global__ void k_type_mlp(const float* __restrict__ atom_emb,
                           const float* __restrict__ vp_w1, const float* __restrict__ vp_b1,
                           const float* __restrict__ vp_w2, const float* __restrict__ vp_b2,
                           const float* __restrict__ bself, const float* __restrict__ bcb1,
                           const float* __restrict__ cpb1,
                           int* __restrict__ pv_tab, float* __restrict__ vl_tab,
                           float* __restrict__ h0_tab,
                           float* __restrict__ bias512, float* __restrict__ biasPost)
{
    __shared__ float zs[11][32];
    __shared__ float lgs[11][8];
    int tid = threadIdx.x;
    for (int i = tid; i < 1024; i += 256) {
        int l = i >> 9, c = i & 511;
        bias512[l * 512 + c] = (c < 256) ? 0.f : bself[(l + 1) * 256 + (c - 256)];
    }
    for (int i = tid; i < 384; i += 256)
        biasPost[i] = (i < 128) ? bcb1[i] : ((i < 256) ? 0.f : cpb1[i - 256]);
    for (int i = tid; i < 11 * 256; i += 256) h0_tab[i] = 0.f;
    for (int u = tid; u < 352; u += 256) {
        int t = u >> 5, j = u & 31;
        const float* ae = atom_emb + t * 64;
        float z = vp_b1[j];
        for (int d = 0; d < 64; ++d) z += ae[d] * vp_w1[d * 32 + j];
        zs[t][j] = fmaxf(z, 0.f);
    }
    __syncthreads();
    if (tid < 88) {
        int t = tid >> 3, c = tid & 7;
        float lg = vp_b2[c];
        #pragma unroll
        for (int j = 0; j < 32; ++j) lg += zs[t][j] * vp_w2[j * 8 + c];
        lgs[t][c] = lg;
        vl_tab[t * 8 + c] = lg;
    }
    __syncthreads();
    if (tid < 11) {
        int t = tid;
        int best = 0;
        #pragma unroll
        for (int c = 1; c < 8; ++c) if (lgs[t][c] > lgs[t][best]) best = c;
        pv_tab[t] = best + 1;
        float* h0 = h0_tab + t * 256;
        const float* ae = atom_emb + t * 64;
        for (int d = 0; d < 64; ++d) h0[d] = ae[d];
        h0[64 + best] = 1.f;
    }
}

// ============ merged: layer-0/bond tables + coalesced bf16 weight transposes ============
// blocks 0..75: k_tables logic. blocks 76..163: 64x64 LDS-transpose tiles for BtL1/BtL2/Bt3.
// blocks 164..419: BtW2/BtCP2 (small, simple path).
__global__ void k_setup2(const float* __restrict__ bond_emb,
                         const float* __restrict__ gnn_wself, const float* __restrict__ gnn_bself,
                         const float* __restrict__ gnn_wmsg, const float* __restrict__ gnn_bmsg,
                         const float* __restrict__ h0_tab,
                         float* __restrict__ self0_tab, float* __restrict__ msg0_tab,
                         float* __restrict__ bondtab,
                         const float* __restrict__ bcw1, const float* __restrict__ cpw1,
                         const float* __restrict__ bcw2, const float* __restrict__ cpw2,
                         u16* __restrict__ BtL1, u16* __restrict__ BtL2, u16* __restrict__ Bt3,
                         u16* __restrict__ BtW2, u16* __restrict__ BtCP2)
{
    int b = blockIdx.x;
    int t = threadIdx.x;
    if (b < 76) {
        int c = t;
        if (b < 11) {
            int ty = b;
            const float* h0 = h0_tab + ty * 256;
            float acc = gnn_bself[c];
            for (int k = 0; k < 256; ++k) acc += h0[k] * gnn_wself[k * 256 + c];
            self0_tab[ty * 256 + c] = acc;
        } else if (b < 66) {
            int idx = b - 11; int ty = idx / 5, bb = idx % 5;
            const float* h0 = h0_tab + ty * 256;
            float acc = gnn_bmsg[c];
            for (int k = 0; k < 256; ++k) acc += h0[k] * gnn_wmsg[k * 256 + c];
            const float* be = bond_emb + bb * 64;
            for (int k = 0; k < 64; ++k) acc += be[k] * gnn_wmsg[(256 + k) * 256 + c];
            msg0_tab[idx * 256 + c] = fmaxf(acc, 0.f);
        } else {
            int idx = b - 66; int l = idx / 5 + 1, bb = idx % 5;
            const float* w = gnn_wmsg + (size_t)l * 320 * 256;
            const float* be = bond_emb + bb * 64;
            float acc = gnn_bmsg[l * 256 + c];
            for (int k = 0; k < 64; ++k) acc += be[k] * w[(256 + k) * 256 + c];
            bondtab[(l - 1) * 5 * 256 + bb * 256 + c] = acc;
        }
    } else if (b < 164) {
        // 64x64 transpose tiles: 32 (BtL1) + 32 (BtL2) + 24 (Bt3)
        __shared__ float tile[64][65];
        int tt = b - 76;
        u16* dst;
        int n0, k0;
        const float* srcbase;      // row-major [k][ld], element (k0+tk, n_src)
        int ld, noff;
        if (tt < 64) {
            int l = (tt < 32) ? 1 : 2;
            int q = tt & 31;
            dst = (l == 1) ? BtL1 : BtL2;
            n0 = (q >> 2) * 64; k0 = (q & 3) * 64;
            if (n0 < 256) { srcbase = gnn_wmsg + (size_t)l * 320 * 256; ld = 256; noff = n0; }
            else          { srcbase = gnn_wself + (size_t)l * 256 * 256; ld = 256; noff = n0 - 256; }
        } else {
            int q = tt - 64;       // 0..23
            dst = Bt3;
            n0 = (q >> 2) * 64; k0 = (q & 3) * 64;
            if (n0 < 128)      { srcbase = bcw1;             ld = 128; noff = n0; }
            else if (n0 < 256) { srcbase = bcw1 + 256 * 128; ld = 128; noff = n0 - 128; }
            else               { srcbase = cpw1;             ld = 128; noff = n0 - 256; }
        }
        int tn = t & 63, tq = t >> 6;
        #pragma unroll
        for (int i = 0; i < 16; ++i) {
            int tk = tq * 16 + i;
            tile[tk][tn] = srcbase[(size_t)(k0 + tk) * ld + noff + tn];   // coalesced 256B
        }
        __syncthreads();
        int tk2 = t & 63;
        #pragma unroll
        for (int i = 0; i < 16; ++i) {
            int tn2 = tq * 16 + i;
            dst[(size_t)(n0 + tn2) * 256 + k0 + tk2] = f2bf(tile[tk2][tn2]);  // coalesced 128B
        }
    } else {
        int bb = b - 164;          // 0..255
        int k = t;
        if (bb < 128) {
            int n = bb;
            if (k < 128) BtW2[n * 128 + k] = f2bf(n < 64 ? bcw2[k * 64 + n] : 0.f);
        } else {
            int n = bb - 128;
            if (k < 128) BtCP2[n * 128 + k] = f2bf(n < 32 ? cpw2[k * 32 + n] : 0.f);
        }
    }
}

// ============ node init + edge degree (merged; degree zeroed by memset before) ============
#define NB_NODE ((N_NODES + 255) / 256)
#define NB_EDGE ((N_EDGES + 255) / 256)
__global__ void k_init_deg(const float* __restrict__ x, const int* __restrict__ pv_tab,
                           const float* __restrict__ vl_tab,
                           int* __restrict__ types, int* __restrict__ pvarr,
                           float* __restrict__ vl_out,
                           const int* __restrict__ ei, int* __restrict__ degree)
{
    int b = blockIdx.x;
    if (b < NB_NODE) {
        int i = b * 256 + threadIdx.x;
        if (i >= N_NODES) return;
        int t = (int)x[i * 16];
        t = min(max(t, 0), 10);
        types[i] = t;
        pvarr[i] = pv_tab[t];
        float4 v0 = *(const float4*)&vl_tab[t * 8];
        float4 v1 = *(const float4*)&vl_tab[t * 8 + 4];
        *(float4*)&vl_out[i * 8]     = v0;
        *(float4*)&vl_out[i * 8 + 4] = v1;
    } else {
        int e = (b - NB_NODE) * 256 + threadIdx.x;
        if (e >= N_EDGES) return;
        atomicAdd(&degree[ei[e]], 1);
    }
}

// ============ scan (scan2 folded into scan3) ============
#define SCAN_B 1024
__global__ void k_scan1(const int* __restrict__ degree, int* __restrict__ part, int* __restrict__ bsum)
{
    __shared__ int s[SCAN_B];
    int tid = threadIdx.x;
    int i = blockIdx.x * SCAN_B + tid;
    int v = (i < N_NODES) ? degree[i] : 0;
    s[tid] = v; __syncthreads();
    for (int off = 1; off < SCAN_B; off <<= 1) {
        int t = (tid >= off) ? s[tid - off] : 0;
        __syncthreads();
        s[tid] += t;
        __syncthreads();
    }
    if (i < N_NODES) part[i] = s[tid] - v;
    if (tid == SCAN_B - 1) bsum[blockIdx.x] = s[tid];
}

__global__ void k_scan3(int* __restrict__ part, const int* __restrict__ bsum,
                        int* __restrict__ cursor, int nb)
{
    __shared__ int s[128];
    int tid = threadIdx.x;
    if (tid < 128) s[tid] = (tid < nb) ? bsum[tid] : 0;
    __syncthreads();
    for (int off = 1; off < 128; off <<= 1) {
        int v = 0;
        if (tid < 128 && tid >= off) v = s[tid - off];
        __syncthreads();
        if (tid < 128) s[tid] += v;
        __syncthreads();
    }
    int base = (blockIdx.x == 0) ? 0 : s[blockIdx.x - 1];
    int i = blockIdx.x * SCAN_B + tid;
    if (i >= N_NODES) return;
    int o = part[i] + base;
    part[i] = o;
    cursor[i] = o;
}

// ============ CSR fill (+ row/eid side arrays for the bond pass) ============
__global__ void k_csr_fill(const int* __restrict__ ei, const float* __restrict__ edge_attr,
                           const int* __restrict__ types, int* __restrict__ cursor,
                           int* __restrict__ csr, int* __restrict__ rowcsr, int* __restrict__ eidarr)
{
    int e = blockIdx.x * blockDim.x + threadIdx.x;
    if (e >= N_EDGES) return;
    int row = ei[e], col = ei[N_EDGES + e];
    int bt = (int)edge_attr[e * 4];
    bt = min(max(bt, 0), 4);
    int pos = atomicAdd(&cursor[row], 1);
    csr[pos] = col | (bt << 20) | (types[col] << 24);
    rowcsr[pos] = row;
    eidarr[pos] = e;
}

// ============ layer-0 aggregation (tables) -> h bf16 ============
__global__ __launch_bounds__(256) void k_agg0(const int* __restrict__ offsets, const int* __restrict__ degree,
                       const int* __restrict__ types,
                       const float* __restrict__ self0_tab, const float* __restrict__ msg0_tab,
                       const int* __restrict__ csr, u16* __restrict__ h)
{
    int wid = threadIdx.x >> 6, lane = threadIdx.x & 63;
    int node = blockIdx.x * 4 + wid;
    if (node >= N_NODES) return;
    int t = types[node];
    float4 acc = *(const float4*)&self0_tab[t * 256 + lane * 4];
    int start = offsets[node], deg = degree[node];
    int pj = (lane < deg) ? csr[start + lane] : 0;
    int dmax = min(deg, 64);
    for (int j = 0; j < dmax; ++j) {
        int p = __shfl(pj, j);
        int combo = ((p >> 24) & 0xF) * 5 + ((p >> 20) & 7);
        float4 m = *(const float4*)&msg0_tab[combo * 256 + lane * 4];
        acc.x += m.x; acc.y += m.y; acc.z += m.z; acc.w += m.w;
    }
    for (int j = 64; j < deg; ++j) {   // practically unreachable (Poisson(3))
        int p = csr[start + j];
        int combo = ((p >> 24) & 0xF) * 5 + ((p >> 20) & 7);
        float4 m = *(const float4*)&msg0_tab[combo * 256 + lane * 4];
        acc.x += m.x; acc.y += m.y; acc.z += m.z; acc.w += m.w;
    }
    ushort4 r;
    r.x = f2bf(fmaxf(acc.x, 0.f)); r.y = f2bf(fmaxf(acc.y, 0.f));
    r.z = f2bf(fmaxf(acc.z, 0.f)); r.w = f2bf(fmaxf(acc.w, 0.f));
    *(ushort4*)&h[(size_t)node * 256 + lane * 4] = r;
}

// ============ layers 1,2 aggregation; shfl-prefetched csr + 1-deep hm pipeline ============
__global__ __launch_bounds__(256) void k_agg12(const int* __restrict__ offsets, const int* __restrict__ degree,
                        const u16* __restrict__ hs, const u16* __restrict__ hm,
                        const float* __restrict__ bondtab, const int* __restrict__ csr,
                        u16* __restrict__ h, int final_layer, const int* __restrict__ pvarr,
                        float* __restrict__ h_out, u16* __restrict__ hd_bf, float* __restrict__ viol_out)
{
    int wid = threadIdx.x >> 6, lane = threadIdx.x & 63;
    int node = blockIdx.x * 4 + wid;
    if (node >= N_NODES) return;
    ushort4 s4 = *(const ushort4*)&hs[(size_t)node * 256 + lane * 4];
    float ax = bf2f(s4.x), ay = bf2f(s4.y), az = bf2f(s4.z), aw = bf2f(s4.w);
    int start = offsets[node], deg = degree[node];
    int pj = (lane < deg) ? csr[start + lane] : 0;
    int dmax = min(deg, 64);
    if (dmax > 0) {
        int p0 = __shfl(pj, 0);
        ushort4 m0 = *(const ushort4*)&hm[(size_t)(p0 & 0xFFFFF) * 256 + lane * 4];
        for (int j = 1; j < dmax; ++j) {
            int p1 = __shfl(pj, j);
            ushort4 m1 = *(const ushort4*)&hm[(size_t)(p1 & 0xFFFFF) * 256 + lane * 4];  // in flight during j-1 math
            float4 bb = *(const float4*)&bondtab[((p0 >> 20) & 7) * 256 + lane * 4];
            ax += fmaxf(bf2f(m0.x) + bb.x, 0.f);
            ay += fmaxf(bf2f(m0.y) + bb.y, 0.f);
            az += fmaxf(bf2f(m0.z) + bb.z, 0.f);
            aw += fmaxf(bf2f(m0.w) + bb.w, 0.f);
            m0 = m1; p0 = p1;
        }
        float4 bb = *(const float4*)&bondtab[((p0 >> 20) & 7) * 256 + lane * 4];
        ax += fmaxf(bf2f(m0.x) + bb.x, 0.f);
        ay += fmaxf(bf2f(m0.y) + bb.y, 0.f);
        az += fmaxf(bf2f(m0.z) + bb.z, 0.f);
        aw += fmaxf(bf2f(m0.w) + bb.w, 0.f);
    }
    for (int j = 64; j < deg; ++j) {   // practically unreachable
        int p = csr[start + j];
        int c = p & 0xFFFFF;
        int bt = (p >> 20) & 7;
        ushort4 m4 = *(const ushort4*)&hm[(size_t)c * 256 + lane * 4];
        float4 bb = *(const float4*)&bondtab[bt * 256 + lane * 4];
        ax += fmaxf(bf2f(m4.x) + bb.x, 0.f);
        ay += fmaxf(bf2f(m4.y) + bb.y, 0.f);
        az += fmaxf(bf2f(m4.z) + bb.z, 0.f);
        aw += fmaxf(bf2f(m4.w) + bb.w, 0.f);
    }
    ax = fmaxf(ax, 0.f); ay = fmaxf(ay, 0.f); az = fmaxf(az, 0.f); aw = fmaxf(aw, 0.f);
    if (!final_layer) {
        ushort4 r;
        r.x = f2bf(ax); r.y = f2bf(ay); r.z = f2bf(az); r.w = f2bf(aw);
        *(ushort4*)&h[(size_t)node * 256 + lane * 4] = r;
    } else {
        float viol = fmaxf((float)deg - (float)pvarr[node], 0.f);
        float s = 1.f / (1.f + viol);
        ax *= s; ay *= s; az *= s; aw *= s;
        float4 v = make_float4(ax, ay, az, aw);
        *(float4*)&h_out[(size_t)node * 256 + lane * 4] = v;
        ushort4 r;
        r.x = f2bf(ax); r.y = f2bf(ay); r.z = f2bf(az); r.w = f2bf(aw);
        *(ushort4*)&hd_bf[(size_t)node * 256 + lane * 4] = r;
        if (lane == 0) viol_out[node] = viol;
    }
}

// ================== layer GEMM: 3-buffer 2-DEEP pipeline + counted vmcnt + setprio ==================
__global__ __launch_bounds__(256) void k_gemm_dual(
    const u16* __restrict__ A, const u16* __restrict__ Bt,
    const float* __restrict__ bias512,
    u16* __restrict__ Dm, u16* __restrict__ Ds, int M, int MT)
{
    __shared__ u16 S[24576];          // 48 KB: buf i at S + i*8192 (A) / +4096 (B), i=0..2
    u16* Cs = S;                      // epilogue reuse [128][128]
    int b = blockIdx.x;
    int rsub = b & 31;
    int nt = rsub >> 3, m8 = rsub & 7;
    int mt = (b >> 5) * 8 + m8;
    if (mt >= MT) return;
    int bm = mt * 128, bn = nt * 128;

    int t = threadIdx.x;
    int lane = t & 63, w = t >> 6;
    int wm = w & 1, wn = w >> 1;
    f32x4 zero = {0.f, 0.f, 0.f, 0.f};
    f32x4 acc[4][4];
    #pragma unroll
    for (int i = 0; i < 4; ++i)
        #pragma unroll
        for (int j = 0; j < 4; ++j) acc[i][j] = zero;

    int arow = t >> 2, acol = (t & 3) * 8;
    const u16* Ag = A + (size_t)(bm + arow) * 256 + acol;
    const u16* Bg = Bt + (size_t)(bn + arow) * 256 + acol;
    int q = lane >> 4, r = lane & 15;

    // prologue: stage k-steps 0 and 1 (2-deep)
    GLL(Ag,                 S + t * 8);
    GLL(Ag + 64 * 256,      S + 2048 + t * 8);
    GLL(Bg,                 S + 4096 + t * 8);
    GLL(Bg + 64 * 256,      S + 4096 + 2048 + t * 8);
    GLL(Ag + 32,            S + 8192 + t * 8);
    GLL(Ag + 64 * 256 + 32, S + 8192 + 2048 + t * 8);
    GLL(Bg + 32,            S + 8192 + 4096 + t * 8);
    GLL(Bg + 64 * 256 + 32, S + 8192 + 4096 + 2048 + t * 8);

    #pragma unroll
    for (int ks = 0; ks < 8; ++ks) {
        int cb = (ks % 3) * 8192;
        if (ks < 7) {
            asm volatile("s_waitcnt vmcnt(4)" ::: "memory");
        } else {
            asm volatile("s_waitcnt vmcnt(0)" ::: "memory");
        }
        __builtin_amdgcn_s_barrier();
        __builtin_amdgcn_sched_barrier(0);
        if (ks < 6) {
            int nb = ((ks + 2) % 3) * 8192;
            int k0 = (ks + 2) * 32;
            GLL(Ag + k0,            S + nb + t * 8);
            GLL(Ag + 64 * 256 + k0, S + nb + 2048 + t * 8);
            GLL(Bg + k0,            S + nb + 4096 + t * 8);
            GLL(Bg + 64 * 256 + k0, S + nb + 4096 + 2048 + t * 8);
        }
        bf16x8 af[4], bfr[4];
        #pragma unroll
        for (int i = 0; i < 4; ++i)
            af[i] = *(const bf16x8*)&S[cb + (wm * 64 + i * 16 + r) * 32 + q * 8];
        #pragma unroll
        for (int j = 0; j < 4; ++j)
            bfr[j] = *(const bf16x8*)&S[cb + 4096 + (wn * 64 + j * 16 + r) * 32 + q * 8];
        __builtin_amdgcn_s_setprio(1);
        #pragma unroll
        for (int i = 0; i < 4; ++i)
            #pragma unroll
            for (int j = 0; j < 4; ++j)
                acc[i][j] = __builtin_amdgcn_mfma_f32_16x16x32_bf16(af[i], bfr[j], acc[i][j], 0, 0, 0);
        __builtin_amdgcn_s_setprio(0);
    }
    __syncthreads();   // all last-buffer reads done before Cs overwrite (vmcnt already 0)

    // ---- epilogue: acc -> LDS C-tile (bias fused), then full-line stores ----
    #pragma unroll
    for (int i = 0; i < 4; ++i) {
        int rowl = wm * 64 + i * 16 + q * 4;
        #pragma unroll
        for (int j = 0; j < 4; ++j) {
            int coll = wn * 64 + j * 16 + r;
            float bv = bias512[bn + coll];
            #pragma unroll
            for (int rr = 0; rr < 4; ++rr)
                Cs[(rowl + rr) * 128 + coll] = f2bf(acc[i][j][rr] + bv);
        }
    }
    __syncthreads();
    u16* Dbase = (nt < 2) ? (Dm + bn) : (Ds + (bn - 256));
    int c16 = (t & 15) * 8, rbase = t >> 4;
    #pragma unroll
    for (int g = 0; g < 8; ++g) {
        int rowl = rbase + g * 16;
        int rowg = bm + rowl;
        if (rowg < M) {
            u16x8 v = *(const u16x8*)&Cs[rowl * 128 + c16];
            *(u16x8*)&Dbase[(size_t)rowg * 256 + c16] = v;
        }
    }
}

// ================== post GEMM (N=384): 2-deep pipeline; nt==2 fuses cp2 ==================
__global__ __launch_bounds__(256) void k_gemm_post(
    const u16* __restrict__ A, const u16* __restrict__ Bt3,
    const float* __restrict__ biasPost,
    u16* __restrict__ UV, const u16* __restrict__ BtCP2, const float* __restrict__ cp_b2,
    float* __restrict__ CPOUT, int M, int MT)
{
    __shared__ u16 S[24576];
    u16* Cs = S;
    int b = blockIdx.x;
    int rsub = b % 24;
    int nt = rsub >> 3, m8 = rsub & 7;
    int mt = (b / 24) * 8 + m8;
    if (mt >= MT) return;
    int bm = mt * 128, bn = nt * 128;

    int t = threadIdx.x;
    int lane = t & 63, w = t >> 6;
    int wm = w & 1, wn = w >> 1;
    f32x4 zero = {0.f, 0.f, 0.f, 0.f};
    f32x4 acc[4][4];
    #pragma unroll
    for (int i = 0; i < 4; ++i)
        #pragma unroll
        for (int j = 0; j < 4; ++j) acc[i][j] = zero;

    int arow = t >> 2, acol = (t & 3) * 8;
    const u16* Ag = A + (size_t)(bm + arow) * 256 + acol;
    const u16* Bg = Bt3 + (size_t)(bn + arow) * 256 + acol;
    int q = lane >> 4, r = lane & 15;

    GLL(Ag,                 S + t * 8);
    GLL(Ag + 64 * 256,      S + 2048 + t * 8);
    GLL(Bg,                 S + 4096 + t * 8);
    GLL(Bg + 64 * 256,      S + 4096 + 2048 + t * 8);
    GLL(Ag + 32,            S + 8192 + t * 8);
    GLL(Ag + 64 * 256 + 32, S + 8192 + 2048 + t * 8);
    GLL(Bg + 32,            S + 8192 + 4096 + t * 8);
    GLL(Bg + 64 * 256 + 32, S + 8192 + 4096 + 2048 + t * 8);

    #pragma unroll
    for (int ks = 0; ks < 8; ++ks) {
        int cb = (ks % 3) * 8192;
        if (ks < 7) {
            asm volatile("s_waitcnt vmcnt(4)" ::: "memory");
        } else {
            asm volatile("s_waitcnt vmcnt(0)" ::: "memory");
        }
        __builtin_amdgcn_s_barrier();
        __builtin_amdgcn_sched_barrier(0);
        if (ks < 6) {
            int nb = ((ks + 2) % 3) * 8192;
            int k0 = (ks + 2) * 32;
            GLL(Ag + k0,            S + nb + t * 8);
            GLL(Ag + 64 * 256 + k0, S + nb + 2048 + t * 8);
            GLL(Bg + k0,            S + nb + 4096 + t * 8);
            GLL(Bg + 64 * 256 + k0, S + nb + 4096 + 2048 + t * 8);
        }
        bf16x8 af[4], bfr[4];
        #pragma unroll
        for (int i = 0; i < 4; ++i)
            af[i] = *(const bf16x8*)&S[cb + (wm * 64 + i * 16 + r) * 32 + q * 8];
        #pragma unroll
        for (int j = 0; j < 4; ++j)
            bfr[j] = *(const bf16x8*)&S[cb + 4096 + (wn * 64 + j * 16 + r) * 32 + q * 8];
        __builtin_amdgcn_s_setprio(1);
        #pragma unroll
        for (int i = 0; i < 4; ++i)
            #pragma unroll
            for (int j = 0; j < 4; ++j)
                acc[i][j] = __builtin_amdgcn_mfma_f32_16x16x32_bf16(af[i], bfr[j], acc[i][j], 0, 0, 0);
        __builtin_amdgcn_s_setprio(0);
    }
    __syncthreads();

    // ---- epilogue: acc -> LDS (bias + relu for cp1 block) ----
    #pragma unroll
    for (int i = 0; i < 4; ++i) {
        int rowl = wm * 64 + i * 16 + q * 4;
        #pragma unroll
        for (int j = 0; j < 4; ++j) {
            int coll = wn * 64 + j * 16 + r;
            float bv = biasPost[bn + coll];
            #pragma unroll
            for (int rr = 0; rr < 4; ++rr) {
                float val = acc[i][j][rr] + bv;
                if (nt == 2) val = fmaxf(val, 0.f);
                Cs[(rowl + rr) * 128 + coll] = f2bf(val);
            }
        }
    }
    __syncthreads();
    if (nt < 2) {
        int c16 = (t & 15) * 8, rbase = t >> 4;
        #pragma unroll
        for (int g = 0; g < 8; ++g) {
            int rowl = rbase + g * 16;
            int rowg = bm + rowl;
            if (rowg < M) {
                u16x8 v = *(const u16x8*)&Cs[rowl * 128 + c16];
                *(u16x8*)&UV[(size_t)rowg * 256 + bn + c16] = v;
            }
        }
    } else if (wn < 2) {
        // ---- fused cp2: Cs (relu cp1 tile, bf16) @ BtCP2 -> CPOUT[128][32] ----
        f32x4 a2[4];
        #pragma unroll
        for (int i = 0; i < 4; ++i) a2[i] = zero;
        #pragma unroll
        for (int kc = 0; kc < 4; ++kc) {
            bf16x8 af2[4];
            #pragma unroll
            for (int i = 0; i < 4; ++i)
                af2[i] = *(const bf16x8*)&Cs[(wm * 64 + i * 16 + r) * 128 + kc * 32 + q * 8];
            bf16x8 bfr2 = *(const bf16x8*)&BtCP2[(size_t)(wn * 16 + r) * 128 + kc * 32 + q * 8];
            #pragma unroll
            for (int i = 0; i < 4; ++i)
                a2[i] = __builtin_amdgcn_mfma_f32_16x16x32_bf16(af2[i], bfr2, a2[i], 0, 0, 0);
        }
        int colg = wn * 16 + r;
        float bv2 = cp_b2[colg];
        #pragma unroll
        for (int i = 0; i < 4; ++i) {
            #pragma unroll
            for (int rr = 0; rr < 4; ++rr) {
                int rowg = bm + wm * 64 + i * 16 + q * 4 + rr;
                if (rowg < M) CPOUT[(size_t)rowg * 32 + colg] = a2[i][rr] + bv2;
            }
        }
    }
}

// ================== fused bond kernel ==================
__global__ __launch_bounds__(256) void k_bond_fused(
    const int* __restrict__ csr, const int* __restrict__ rowcsr, const int* __restrict__ eidarr,
    const int* __restrict__ types, const int* __restrict__ pvarr, const int* __restrict__ pv_tab,
    const u16* __restrict__ uv, const float* __restrict__ bc_w1,
    const u16* __restrict__ BtW2, const float* __restrict__ bc_b2,
    const float* __restrict__ bc_w3, const float* __restrict__ bc_b3,
    float* __restrict__ bl_out)
{
    __shared__ u16 T1s[16384];     // 32 KB: 4 chunks x [128 rows][32 k]; reused as f32 T2 [128][64]
    __shared__ u16 Bs[16384];      // 32 KB: 4 chunks x [128 cols][32 k]
    __shared__ float w5s[128], w6s[128], W3s[256], b2s[64], b3s[4];
    __shared__ int pvts[16];

    int t = threadIdx.x;
    int p0 = blockIdx.x * 128;

    if (t < 128) { w5s[t] = bc_w1[512 * 128 + t]; w6s[t] = bc_w1[513 * 128 + t]; }
    if (t < 256) W3s[t] = bc_w3[t];
    if (t < 64) b2s[t] = bc_b2[t];
    if (t < 4)  b3s[t] = bc_b3[t];
    if (t < 11) pvts[t] = pv_tab[t];
    #pragma unroll
    for (int c = 0; c < 4; ++c) {
        GLL(BtW2 + (size_t)(t >> 2) * 128 + c * 32 + (t & 3) * 8,        Bs + c * 4096 + t * 8);
        GLL(BtW2 + (size_t)(64 + (t >> 2)) * 128 + c * 32 + (t & 3) * 8, Bs + c * 4096 + 2048 + t * 8);
    }

    int l = t >> 1;            // local row 0..127
    int half = t & 1;          // which 64-col half
    int pos = p0 + l;
    int prow = 0, pk = 0;
    if (pos < N_EDGES) { prow = rowcsr[pos]; pk = csr[pos]; }
    int pcol = pk & 0xFFFFF;
    float pvr = (float)pvarr[prow];
    __syncthreads();   // w5s/w6s/pvts ready (pvts must not be read before this barrier)
    float pvc = (float)pvts[(pk >> 24) & 0xF];

    const u16* up = uv + (size_t)prow * 256 + half * 64;
    const u16* vp = uv + (size_t)pcol * 256 + 128 + half * 64;
    #pragma unroll
    for (int j = 0; j < 8; ++j) {
        int c = half * 64 + j * 8;
        u16x8 uu = *(const u16x8*)(up + j * 8);      // 16 B load
        u16x8 vv = *(const u16x8*)(vp + j * 8);      // 16 B load
        int chunk = c >> 5, kk = c & 31;
        u16x8 o;
        #pragma unroll
        for (int e = 0; e < 8; ++e)
            o[e] = f2bf(fmaxf(bf2f(uu[e]) + bf2f(vv[e]) + pvr * w5s[c + e] + pvc * w6s[c + e], 0.f));
        *(u16x8*)(T1s + chunk * 4096 + l * 32 + kk) = o;   // one ds_write_b128
    }
    __syncthreads();   // T1s + Bs (GLL drained by barrier) ready

    int lane = t & 63, w = t >> 6;
    int wm = w & 1, wn = w >> 1;
    int q = lane >> 4, r = lane & 15;
    f32x4 zero = {0.f, 0.f, 0.f, 0.f};
    f32x4 acc[4][4];
    #pragma unroll
    for (int i = 0; i < 4; ++i)
        #pragma unroll
        for (int j = 0; j < 4; ++j) acc[i][j] = zero;
    #pragma unroll
    for (int c = 0; c < 4; ++c) {
        bf16x8 af[4], bfr[4];
        #pragma unroll
        for (int i = 0; i < 4; ++i)
            af[i] = *(const bf16x8*)&T1s[c * 4096 + (wm * 64 + i * 16 + r) * 32 + q * 8];
        #pragma unroll
        for (int j = 0; j < 4; ++j)
            bfr[j] = *(const bf16x8*)&Bs[c * 4096 + (wn * 64 + j * 16 + r) * 32 + q * 8];
        #pragma unroll
        for (int i = 0; i < 4; ++i)
            #pragma unroll
            for (int j = 0; j < 4; ++j)
                acc[i][j] = __builtin_amdgcn_mfma_f32_16x16x32_bf16(af[i], bfr[j], acc[i][j], 0, 0, 0);
    }
    __syncthreads();   // all T1s reads done; reuse as f32 T2

    float* T2f = (float*)T1s;   // [128][64]
    if (wn == 0) {
        #pragma unroll
        for (int i = 0; i < 4; ++i) {
            int row = wm * 64 + i * 16 + q * 4;
            #pragma unroll
            for (int j = 0; j < 4; ++j) {
                int col = j * 16 + r;
                float bv = b2s[col];
                #pragma unroll
                for (int rr = 0; rr < 4; ++rr)
                    T2f[(row + rr) * 64 + col] = fmaxf(acc[i][j][rr] + bv, 0.f);
            }
        }
    }
    __syncthreads();

    if (t < 128) {
        int pos3 = p0 + t;
        if (pos3 < N_EDGES) {
            float a0 = b3s[0], a1 = b3s[1], a2 = b3s[2], a3 = b3s[3];
            const float* trow = &T2f[t * 64];
            #pragma unroll 8
            for (int kk = 0; kk < 64; ++kk) {
                int k = (kk + t) & 63;           // rotate start: spread banks across lanes
                float tv = trow[k];
                float4 w3 = *(const float4*)&W3s[k * 4];   // one b128 LDS read
                a0 += tv * w3.x;
                a1 += tv * w3.y;
                a2 += tv * w3.z;
                a3 += tv * w3.w;
            }
            int prow3 = rowcsr[pos3];
            int pk3 = csr[pos3];
            int tc = (pk3 >> 24) & 0xF;
            int tr = types[prow3];
            int pr = pvarr[prow3];
            int pc = pvts[tc];
            float halogen = (tr == 4 || tr == 5 || tc == 4 || tc == 5) ? 1.f : 0.f;
            float l1 = (pr <= 1 || pc <= 1) ? 1.f : 0.f;
            float l2 = (pr <= 2 || pc <= 2) ? 1.f : 0.f;
            float pen13 = -100.f * halogen - 50.f * l1;
            a1 += pen13;
            a3 += pen13;
            a2 += pen13 - 50.f * l2;
            int eid = eidarr[pos3];
            *(float4*)&bl_out[(size_t)eid * 4] = make_float4(a0, a1, a2, a3);
        }
    }
}

// ================================================================
extern "C" void kernel_launch(void* const* d_in, const int* in_sizes, int n_in,
                              void* d_out, int out_size, void* d_ws, size_t ws_size,
                              hipStream_t stream)
{
    const float* x          = (const float*)d_in[0];
    const float* edge_attr  = (const float*)d_in[1];
    const float* atom_emb   = (const float*)d_in[2];
    const float* bond_emb   = (const float*)d_in[3];
    const float* vp_w1      = (const float*)d_in[4];
    const float* vp_b1      = (const float*)d_in[5];
    const float* vp_w2      = (const float*)d_in[6];
    const float* vp_b2      = (const float*)d_in[7];
    const float* gnn_wself  = (const float*)d_in[8];
    const float* gnn_bself  = (const float*)d_in[9];
    const float* gnn_wmsg   = (const float*)d_in[10];
    const float* gnn_bmsg   = (const float*)d_in[11];
    const float* bc_w1      = (const float*)d_in[12];
    const float* bc_b1      = (const float*)d_in[13];
    const float* bc_w2      = (const float*)d_in[14];
    const float* bc_b2      = (const float*)d_in[15];
    const float* bc_w3      = (const float*)d_in[16];
    const float* bc_b3      = (const float*)d_in[17];
    const float* cp_w1      = (const float*)d_in[18];
    const float* cp_b1      = (const float*)d_in[19];
    const float* cp_w2      = (const float*)d_in[20];
    const float* cp_b2      = (const float*)d_in[21];
    const int*   ei         = (const int*)d_in[22];

    float* out    = (float*)d_out;
    float* h_out  = out + H_OFF;
    float* cp_out = out + CP_OFF;
    float* vl_out = out + VL_OFF;
    float* bl_out = out + BL_OFF;
    float* vi_out = out + VI_OFF;

    // ---- workspace layout ----
    char* base = (char*)d_ws;
    const size_t S = (size_t)M_PAD * 256 * 2;   // 51,249,152 B
    u16* h_bf  = (u16*)(base + 0 * S);           // R0: h ; later uv
    u16* uv_bf = (u16*)(base + 0 * S);
    u16* hm_bf = (u16*)(base + 1 * S);           // R1: hm
    u16* hs_bf = (u16*)(base + 2 * S);           // R2: hs
    u16* hd_bf = (u16*)(base + 3 * S);           // R3: damped h bf16
    u16* cp1_bf= (u16*)(base + 4 * S);           // R4: unused (cp2 fused)
    char* w    = base + 4 * S + (size_t)M_PAD * 128 * 2;
    int* degree  = (int*)w; w += (size_t)N_NODES * 4;
    int* offsets = (int*)w; w += (size_t)N_NODES * 4;
    int* cursor  = (int*)w; w += (size_t)N_NODES * 4;
    int* types   = (int*)w; w += (size_t)N_NODES * 4;
    int* pvarr   = (int*)w; w += (size_t)N_NODES * 4;
    int* csr     = (int*)w; w += (size_t)E_PAD * 4;
    int* rowcsr  = (int*)w; w += (size_t)E_PAD * 4;
    int* eidarr  = (int*)w; w += (size_t)E_PAD * 4;
    int* bsum    = (int*)w; w += 4096;
    int* bbase   = (int*)w; w += 4096;
    int* pv_tab  = (int*)w; w += 1024;
    float* vl_tab    = (float*)w; w += 2048;
    float* h0_tab    = (float*)w; w += 11 * 256 * 4;
    float* self0_tab = (float*)w; w += 11 * 256 * 4;
    float* msg0_tab  = (float*)w; w += 55 * 256 * 4;
    float* bondtab   = (float*)w; w += 2 * 5 * 256 * 4;
    u16* BtL1  = (u16*)w; w += 512 * 256 * 2;
    u16* BtL2  = (u16*)w; w += 512 * 256 * 2;
    u16* Bt3   = (u16*)w; w += 384 * 256 * 2;
    u16* BtW2  = (u16*)w; w += 128 * 128 * 2;
    u16* BtCP2 = (u16*)w; w += 128 * 128 * 2;
    float* bias512  = (float*)w; w += 2 * 512 * 4;
    float* biasPost = (float*)w; w += 384 * 4;

    // ---- setup ----
    hipMemsetAsync(degree, 0, (size_t)N_NODES * 4, stream);
    k_type_mlp<<<1, 256, 0, stream>>>(atom_emb, vp_w1, vp_b1, vp_w2, vp_b2,
                                      gnn_bself, bc_b1, cp_b1,
                                      pv_tab, vl_tab, h0_tab, bias512, biasPost);
    k_setup2<<<420, 256, 0, stream>>>(bond_emb, gnn_wself, gnn_bself, gnn_wmsg, gnn_bmsg,
                                      h0_tab, self0_tab, msg0_tab, bondtab,
                                      bc_w1, cp_w1, bc_w2, cp_w2,
                                      BtL1, BtL2, Bt3, BtW2, BtCP2);
    k_init_deg<<<NB_NODE + NB_EDGE, 256, 0, stream>>>(x, pv_tab, vl_tab, types, pvarr, vl_out, ei, degree);
    int nb = (N_NODES + SCAN_B - 1) / SCAN_B;
    k_scan1<<<nb, SCAN_B, 0, stream>>>(degree, offsets, bsum);
    k_scan3<<<nb, SCAN_B, 0, stream>>>(offsets, bsum, cursor, nb);
    k_csr_fill<<<(N_EDGES + 255) / 256, 256, 0, stream>>>(ei, edge_attr, types, cursor, csr, rowcsr, eidarr);
    k_agg0<<<N_NODES / 4, 256, 0, stream>>>(offsets, degree, types, self0_tab, msg0_tab, csr, h_bf);

    // ---- GNN layers 1,2 (l=2 fuses damp/viol/h_out) ----
    const int MT = M_PAD / 128;           // 782
    const int QB = (MT + 7) / 8;          // 98
    for (int l = 1; l <= 2; ++l) {
        const u16* BtL = (l == 1) ? BtL1 : BtL2;
        k_gemm_dual<<<QB * 32, 256, 0, stream>>>(h_bf, BtL, bias512 + (size_t)(l - 1) * 512,
                                                 hm_bf, hs_bf, N_NODES, MT);
        k_agg12<<<N_NODES / 4, 256, 0, stream>>>(offsets, degree, hs_bf, hm_bf,
                                                 bondtab + (size_t)(l - 1) * 5 * 256, csr, h_bf,
                                                 (l == 2) ? 1 : 0, pvarr, h_out, hd_bf, vi_out);
    }

    // ---- uv + cp1 + cp2 fully fused ----
    k_gemm_post<<<QB * 24, 256, 0, stream>>>(hd_bf, Bt3, biasPost, uv_bf, BtCP2, cp_b2, cp_out, N_NODES, MT);

    // ---- fused bond chain ----
    k_bond_fused<<<E_PAD / 128, 256, 0, stream>>>(csr, rowcsr, eidarr, types, pvarr, pv_tab,
                                                  uv_bf, bc_w1, BtW2, bc_b2, bc_w3, bc_b3, bl_out);
}